// Round 2
// baseline (1513.493 us; speedup 1.0000x reference)
//
#include <hip/hip_runtime.h>
#include <hip/hip_bf16.h>
#include <cstdint>
#include <cstddef>

typedef __attribute__((ext_vector_type(8))) short bf16x8;
typedef __attribute__((ext_vector_type(4))) float f32x4;

#define BB 32
#define NN 1024
#define CC 768
#define NHH 12
#define HDD 64
#define KKK 9
#define MM (BB * NN)   /* 32768 */
#define KNN (3 * CC)   /* 2304 = 2C (kv) + C (xq) */
#define PMDD 1536
#define CMDD 1536

__device__ __forceinline__ float bfbits2f(short s) {
  union { uint32_t u; float f; } cv;
  cv.u = ((uint32_t)(uint16_t)s) << 16;
  return cv.f;
}
__device__ __forceinline__ short f2bf(float f) {
  // round-to-nearest-even fp32 -> bf16 (inputs are finite)
  union { float f; uint32_t u; } cv;
  cv.f = f;
  uint32_t u = cv.u;
  uint32_t r = (u + 0x7fffu + ((u >> 16) & 1u)) >> 16;
  return (short)r;
}
__device__ __forceinline__ float gelu_f(float x) {
  return 0.5f * x * (1.0f + erff(x * 0.7071067811865476f));
}

// ---------------- weight transpose: Wt[j][c] = [kv_w | projq_w]^T (bf16) ---
__global__ __launch_bounds__(256) void transpose_w_kernel(
    const float* __restrict__ kv_w,     // [768][1536]
    const float* __restrict__ projq_w,  // [768][768]
    short* __restrict__ Wt)             // [2304][768] bf16 bits
{
  const int j = blockIdx.x;
  for (int c = threadIdx.x; c < CC; c += 256) {
    float v;
    if (j < 2 * CC) v = kv_w[(size_t)c * (2 * CC) + j];
    else            v = projq_w[(size_t)c * CC + (j - 2 * CC)];
    Wt[(size_t)j * CC + c] = f2bf(v);
  }
}

// ---------------- fused GEMM: big = x @ [kv_w | projq_w]  (bf16 MFMA) ------
#define LDSS 40  // padded LDS row stride (elems) to spread banks
__global__ __launch_bounds__(256) void gemm_bt_kernel(
    const float* __restrict__ A,     // [MM][768] fp32 row-major
    const short* __restrict__ Bt,    // [2304][768] bf16 row-major (B^T)
    short* __restrict__ C)           // [MM][2304] bf16
{
  __shared__ short As[128 * LDSS];
  __shared__ short Bs[128 * LDSS];
  const int tid = threadIdx.x;
  const int wave = tid >> 6, lane = tid & 63;
  const int bm = blockIdx.x * 128;
  const int bn = blockIdx.y * 128;
  const int srow = tid >> 2;           // 0..63
  const int scol = (tid & 3) * 8;      // 0,8,16,24
  const int wmo = (wave >> 1) * 64;
  const int wno = (wave & 1) * 64;
  const int lrow = lane & 15;
  const int kgrp = lane >> 4;          // 0..3
  f32x4 acc[4][4];
#pragma unroll
  for (int i = 0; i < 4; i++)
#pragma unroll
    for (int j = 0; j < 4; j++) acc[i][j] = (f32x4){0.f, 0.f, 0.f, 0.f};
  for (int k0 = 0; k0 < CC; k0 += 32) {
    f32x4 a0l = *(const f32x4*)&A[(size_t)(bm + srow) * CC + k0 + scol];
    f32x4 a0h = *(const f32x4*)&A[(size_t)(bm + srow) * CC + k0 + scol + 4];
    f32x4 a1l = *(const f32x4*)&A[(size_t)(bm + 64 + srow) * CC + k0 + scol];
    f32x4 a1h = *(const f32x4*)&A[(size_t)(bm + 64 + srow) * CC + k0 + scol + 4];
    bf16x8 vb0 = *(const bf16x8*)&Bt[(size_t)(bn + srow) * CC + k0 + scol];
    bf16x8 vb1 = *(const bf16x8*)&Bt[(size_t)(bn + 64 + srow) * CC + k0 + scol];
    bf16x8 va0, va1;
#pragma unroll
    for (int e = 0; e < 4; e++) {
      va0[e] = f2bf(a0l[e]); va0[e + 4] = f2bf(a0h[e]);
      va1[e] = f2bf(a1l[e]); va1[e + 4] = f2bf(a1h[e]);
    }
    __syncthreads();
    *(bf16x8*)&As[srow * LDSS + scol] = va0;
    *(bf16x8*)&As[(64 + srow) * LDSS + scol] = va1;
    *(bf16x8*)&Bs[srow * LDSS + scol] = vb0;
    *(bf16x8*)&Bs[(64 + srow) * LDSS + scol] = vb1;
    __syncthreads();
    bf16x8 af[4], bfr[4];
#pragma unroll
    for (int i = 0; i < 4; i++)
      af[i] = *(const bf16x8*)&As[(wmo + i * 16 + lrow) * LDSS + kgrp * 8];
#pragma unroll
    for (int j = 0; j < 4; j++)
      bfr[j] = *(const bf16x8*)&Bs[(wno + j * 16 + lrow) * LDSS + kgrp * 8];
#pragma unroll
    for (int i = 0; i < 4; i++)
#pragma unroll
      for (int j = 0; j < 4; j++)
        acc[i][j] = __builtin_amdgcn_mfma_f32_16x16x32_bf16(af[i], bfr[j], acc[i][j], 0, 0, 0);
  }
#pragma unroll
  for (int i = 0; i < 4; i++)
#pragma unroll
    for (int j = 0; j < 4; j++)
#pragma unroll
      for (int r = 0; r < 4; r++) {
        const int row = bm + wmo + i * 16 + kgrp * 4 + r;
        const int col = bn + wno + j * 16 + lrow;
        C[(size_t)row * KNN + col] = f2bf(acc[i][j][r]);
      }
}

// ---------------- row LayerNorm over C=768 (fp32 in/out) -------------------
__global__ __launch_bounds__(256) void row_ln_kernel(
    const float* __restrict__ in, float* __restrict__ out,
    const float* __restrict__ g, const float* __restrict__ bb, float eps)
{
  const int row = blockIdx.x;
  const int tid = threadIdx.x;
  __shared__ float red[256];
  const size_t base = (size_t)row * CC;
  float x0 = in[base + tid];
  float x1 = in[base + tid + 256];
  float x2 = in[base + tid + 512];
  red[tid] = x0 + x1 + x2;
  __syncthreads();
  for (int st = 128; st > 0; st >>= 1) { if (tid < st) red[tid] += red[tid + st]; __syncthreads(); }
  float mean = red[0] * (1.0f / 768.0f);
  __syncthreads();
  float d0 = x0 - mean, d1 = x1 - mean, d2 = x2 - mean;
  red[tid] = d0 * d0 + d1 * d1 + d2 * d2;
  __syncthreads();
  for (int st = 128; st > 0; st >>= 1) { if (tid < st) red[tid] += red[tid + st]; __syncthreads(); }
  float rstd = rsqrtf(red[0] * (1.0f / 768.0f) + eps);
  out[base + tid]       = d0 * rstd * g[tid]       + bb[tid];
  out[base + tid + 256] = d1 * rstd * g[tid + 256] + bb[tid + 256];
  out[base + tid + 512] = d2 * rstd * g[tid + 512] + bb[tid + 512];
}

// ---------------- attention: 9 queries x 1024 keys per (b,h) ---------------
__global__ __launch_bounds__(256) void attn_kernel(
    const float* __restrict__ wm,       // [9][768] = LN(kernel)
    const short* __restrict__ big,      // [32768][2304] bf16 (kv | xq)
    float* __restrict__ ca)             // [32][9][768]
{
  const int b = blockIdx.x;
  const int h = blockIdx.y;
  const int tid = threadIdx.x;
  __shared__ float wmh[KKK][HDD];
  __shared__ float sc[KKK][NN];
  __shared__ float part[4][KKK][HDD];
  __shared__ float red[256];
  for (int i = tid; i < KKK * HDD; i += 256) {
    int q = i >> 6, d = i & 63;
    wmh[q][d] = wm[q * CC + h * HDD + d];
  }
  __syncthreads();
  for (int n = tid; n < NN; n += 256) {
    const short* kp = &big[(size_t)(b * NN + n) * KNN + h * HDD];
    float acc[KKK];
#pragma unroll
    for (int q = 0; q < KKK; q++) acc[q] = 0.f;
    for (int d0 = 0; d0 < HDD; d0 += 8) {
      bf16x8 kv8 = *(const bf16x8*)&kp[d0];
#pragma unroll
      for (int e = 0; e < 8; e++) {
        float kf = bfbits2f(kv8[e]);
#pragma unroll
        for (int q = 0; q < KKK; q++) acc[q] += wmh[q][d0 + e] * kf;
      }
    }
#pragma unroll
    for (int q = 0; q < KKK; q++) sc[q][n] = acc[q] * 0.125f;
  }
  __syncthreads();
  for (int q = 0; q < KKK; q++) {
    float lm = -1e30f;
    for (int n = tid; n < NN; n += 256) lm = fmaxf(lm, sc[q][n]);
    red[tid] = lm; __syncthreads();
    for (int st = 128; st > 0; st >>= 1) { if (tid < st) red[tid] = fmaxf(red[tid], red[tid + st]); __syncthreads(); }
    float mx = red[0]; __syncthreads();
    float ls = 0.f;
    for (int n = tid; n < NN; n += 256) { float e = expf(sc[q][n] - mx); sc[q][n] = e; ls += e; }
    red[tid] = ls; __syncthreads();
    for (int st = 128; st > 0; st >>= 1) { if (tid < st) red[tid] += red[tid + st]; __syncthreads(); }
    float inv = 1.0f / red[0]; __syncthreads();
    for (int n = tid; n < NN; n += 256) sc[q][n] *= inv;
    __syncthreads();
  }
  const int d = tid & 63, prt = tid >> 6;
  float acc[KKK];
#pragma unroll
  for (int q = 0; q < KKK; q++) acc[q] = 0.f;
  for (int n = prt * 256; n < prt * 256 + 256; n++) {
    float vf = bfbits2f(big[(size_t)(b * NN + n) * KNN + CC + h * HDD + d]);
#pragma unroll
    for (int q = 0; q < KKK; q++) acc[q] += sc[q][n] * vf;
  }
#pragma unroll
  for (int q = 0; q < KKK; q++) part[prt][q][d] = acc[q];
  __syncthreads();
  for (int i = tid; i < KKK * HDD; i += 256) {
    int q = i >> 6, dd = i & 63;
    ca[(size_t)(b * KKK + q) * CC + h * HDD + dd] =
        part[0][q][dd] + part[1][q][dd] + part[2][q][dd] + part[3][q][dd];
  }
}

// ---------------- proj + residual: w1 = kernel + ca @ proj_w + proj_b ------
__global__ __launch_bounds__(256) void proj_res_kernel(
    const float* __restrict__ ca,      // [288][768]
    const float* __restrict__ proj_w,  // [768][768]
    const float* __restrict__ proj_b,  // [768]
    const float* __restrict__ kern,    // [9][768]
    float* __restrict__ w1)            // [288][768]
{
  const int row = blockIdx.x;  // b*9+q
  const int q = row % KKK;
  const int tid = threadIdx.x;
  __shared__ float car[CC];
  for (int i = tid; i < CC; i += 256) car[i] = ca[(size_t)row * CC + i];
  __syncthreads();
  float a0 = 0.f, a1 = 0.f, a2 = 0.f;
  for (int k = 0; k < CC; k++) {
    float av = car[k];
    const float* pw = &proj_w[(size_t)k * CC];
    a0 += av * pw[tid];
    a1 += av * pw[tid + 256];
    a2 += av * pw[tid + 512];
  }
  w1[(size_t)row * CC + tid]       = a0 + proj_b[tid]       + kern[q * CC + tid];
  w1[(size_t)row * CC + tid + 256] = a1 + proj_b[tid + 256] + kern[q * CC + tid + 256];
  w1[(size_t)row * CC + tid + 512] = a2 + proj_b[tid + 512] + kern[q * CC + tid + 512];
}

// ---------------- token mixer: per (b,c), 9 -> 1536 -> 9 -------------------
__global__ __launch_bounds__(256) void token_mix_kernel(
    const float* __restrict__ ln1,     // [288][768]
    const float* __restrict__ pm1_w,   // [9][1536]
    const float* __restrict__ pm1_b,   // [1536]
    const float* __restrict__ pm2_w,   // [1536][9]
    const float* __restrict__ pm2_b,   // [9]
    float* __restrict__ w1)
{
  const int idx = blockIdx.x * 256 + threadIdx.x;  // 0..24575
  const int b = idx / CC, c = idx % CC;
  float u[KKK], o[KKK];
#pragma unroll
  for (int q = 0; q < KKK; q++) { u[q] = ln1[(size_t)(b * KKK + q) * CC + c]; o[q] = 0.f; }
  for (int j = 0; j < PMDD; j++) {
    float hs = pm1_b[j];
#pragma unroll
    for (int q = 0; q < KKK; q++) hs += u[q] * pm1_w[q * PMDD + j];
    float gv = gelu_f(hs);
#pragma unroll
    for (int q = 0; q < KKK; q++) o[q] += gv * pm2_w[j * KKK + q];
  }
#pragma unroll
  for (int q = 0; q < KKK; q++)
    w1[(size_t)(b * KKK + q) * CC + c] += o[q] + pm2_b[q];
}

// ---------------- channel mixer: per (b,q) row, 768 -> 1536 -> 768 ---------
__global__ __launch_bounds__(256) void chan_mix_kernel(
    const float* __restrict__ ln2,     // [288][768]
    const float* __restrict__ cm1_w,   // [768][1536]
    const float* __restrict__ cm1_b,   // [1536]
    const float* __restrict__ cm2_w,   // [1536][768]
    const float* __restrict__ cm2_b,   // [768]
    float* __restrict__ w1)
{
  const int row = blockIdx.x;
  const int tid = threadIdx.x;
  __shared__ float xr[CC];
  __shared__ float h1[CMDD];
  for (int i = tid; i < CC; i += 256) xr[i] = ln2[(size_t)row * CC + i];
  __syncthreads();
  for (int j = tid; j < CMDD; j += 256) {
    float acc = cm1_b[j];
    for (int k = 0; k < CC; k++) acc += xr[k] * cm1_w[(size_t)k * CMDD + j];
    h1[j] = gelu_f(acc);
  }
  __syncthreads();
  for (int c = tid; c < CC; c += 256) {
    float acc = cm2_b[c];
    for (int j = 0; j < CMDD; j++) acc += h1[j] * cm2_w[(size_t)j * CC + c];
    w1[(size_t)row * CC + c] += acc;
  }
}

// ---------------- dynamic depthwise 3x3 conv + output transpose ------------
__global__ __launch_bounds__(256) void conv_kernel(
    const short* __restrict__ big,   // xq (bf16) at column offset 1536
    const float* __restrict__ w1,    // [32][9][768] filters
    float* __restrict__ out)         // [32][1024][768] fp32
{
  const int cchunk = blockIdx.x;  // 0..2
  const int y = blockIdx.y;       // 0..31
  const int b = blockIdx.z;       // 0..31
  const int c = cchunk * 256 + threadIdx.x;
  float f[KKK];
#pragma unroll
  for (int q = 0; q < KKK; q++) f[q] = w1[(size_t)(b * KKK + q) * CC + c];
  for (int x = 0; x < 32; x++) {
    float acc = 0.f;
#pragma unroll
    for (int ky = 0; ky < 3; ky++) {
      int yy = y + ky - 1;
      if (yy < 0 || yy > 31) continue;
#pragma unroll
      for (int kx = 0; kx < 3; kx++) {
        int xx = x + kx - 1;
        if (xx < 0 || xx > 31) continue;
        float v = bfbits2f(big[(size_t)(b * NN + yy * 32 + xx) * KNN + 2 * CC + c]);
        acc += f[ky * 3 + kx] * v;
      }
    }
    out[(size_t)(b * NN + y * 32 + x) * CC + c] = acc;
  }
}

// ---------------------------------------------------------------------------
extern "C" void kernel_launch(void* const* d_in, const int* in_sizes, int n_in,
                              void* d_out, int out_size, void* d_ws, size_t ws_size,
                              hipStream_t stream) {
  (void)in_sizes; (void)n_in; (void)out_size; (void)ws_size;
  const float* x       = (const float*)d_in[0];
  // d_in[1]=H, d_in[2]=W (int32 scalars == 32, unused)
  const float* kern    = (const float*)d_in[3];
  const float* ln_g    = (const float*)d_in[4];
  const float* ln_b    = (const float*)d_in[5];
  const float* kv_w    = (const float*)d_in[6];
  const float* proj_w  = (const float*)d_in[7];
  const float* proj_b  = (const float*)d_in[8];
  const float* projq_w = (const float*)d_in[9];
  const float* n1_g    = (const float*)d_in[10];
  const float* n1_b    = (const float*)d_in[11];
  const float* n2_g    = (const float*)d_in[12];
  const float* n2_b    = (const float*)d_in[13];
  const float* pm1_w   = (const float*)d_in[14];
  const float* pm1_b   = (const float*)d_in[15];
  const float* pm2_w   = (const float*)d_in[16];
  const float* pm2_b   = (const float*)d_in[17];
  const float* cm1_w   = (const float*)d_in[18];
  const float* cm1_b   = (const float*)d_in[19];
  const float* cm2_w   = (const float*)d_in[20];
  const float* cm2_b   = (const float*)d_in[21];
  float* out = (float*)d_out;

  uint8_t* ws = (uint8_t*)d_ws;
  short* Wt  = (short*)(ws);                    // 2304*768*2   = 3,538,944
  short* big = (short*)(ws + 3538944);          // 32768*2304*2 = 150,994,944
  float* wm  = (float*)(ws + 154533888);        // 9*768*4      = 27,648
  float* ca  = (float*)(ws + 154561536);        // 288*768*4    = 884,736
  float* w1  = (float*)(ws + 155446272);        // 884,736
  float* lnb = (float*)(ws + 156331008);        // 884,736  -> total 157,215,744 B

  transpose_w_kernel<<<dim3(KNN), 256, 0, stream>>>(kv_w, projq_w, Wt);
  gemm_bt_kernel<<<dim3(MM / 128, KNN / 128), 256, 0, stream>>>(x, Wt, big);
  row_ln_kernel<<<dim3(KKK), 256, 0, stream>>>(kern, wm, ln_g, ln_b, 1e-6f);
  attn_kernel<<<dim3(BB, NHH), 256, 0, stream>>>(wm, big, ca);
  proj_res_kernel<<<dim3(BB * KKK), 256, 0, stream>>>(ca, proj_w, proj_b, kern, w1);
  row_ln_kernel<<<dim3(BB * KKK), 256, 0, stream>>>(w1, lnb, n1_g, n1_b, 1e-5f);
  token_mix_kernel<<<dim3(96), 256, 0, stream>>>(lnb, pm1_w, pm1_b, pm2_w, pm2_b, w1);
  row_ln_kernel<<<dim3(BB * KKK), 256, 0, stream>>>(w1, lnb, n2_g, n2_b, 1e-5f);
  chan_mix_kernel<<<dim3(BB * KKK), 256, 0, stream>>>(lnb, cm1_w, cm1_b, cm2_w, cm2_b, w1);
  conv_kernel<<<dim3(3, 32, 32), 256, 0, stream>>>(big, w1, out);
}

// Round 3
// 825.875 us; speedup vs baseline: 1.8326x; 1.8326x over previous
//
#include <hip/hip_runtime.h>
#include <hip/hip_bf16.h>
#include <cstdint>
#include <cstddef>

typedef __attribute__((ext_vector_type(8))) short bf16x8;
typedef __attribute__((ext_vector_type(4))) float f32x4;

#define BB 32
#define NN 1024
#define CC 768
#define NHH 12
#define HDD 64
#define KKK 9
#define MM (BB * NN)   /* 32768 */
#define KNN (3 * CC)   /* 2304 = 2C (kv) + C (xq) */
#define PMDD 1536
#define CMDD 1536

__device__ __forceinline__ float bfbits2f(short s) {
  union { uint32_t u; float f; } cv;
  cv.u = ((uint32_t)(uint16_t)s) << 16;
  return cv.f;
}
__device__ __forceinline__ short f2bf(float f) {
  union { float f; uint32_t u; } cv;
  cv.f = f;
  uint32_t u = cv.u;
  uint32_t r = (u + 0x7fffu + ((u >> 16) & 1u)) >> 16;
  return (short)r;
}
__device__ __forceinline__ float gelu_f(float x) {
  return 0.5f * x * (1.0f + erff(x * 0.7071067811865476f));
}

// ---------------- weight transpose: Wt[j][c] = [kv_w | projq_w]^T (bf16) ---
__global__ __launch_bounds__(256) void transpose_w_kernel(
    const float* __restrict__ kv_w,     // [768][1536]
    const float* __restrict__ projq_w,  // [768][768]
    short* __restrict__ Wt)             // [2304][768] bf16 bits
{
  const int j = blockIdx.x;
  for (int c = threadIdx.x; c < CC; c += 256) {
    float v;
    if (j < 2 * CC) v = kv_w[(size_t)c * (2 * CC) + j];
    else            v = projq_w[(size_t)c * CC + (j - 2 * CC)];
    Wt[(size_t)j * CC + c] = f2bf(v);
  }
}

// ---------------- fused GEMM: big = x @ [kv_w | projq_w]  (bf16 MFMA) ------
#define LDSS 40
__global__ __launch_bounds__(256) void gemm_bt_kernel(
    const float* __restrict__ A,     // [MM][768] fp32 row-major
    const short* __restrict__ Bt,    // [2304][768] bf16 row-major (B^T)
    short* __restrict__ C)           // [MM][2304] bf16
{
  __shared__ short As[128 * LDSS];
  __shared__ short Bs[128 * LDSS];
  const int tid = threadIdx.x;
  const int wave = tid >> 6, lane = tid & 63;
  const int bm = blockIdx.x * 128;
  const int bn = blockIdx.y * 128;
  const int srow = tid >> 2;
  const int scol = (tid & 3) * 8;
  const int wmo = (wave >> 1) * 64;
  const int wno = (wave & 1) * 64;
  const int lrow = lane & 15;
  const int kgrp = lane >> 4;
  f32x4 acc[4][4];
#pragma unroll
  for (int i = 0; i < 4; i++)
#pragma unroll
    for (int j = 0; j < 4; j++) acc[i][j] = (f32x4){0.f, 0.f, 0.f, 0.f};
  for (int k0 = 0; k0 < CC; k0 += 32) {
    f32x4 a0l = *(const f32x4*)&A[(size_t)(bm + srow) * CC + k0 + scol];
    f32x4 a0h = *(const f32x4*)&A[(size_t)(bm + srow) * CC + k0 + scol + 4];
    f32x4 a1l = *(const f32x4*)&A[(size_t)(bm + 64 + srow) * CC + k0 + scol];
    f32x4 a1h = *(const f32x4*)&A[(size_t)(bm + 64 + srow) * CC + k0 + scol + 4];
    bf16x8 vb0 = *(const bf16x8*)&Bt[(size_t)(bn + srow) * CC + k0 + scol];
    bf16x8 vb1 = *(const bf16x8*)&Bt[(size_t)(bn + 64 + srow) * CC + k0 + scol];
    bf16x8 va0, va1;
#pragma unroll
    for (int e = 0; e < 4; e++) {
      va0[e] = f2bf(a0l[e]); va0[e + 4] = f2bf(a0h[e]);
      va1[e] = f2bf(a1l[e]); va1[e + 4] = f2bf(a1h[e]);
    }
    __syncthreads();
    *(bf16x8*)&As[srow * LDSS + scol] = va0;
    *(bf16x8*)&As[(64 + srow) * LDSS + scol] = va1;
    *(bf16x8*)&Bs[srow * LDSS + scol] = vb0;
    *(bf16x8*)&Bs[(64 + srow) * LDSS + scol] = vb1;
    __syncthreads();
    bf16x8 af[4], bfr[4];
#pragma unroll
    for (int i = 0; i < 4; i++)
      af[i] = *(const bf16x8*)&As[(wmo + i * 16 + lrow) * LDSS + kgrp * 8];
#pragma unroll
    for (int j = 0; j < 4; j++)
      bfr[j] = *(const bf16x8*)&Bs[(wno + j * 16 + lrow) * LDSS + kgrp * 8];
#pragma unroll
    for (int i = 0; i < 4; i++)
#pragma unroll
      for (int j = 0; j < 4; j++)
        acc[i][j] = __builtin_amdgcn_mfma_f32_16x16x32_bf16(af[i], bfr[j], acc[i][j], 0, 0, 0);
  }
#pragma unroll
  for (int i = 0; i < 4; i++)
#pragma unroll
    for (int j = 0; j < 4; j++)
#pragma unroll
      for (int r = 0; r < 4; r++) {
        const int row = bm + wmo + i * 16 + kgrp * 4 + r;
        const int col = bn + wno + j * 16 + lrow;
        C[(size_t)row * KNN + col] = f2bf(acc[i][j][r]);
      }
}

// ---------------- row LayerNorm over C=768 (fp32 in/out) -------------------
__global__ __launch_bounds__(256) void row_ln_kernel(
    const float* __restrict__ in, float* __restrict__ out,
    const float* __restrict__ g, const float* __restrict__ bb, float eps)
{
  const int row = blockIdx.x;
  const int tid = threadIdx.x;
  __shared__ float red[256];
  const size_t base = (size_t)row * CC;
  float x0 = in[base + tid];
  float x1 = in[base + tid + 256];
  float x2 = in[base + tid + 512];
  red[tid] = x0 + x1 + x2;
  __syncthreads();
  for (int st = 128; st > 0; st >>= 1) { if (tid < st) red[tid] += red[tid + st]; __syncthreads(); }
  float mean = red[0] * (1.0f / 768.0f);
  __syncthreads();
  float d0 = x0 - mean, d1 = x1 - mean, d2 = x2 - mean;
  red[tid] = d0 * d0 + d1 * d1 + d2 * d2;
  __syncthreads();
  for (int st = 128; st > 0; st >>= 1) { if (tid < st) red[tid] += red[tid + st]; __syncthreads(); }
  float rstd = rsqrtf(red[0] * (1.0f / 768.0f) + eps);
  out[base + tid]       = d0 * rstd * g[tid]       + bb[tid];
  out[base + tid + 256] = d1 * rstd * g[tid + 256] + bb[tid + 256];
  out[base + tid + 512] = d2 * rstd * g[tid + 512] + bb[tid + 512];
}

// ---------------- attention: 9 queries x 1024 keys per (b,h) ---------------
__global__ __launch_bounds__(256) void attn_kernel(
    const float* __restrict__ wm,       // [9][768]
    const short* __restrict__ big,      // [32768][2304] bf16 (kv | xq)
    float* __restrict__ ca)             // [32][9][768]
{
  const int b = blockIdx.x;
  const int h = blockIdx.y;
  const int tid = threadIdx.x;
  __shared__ float wmh[KKK][HDD];
  __shared__ float sc[KKK][NN];
  __shared__ float part[4][KKK][HDD];
  __shared__ float red[256];
  for (int i = tid; i < KKK * HDD; i += 256) {
    int q = i >> 6, d = i & 63;
    wmh[q][d] = wm[q * CC + h * HDD + d];
  }
  __syncthreads();
  for (int n = tid; n < NN; n += 256) {
    const short* kp = &big[(size_t)(b * NN + n) * KNN + h * HDD];
    float acc[KKK];
#pragma unroll
    for (int q = 0; q < KKK; q++) acc[q] = 0.f;
    for (int d0 = 0; d0 < HDD; d0 += 8) {
      bf16x8 kv8 = *(const bf16x8*)&kp[d0];
#pragma unroll
      for (int e = 0; e < 8; e++) {
        float kf = bfbits2f(kv8[e]);
#pragma unroll
        for (int q = 0; q < KKK; q++) acc[q] += wmh[q][d0 + e] * kf;
      }
    }
#pragma unroll
    for (int q = 0; q < KKK; q++) sc[q][n] = acc[q] * 0.125f;
  }
  __syncthreads();
  for (int q = 0; q < KKK; q++) {
    float lm = -1e30f;
    for (int n = tid; n < NN; n += 256) lm = fmaxf(lm, sc[q][n]);
    red[tid] = lm; __syncthreads();
    for (int st = 128; st > 0; st >>= 1) { if (tid < st) red[tid] = fmaxf(red[tid], red[tid + st]); __syncthreads(); }
    float mx = red[0]; __syncthreads();
    float ls = 0.f;
    for (int n = tid; n < NN; n += 256) { float e = expf(sc[q][n] - mx); sc[q][n] = e; ls += e; }
    red[tid] = ls; __syncthreads();
    for (int st = 128; st > 0; st >>= 1) { if (tid < st) red[tid] += red[tid + st]; __syncthreads(); }
    float inv = 1.0f / red[0]; __syncthreads();
    for (int n = tid; n < NN; n += 256) sc[q][n] *= inv;
    __syncthreads();
  }
  const int d = tid & 63, prt = tid >> 6;
  float acc[KKK];
#pragma unroll
  for (int q = 0; q < KKK; q++) acc[q] = 0.f;
  for (int n = prt * 256; n < prt * 256 + 256; n++) {
    float vf = bfbits2f(big[(size_t)(b * NN + n) * KNN + CC + h * HDD + d]);
#pragma unroll
    for (int q = 0; q < KKK; q++) acc[q] += sc[q][n] * vf;
  }
#pragma unroll
  for (int q = 0; q < KKK; q++) part[prt][q][d] = acc[q];
  __syncthreads();
  for (int i = tid; i < KKK * HDD; i += 256) {
    int q = i >> 6, dd = i & 63;
    ca[(size_t)(b * KKK + q) * CC + h * HDD + dd] =
        part[0][q][dd] + part[1][q][dd] + part[2][q][dd] + part[3][q][dd];
  }
}

// ---------------- proj + residual: w1 = kernel + ca @ proj_w + proj_b ------
// grid (144, 3): 2 rows per block, 256 cols per block
__global__ __launch_bounds__(256) void proj_res_kernel(
    const float* __restrict__ ca,      // [288][768]
    const float* __restrict__ proj_w,  // [768][768]
    const float* __restrict__ proj_b,  // [768]
    const float* __restrict__ kern,    // [9][768]
    float* __restrict__ w1)            // [288][768]
{
  const int r0 = blockIdx.x * 2;
  const int c = blockIdx.y * 256 + threadIdx.x;
  const int tid = threadIdx.x;
  __shared__ float car[2][CC];
  for (int i = tid; i < 2 * CC; i += 256)
    car[i / CC][i % CC] = ca[(size_t)(r0 + i / CC) * CC + (i % CC)];
  __syncthreads();
  float a0 = 0.f, a1 = 0.f;
  for (int k = 0; k < CC; k++) {
    float w = proj_w[(size_t)k * CC + c];
    a0 += car[0][k] * w;
    a1 += car[1][k] * w;
  }
  const int q0 = r0 % KKK, q1 = (r0 + 1) % KKK;
  w1[(size_t)r0 * CC + c]       = a0 + proj_b[c] + kern[q0 * CC + c];
  w1[(size_t)(r0 + 1) * CC + c] = a1 + proj_b[c] + kern[q1 * CC + c];
}

// ---------------- token mixer: per (b,c), 9 -> 1536 -> 9 -------------------
// grid (24, 32): 32 c-lanes x 8 j-groups per block
__global__ __launch_bounds__(256) void token_mix_kernel(
    const float* __restrict__ ln1,     // [288][768]
    const float* __restrict__ pm1_w,   // [9][1536]
    const float* __restrict__ pm1_b,   // [1536]
    const float* __restrict__ pm2_w,   // [1536][9]
    const float* __restrict__ pm2_b,   // [9]
    float* __restrict__ w1)
{
  const int tid = threadIdx.x;
  const int cl = tid & 31;        // c within chunk
  const int jg = tid >> 5;        // j-group 0..7
  const int c = blockIdx.x * 32 + cl;
  const int b = blockIdx.y;
  __shared__ float part[8][KKK][32];
  float u[KKK], o[KKK];
#pragma unroll
  for (int q = 0; q < KKK; q++) {
    u[q] = ln1[(size_t)(b * KKK + q) * CC + c];
    o[q] = 0.f;
  }
  for (int j = jg; j < PMDD; j += 8) {
    float hs = pm1_b[j];
#pragma unroll
    for (int q = 0; q < KKK; q++) hs += u[q] * pm1_w[q * PMDD + j];
    float gv = gelu_f(hs);
    const float* p2 = &pm2_w[(size_t)j * KKK];
#pragma unroll
    for (int q = 0; q < KKK; q++) o[q] += gv * p2[q];
  }
#pragma unroll
  for (int q = 0; q < KKK; q++) part[jg][q][cl] = o[q];
  __syncthreads();
  for (int i = tid; i < KKK * 32; i += 256) {
    int q = i >> 5, ccl = i & 31;
    float s = 0.f;
#pragma unroll
    for (int g = 0; g < 8; g++) s += part[g][q][ccl];
    w1[(size_t)(b * KKK + q) * CC + blockIdx.x * 32 + ccl] += s + pm2_b[q];
  }
}

// ---------------- channel mixer phase A: h1 = gelu(ln2 @ cm1_w + b) --------
// grid (72, 6): 4 rows per block, 256 j per block
__global__ __launch_bounds__(256) void chan_mix_a_kernel(
    const float* __restrict__ ln2,     // [288][768]
    const float* __restrict__ cm1_w,   // [768][1536]
    const float* __restrict__ cm1_b,   // [1536]
    float* __restrict__ h1g)           // [288][1536]
{
  const int r0 = blockIdx.x * 4;
  const int j = blockIdx.y * 256 + threadIdx.x;
  const int tid = threadIdx.x;
  __shared__ float xr[4][CC];
  for (int i = tid; i < 4 * CC; i += 256)
    xr[i / CC][i % CC] = ln2[(size_t)(r0 + i / CC) * CC + (i % CC)];
  __syncthreads();
  float a0, a1, a2, a3;
  a0 = a1 = a2 = a3 = cm1_b[j];
  for (int k = 0; k < CC; k++) {
    float w = cm1_w[(size_t)k * CMDD + j];
    a0 += xr[0][k] * w;
    a1 += xr[1][k] * w;
    a2 += xr[2][k] * w;
    a3 += xr[3][k] * w;
  }
  h1g[(size_t)(r0 + 0) * CMDD + j] = gelu_f(a0);
  h1g[(size_t)(r0 + 1) * CMDD + j] = gelu_f(a1);
  h1g[(size_t)(r0 + 2) * CMDD + j] = gelu_f(a2);
  h1g[(size_t)(r0 + 3) * CMDD + j] = gelu_f(a3);
}

// ---------------- channel mixer phase B: w1 += h1 @ cm2_w + cm2_b ----------
// grid (144, 3): 2 rows per block, 256 c per block
__global__ __launch_bounds__(256) void chan_mix_b_kernel(
    const float* __restrict__ h1g,     // [288][1536]
    const float* __restrict__ cm2_w,   // [1536][768]
    const float* __restrict__ cm2_b,   // [768]
    float* __restrict__ w1)
{
  const int r0 = blockIdx.x * 2;
  const int c = blockIdx.y * 256 + threadIdx.x;
  const int tid = threadIdx.x;
  __shared__ float hr[2][CMDD];
  for (int i = tid; i < 2 * CMDD; i += 256)
    hr[i / CMDD][i % CMDD] = h1g[(size_t)(r0 + i / CMDD) * CMDD + (i % CMDD)];
  __syncthreads();
  float a0 = cm2_b[c], a1 = a0;
  for (int jj = 0; jj < CMDD; jj++) {
    float w = cm2_w[(size_t)jj * CC + c];
    a0 += hr[0][jj] * w;
    a1 += hr[1][jj] * w;
  }
  w1[(size_t)r0 * CC + c]       += a0;
  w1[(size_t)(r0 + 1) * CC + c] += a1;
}

// ---------------- dynamic depthwise 3x3 conv + output transpose ------------
__global__ __launch_bounds__(256) void conv_kernel(
    const short* __restrict__ big,   // xq (bf16) at column offset 1536
    const float* __restrict__ w1,    // [32][9][768] filters
    float* __restrict__ out)         // [32][1024][768] fp32
{
  const int cchunk = blockIdx.x;
  const int y = blockIdx.y;
  const int b = blockIdx.z;
  const int c = cchunk * 256 + threadIdx.x;
  float f[KKK];
#pragma unroll
  for (int q = 0; q < KKK; q++) f[q] = w1[(size_t)(b * KKK + q) * CC + c];
  for (int x = 0; x < 32; x++) {
    float acc = 0.f;
#pragma unroll
    for (int ky = 0; ky < 3; ky++) {
      int yy = y + ky - 1;
      if (yy < 0 || yy > 31) continue;
#pragma unroll
      for (int kx = 0; kx < 3; kx++) {
        int xx = x + kx - 1;
        if (xx < 0 || xx > 31) continue;
        float v = bfbits2f(big[(size_t)(b * NN + yy * 32 + xx) * KNN + 2 * CC + c]);
        acc += f[ky * 3 + kx] * v;
      }
    }
    out[(size_t)(b * NN + y * 32 + x) * CC + c] = acc;
  }
}

// ---------------------------------------------------------------------------
extern "C" void kernel_launch(void* const* d_in, const int* in_sizes, int n_in,
                              void* d_out, int out_size, void* d_ws, size_t ws_size,
                              hipStream_t stream) {
  (void)in_sizes; (void)n_in; (void)out_size; (void)ws_size;
  const float* x       = (const float*)d_in[0];
  const float* kern    = (const float*)d_in[3];
  const float* ln_g    = (const float*)d_in[4];
  const float* ln_b    = (const float*)d_in[5];
  const float* kv_w    = (const float*)d_in[6];
  const float* proj_w  = (const float*)d_in[7];
  const float* proj_b  = (const float*)d_in[8];
  const float* projq_w = (const float*)d_in[9];
  const float* n1_g    = (const float*)d_in[10];
  const float* n1_b    = (const float*)d_in[11];
  const float* n2_g    = (const float*)d_in[12];
  const float* n2_b    = (const float*)d_in[13];
  const float* pm1_w   = (const float*)d_in[14];
  const float* pm1_b   = (const float*)d_in[15];
  const float* pm2_w   = (const float*)d_in[16];
  const float* pm2_b   = (const float*)d_in[17];
  const float* cm1_w   = (const float*)d_in[18];
  const float* cm1_b   = (const float*)d_in[19];
  const float* cm2_w   = (const float*)d_in[20];
  const float* cm2_b   = (const float*)d_in[21];
  float* out = (float*)d_out;

  uint8_t* ws = (uint8_t*)d_ws;
  short* Wt  = (short*)(ws);                    // 2304*768*2   = 3,538,944
  float* h1g = (float*)(ws);                    // ALIAS: 288*1536*4 = 1,769,472 (Wt dead after GEMM)
  short* big = (short*)(ws + 3538944);          // 32768*2304*2 = 150,994,944
  float* wm  = (float*)(ws + 154533888);        // 27,648
  float* ca  = (float*)(ws + 154561536);        // 884,736
  float* w1  = (float*)(ws + 155446272);        // 884,736
  float* lnb = (float*)(ws + 156331008);        // 884,736 -> total 157,215,744 B

  transpose_w_kernel<<<dim3(KNN), 256, 0, stream>>>(kv_w, projq_w, Wt);
  gemm_bt_kernel<<<dim3(MM / 128, KNN / 128), 256, 0, stream>>>(x, Wt, big);
  row_ln_kernel<<<dim3(KKK), 256, 0, stream>>>(kern, wm, ln_g, ln_b, 1e-6f);
  attn_kernel<<<dim3(BB, NHH), 256, 0, stream>>>(wm, big, ca);
  proj_res_kernel<<<dim3(144, 3), 256, 0, stream>>>(ca, proj_w, proj_b, kern, w1);
  row_ln_kernel<<<dim3(BB * KKK), 256, 0, stream>>>(w1, lnb, n1_g, n1_b, 1e-5f);
  token_mix_kernel<<<dim3(24, 32), 256, 0, stream>>>(lnb, pm1_w, pm1_b, pm2_w, pm2_b, w1);
  row_ln_kernel<<<dim3(BB * KKK), 256, 0, stream>>>(w1, lnb, n2_g, n2_b, 1e-5f);
  chan_mix_a_kernel<<<dim3(72, 6), 256, 0, stream>>>(lnb, cm1_w, cm1_b, h1g);
  chan_mix_b_kernel<<<dim3(144, 3), 256, 0, stream>>>(h1g, cm2_w, cm2_b, w1);
  conv_kernel<<<dim3(3, 32, 32), 256, 0, stream>>>(big, w1, out);
}

// Round 4
// 730.534 us; speedup vs baseline: 2.0718x; 1.1305x over previous
//
#include <hip/hip_runtime.h>
#include <hip/hip_bf16.h>
#include <cstdint>
#include <cstddef>

typedef __attribute__((ext_vector_type(8))) short bf16x8;
typedef __attribute__((ext_vector_type(4))) float f32x4;

#define BB 32
#define NN 1024
#define CC 768
#define NHH 12
#define HDD 64
#define KKK 9
#define MM (BB * NN)   /* 32768 */
#define KNN (3 * CC)   /* 2304 = 2C (kv) + C (xq) */
#define PMDD 1536
#define CMDD 1536

__device__ __forceinline__ float bfbits2f(short s) {
  union { uint32_t u; float f; } cv;
  cv.u = ((uint32_t)(uint16_t)s) << 16;
  return cv.f;
}
__device__ __forceinline__ short f2bf(float f) {
  union { float f; uint32_t u; } cv;
  cv.f = f;
  uint32_t u = cv.u;
  uint32_t r = (u + 0x7fffu + ((u >> 16) & 1u)) >> 16;
  return (short)r;
}
__device__ __forceinline__ float gelu_f(float x) {
  return 0.5f * x * (1.0f + erff(x * 0.7071067811865476f));
}

typedef const __attribute__((address_space(1))) uint32_t* gp1_t;
typedef __attribute__((address_space(3))) uint32_t* lp3_t;
__device__ __forceinline__ void gload16(const short* g, const short* l) {
  __builtin_amdgcn_global_load_lds((gp1_t)(uintptr_t)(const void*)g,
                                   (lp3_t)(uint32_t)(uintptr_t)(const void*)l,
                                   16, 0, 0);
}

// ---------------- x -> bf16 prepass ----------------------------------------
__global__ __launch_bounds__(256) void xbf_kernel(
    const float* __restrict__ x, short* __restrict__ xb)
{
  const int i = (blockIdx.x * 256 + threadIdx.x) * 8;  // MM*CC = 25165824
  f32x4 a = *(const f32x4*)&x[i];
  f32x4 b = *(const f32x4*)&x[i + 4];
  bf16x8 o;
#pragma unroll
  for (int e = 0; e < 4; e++) { o[e] = f2bf(a[e]); o[e + 4] = f2bf(b[e]); }
  *(bf16x8*)&xb[i] = o;
}

// ---------------- weight transpose (tiled): Wt[j][c] = W^T (bf16) ----------
__global__ __launch_bounds__(256) void transpose_w_kernel(
    const float* __restrict__ kv_w,     // [768][1536]
    const float* __restrict__ projq_w,  // [768][768]
    short* __restrict__ Wt)             // [2304][768] bf16 bits
{
  __shared__ float tile[32][33];
  const int j0 = blockIdx.x * 32;   // 0..2303
  const int c0 = blockIdx.y * 32;   // 0..767
  const int tx = threadIdx.x & 31, ty = threadIdx.x >> 5;  // ty 0..7
  const float* src; int ldj, jj;
  if (j0 < 2 * CC) { src = kv_w; ldj = 2 * CC; jj = j0; }
  else             { src = projq_w; ldj = CC; jj = j0 - 2 * CC; }
#pragma unroll
  for (int r = 0; r < 4; r++) {
    int cl = ty + r * 8;
    tile[cl][tx] = src[(size_t)(c0 + cl) * ldj + jj + tx];
  }
  __syncthreads();
#pragma unroll
  for (int r = 0; r < 4; r++) {
    int jl = ty + r * 8;
    Wt[(size_t)(j0 + jl) * CC + c0 + tx] = f2bf(tile[tx][jl]);
  }
}

// ---------------- fused GEMM: big = x @ [kv_w | projq_w]  (bf16 MFMA) ------
// m97 structure: 128x128 tile, BK=32, global_load_lds w16, linear LDS.
__global__ __launch_bounds__(256) void gemm_bt_kernel(
    const short* __restrict__ A,     // [MM][768] bf16
    const short* __restrict__ Bt,    // [2304][768] bf16 (B^T)
    short* __restrict__ C)           // [MM][2304] bf16
{
  __shared__ short As[128 * 32];
  __shared__ short Bs[128 * 32];
  const int tid = threadIdx.x;
  const int wave = tid >> 6, lane = tid & 63;
  // XCD-aware swizzle, n-fastest logical order (4608 = 8 * 576, bijective)
  const int lid = blockIdx.x;
  const int wid = (lid & 7) * 576 + (lid >> 3);
  const int bn = (wid % 18) * 128;
  const int bm = (wid / 18) * 128;
  const int wmo = (wave >> 1) * 64;
  const int wno = (wave & 1) * 64;
  const int lrow = lane & 15;
  const int kgrp = lane >> 4;
  // staging: wave w covers rows [w*32, w*32+32) in two 16-row chunks
  const int srow = wave * 32 + (lane >> 2);
  const int scol = (lane & 3) * 8;
  const short* gA0 = A + (size_t)(bm + srow) * CC + scol;
  const short* gA1 = gA0 + (size_t)16 * CC;
  const short* gB0 = Bt + (size_t)(bn + srow) * CC + scol;
  const short* gB1 = gB0 + (size_t)16 * CC;
  const short* lA0 = &As[(wave * 32) * 32];
  const short* lA1 = &As[(wave * 32 + 16) * 32];
  const short* lB0 = &Bs[(wave * 32) * 32];
  const short* lB1 = &Bs[(wave * 32 + 16) * 32];
  f32x4 acc[4][4];
#pragma unroll
  for (int i = 0; i < 4; i++)
#pragma unroll
    for (int j = 0; j < 4; j++) acc[i][j] = (f32x4){0.f, 0.f, 0.f, 0.f};
  for (int k0 = 0; k0 < CC; k0 += 32) {
    __syncthreads();
    gload16(gA0 + k0, lA0);
    gload16(gA1 + k0, lA1);
    gload16(gB0 + k0, lB0);
    gload16(gB1 + k0, lB1);
    __syncthreads();
    bf16x8 af[4], bfr[4];
#pragma unroll
    for (int i = 0; i < 4; i++)
      af[i] = *(const bf16x8*)&As[(wmo + i * 16 + lrow) * 32 + kgrp * 8];
#pragma unroll
    for (int j = 0; j < 4; j++)
      bfr[j] = *(const bf16x8*)&Bs[(wno + j * 16 + lrow) * 32 + kgrp * 8];
#pragma unroll
    for (int i = 0; i < 4; i++)
#pragma unroll
      for (int j = 0; j < 4; j++)
        acc[i][j] = __builtin_amdgcn_mfma_f32_16x16x32_bf16(af[i], bfr[j], acc[i][j], 0, 0, 0);
  }
#pragma unroll
  for (int i = 0; i < 4; i++)
#pragma unroll
    for (int j = 0; j < 4; j++)
#pragma unroll
      for (int r = 0; r < 4; r++) {
        const int row = bm + wmo + i * 16 + kgrp * 4 + r;
        const int col = bn + wno + j * 16 + lrow;
        C[(size_t)row * KNN + col] = f2bf(acc[i][j][r]);
      }
}

// ---------------- row LayerNorm over C=768 (fp32 in/out) -------------------
__global__ __launch_bounds__(256) void row_ln_kernel(
    const float* __restrict__ in, float* __restrict__ out,
    const float* __restrict__ g, const float* __restrict__ bb, float eps)
{
  const int row = blockIdx.x;
  const int tid = threadIdx.x;
  __shared__ float red[256];
  const size_t base = (size_t)row * CC;
  float x0 = in[base + tid];
  float x1 = in[base + tid + 256];
  float x2 = in[base + tid + 512];
  red[tid] = x0 + x1 + x2;
  __syncthreads();
  for (int st = 128; st > 0; st >>= 1) { if (tid < st) red[tid] += red[tid + st]; __syncthreads(); }
  float mean = red[0] * (1.0f / 768.0f);
  __syncthreads();
  float d0 = x0 - mean, d1 = x1 - mean, d2 = x2 - mean;
  red[tid] = d0 * d0 + d1 * d1 + d2 * d2;
  __syncthreads();
  for (int st = 128; st > 0; st >>= 1) { if (tid < st) red[tid] += red[tid + st]; __syncthreads(); }
  float rstd = rsqrtf(red[0] * (1.0f / 768.0f) + eps);
  out[base + tid]       = d0 * rstd * g[tid]       + bb[tid];
  out[base + tid + 256] = d1 * rstd * g[tid + 256] + bb[tid + 256];
  out[base + tid + 512] = d2 * rstd * g[tid + 512] + bb[tid + 512];
}

// ---------------- attention: 9 queries x 1024 keys per (b,h) ---------------
__global__ __launch_bounds__(256) void attn_kernel(
    const float* __restrict__ wm,       // [9][768]
    const short* __restrict__ big,      // [32768][2304] bf16 (kv | xq)
    float* __restrict__ ca)             // [32][9][768]
{
  const int b = blockIdx.x;
  const int h = blockIdx.y;
  const int tid = threadIdx.x;
  __shared__ float wmh[KKK][HDD];
  __shared__ float sc[KKK][NN];
  __shared__ float part[4][KKK][HDD];
  __shared__ float red[256];
  for (int i = tid; i < KKK * HDD; i += 256) {
    int q = i >> 6, d = i & 63;
    wmh[q][d] = wm[q * CC + h * HDD + d];
  }
  __syncthreads();
  for (int n = tid; n < NN; n += 256) {
    const short* kp = &big[(size_t)(b * NN + n) * KNN + h * HDD];
    float acc[KKK];
#pragma unroll
    for (int q = 0; q < KKK; q++) acc[q] = 0.f;
    for (int d0 = 0; d0 < HDD; d0 += 8) {
      bf16x8 kv8 = *(const bf16x8*)&kp[d0];
#pragma unroll
      for (int e = 0; e < 8; e++) {
        float kf = bfbits2f(kv8[e]);
#pragma unroll
        for (int q = 0; q < KKK; q++) acc[q] += wmh[q][d0 + e] * kf;
      }
    }
#pragma unroll
    for (int q = 0; q < KKK; q++) sc[q][n] = acc[q] * 0.125f;
  }
  __syncthreads();
  for (int q = 0; q < KKK; q++) {
    float lm = -1e30f;
    for (int n = tid; n < NN; n += 256) lm = fmaxf(lm, sc[q][n]);
    red[tid] = lm; __syncthreads();
    for (int st = 128; st > 0; st >>= 1) { if (tid < st) red[tid] = fmaxf(red[tid], red[tid + st]); __syncthreads(); }
    float mx = red[0]; __syncthreads();
    float ls = 0.f;
    for (int n = tid; n < NN; n += 256) { float e = expf(sc[q][n] - mx); sc[q][n] = e; ls += e; }
    red[tid] = ls; __syncthreads();
    for (int st = 128; st > 0; st >>= 1) { if (tid < st) red[tid] += red[tid + st]; __syncthreads(); }
    float inv = 1.0f / red[0]; __syncthreads();
    for (int n = tid; n < NN; n += 256) sc[q][n] *= inv;
    __syncthreads();
  }
  const int d = tid & 63, prt = tid >> 6;
  float acc[KKK];
#pragma unroll
  for (int q = 0; q < KKK; q++) acc[q] = 0.f;
  for (int n = prt * 256; n < prt * 256 + 256; n++) {
    float vf = bfbits2f(big[(size_t)(b * NN + n) * KNN + CC + h * HDD + d]);
#pragma unroll
    for (int q = 0; q < KKK; q++) acc[q] += sc[q][n] * vf;
  }
#pragma unroll
  for (int q = 0; q < KKK; q++) part[prt][q][d] = acc[q];
  __syncthreads();
  for (int i = tid; i < KKK * HDD; i += 256) {
    int q = i >> 6, dd = i & 63;
    ca[(size_t)(b * KKK + q) * CC + h * HDD + dd] =
        part[0][q][dd] + part[1][q][dd] + part[2][q][dd] + part[3][q][dd];
  }
}

// ---------------- proj + residual ------------------------------------------
__global__ __launch_bounds__(256) void proj_res_kernel(
    const float* __restrict__ ca,      // [288][768]
    const float* __restrict__ proj_w,  // [768][768]
    const float* __restrict__ proj_b,  // [768]
    const float* __restrict__ kern,    // [9][768]
    float* __restrict__ w1)            // [288][768]
{
  const int r0 = blockIdx.x * 2;
  const int c = blockIdx.y * 256 + threadIdx.x;
  const int tid = threadIdx.x;
  __shared__ float car[2][CC];
  for (int i = tid; i < 2 * CC; i += 256)
    car[i / CC][i % CC] = ca[(size_t)(r0 + i / CC) * CC + (i % CC)];
  __syncthreads();
  float a0 = 0.f, a1 = 0.f;
  for (int k = 0; k < CC; k++) {
    float w = proj_w[(size_t)k * CC + c];
    a0 += car[0][k] * w;
    a1 += car[1][k] * w;
  }
  const int q0 = r0 % KKK, q1 = (r0 + 1) % KKK;
  w1[(size_t)r0 * CC + c]       = a0 + proj_b[c] + kern[q0 * CC + c];
  w1[(size_t)(r0 + 1) * CC + c] = a1 + proj_b[c] + kern[q1 * CC + c];
}

// ---------------- token mixer ----------------------------------------------
__global__ __launch_bounds__(256) void token_mix_kernel(
    const float* __restrict__ ln1,     // [288][768]
    const float* __restrict__ pm1_w,   // [9][1536]
    const float* __restrict__ pm1_b,   // [1536]
    const float* __restrict__ pm2_w,   // [1536][9]
    const float* __restrict__ pm2_b,   // [9]
    float* __restrict__ w1)
{
  const int tid = threadIdx.x;
  const int cl = tid & 31;
  const int jg = tid >> 5;
  const int c = blockIdx.x * 32 + cl;
  const int b = blockIdx.y;
  __shared__ float part[8][KKK][32];
  float u[KKK], o[KKK];
#pragma unroll
  for (int q = 0; q < KKK; q++) {
    u[q] = ln1[(size_t)(b * KKK + q) * CC + c];
    o[q] = 0.f;
  }
  for (int j = jg; j < PMDD; j += 8) {
    float hs = pm1_b[j];
#pragma unroll
    for (int q = 0; q < KKK; q++) hs += u[q] * pm1_w[q * PMDD + j];
    float gv = gelu_f(hs);
    const float* p2 = &pm2_w[(size_t)j * KKK];
#pragma unroll
    for (int q = 0; q < KKK; q++) o[q] += gv * p2[q];
  }
#pragma unroll
  for (int q = 0; q < KKK; q++) part[jg][q][cl] = o[q];
  __syncthreads();
  for (int i = tid; i < KKK * 32; i += 256) {
    int q = i >> 5, ccl = i & 31;
    float s = 0.f;
#pragma unroll
    for (int g = 0; g < 8; g++) s += part[g][q][ccl];
    w1[(size_t)(b * KKK + q) * CC + blockIdx.x * 32 + ccl] += s + pm2_b[q];
  }
}

// ---------------- channel mixer A ------------------------------------------
__global__ __launch_bounds__(256) void chan_mix_a_kernel(
    const float* __restrict__ ln2,     // [288][768]
    const float* __restrict__ cm1_w,   // [768][1536]
    const float* __restrict__ cm1_b,   // [1536]
    float* __restrict__ h1g)           // [288][1536]
{
  const int r0 = blockIdx.x * 4;
  const int j = blockIdx.y * 256 + threadIdx.x;
  const int tid = threadIdx.x;
  __shared__ float xr[4][CC];
  for (int i = tid; i < 4 * CC; i += 256)
    xr[i / CC][i % CC] = ln2[(size_t)(r0 + i / CC) * CC + (i % CC)];
  __syncthreads();
  float a0, a1, a2, a3;
  a0 = a1 = a2 = a3 = cm1_b[j];
  for (int k = 0; k < CC; k++) {
    float w = cm1_w[(size_t)k * CMDD + j];
    a0 += xr[0][k] * w;
    a1 += xr[1][k] * w;
    a2 += xr[2][k] * w;
    a3 += xr[3][k] * w;
  }
  h1g[(size_t)(r0 + 0) * CMDD + j] = gelu_f(a0);
  h1g[(size_t)(r0 + 1) * CMDD + j] = gelu_f(a1);
  h1g[(size_t)(r0 + 2) * CMDD + j] = gelu_f(a2);
  h1g[(size_t)(r0 + 3) * CMDD + j] = gelu_f(a3);
}

// ---------------- channel mixer B ------------------------------------------
__global__ __launch_bounds__(256) void chan_mix_b_kernel(
    const float* __restrict__ h1g,     // [288][1536]
    const float* __restrict__ cm2_w,   // [1536][768]
    const float* __restrict__ cm2_b,   // [768]
    float* __restrict__ w1)
{
  const int r0 = blockIdx.x * 2;
  const int c = blockIdx.y * 256 + threadIdx.x;
  const int tid = threadIdx.x;
  __shared__ float hr[2][CMDD];
  for (int i = tid; i < 2 * CMDD; i += 256)
    hr[i / CMDD][i % CMDD] = h1g[(size_t)(r0 + i / CMDD) * CMDD + (i % CMDD)];
  __syncthreads();
  float a0 = cm2_b[c], a1 = a0;
  for (int jj = 0; jj < CMDD; jj++) {
    float w = cm2_w[(size_t)jj * CC + c];
    a0 += hr[0][jj] * w;
    a1 += hr[1][jj] * w;
  }
  w1[(size_t)r0 * CC + c]       += a0;
  w1[(size_t)(r0 + 1) * CC + c] += a1;
}

// ---------------- dynamic depthwise 3x3 conv (sliding window) --------------
__global__ __launch_bounds__(256) void conv_kernel(
    const short* __restrict__ big,   // xq (bf16) at column offset 1536
    const float* __restrict__ w1,    // [32][9][768] filters
    float* __restrict__ out)         // [32][1024][768] fp32
{
  const int cchunk = blockIdx.x;
  const int y = blockIdx.y;
  const int b = blockIdx.z;
  const int c = cchunk * 256 + threadIdx.x;
  float f[KKK];
#pragma unroll
  for (int q = 0; q < KKK; q++) f[q] = w1[(size_t)(b * KKK + q) * CC + c];
  const short* rp[3];
  bool rv[3];
#pragma unroll
  for (int ky = 0; ky < 3; ky++) {
    int yy = y + ky - 1;
    rv[ky] = (yy >= 0 && yy < 32);
    rp[ky] = big + (size_t)(b * NN + (rv[ky] ? yy : 0) * 32) * KNN + 2 * CC + c;
  }
  float c0[3] = {0.f, 0.f, 0.f}, c1[3], c2[3];
#pragma unroll
  for (int ky = 0; ky < 3; ky++) c1[ky] = rv[ky] ? bfbits2f(rp[ky][0]) : 0.f;
  float* op = &out[(size_t)(b * NN + y * 32) * CC + c];
  for (int x = 0; x < 32; x++) {
#pragma unroll
    for (int ky = 0; ky < 3; ky++)
      c2[ky] = (x + 1 < 32 && rv[ky]) ? bfbits2f(rp[ky][(size_t)(x + 1) * KNN]) : 0.f;
    float acc = 0.f;
#pragma unroll
    for (int ky = 0; ky < 3; ky++)
      acc += f[ky * 3 + 0] * c0[ky] + f[ky * 3 + 1] * c1[ky] + f[ky * 3 + 2] * c2[ky];
    op[(size_t)x * CC] = acc;
#pragma unroll
    for (int ky = 0; ky < 3; ky++) { c0[ky] = c1[ky]; c1[ky] = c2[ky]; }
  }
}

// ---------------------------------------------------------------------------
extern "C" void kernel_launch(void* const* d_in, const int* in_sizes, int n_in,
                              void* d_out, int out_size, void* d_ws, size_t ws_size,
                              hipStream_t stream) {
  (void)in_sizes; (void)n_in; (void)out_size; (void)ws_size;
  const float* x       = (const float*)d_in[0];
  const float* kern    = (const float*)d_in[3];
  const float* ln_g    = (const float*)d_in[4];
  const float* ln_b    = (const float*)d_in[5];
  const float* kv_w    = (const float*)d_in[6];
  const float* proj_w  = (const float*)d_in[7];
  const float* proj_b  = (const float*)d_in[8];
  const float* projq_w = (const float*)d_in[9];
  const float* n1_g    = (const float*)d_in[10];
  const float* n1_b    = (const float*)d_in[11];
  const float* n2_g    = (const float*)d_in[12];
  const float* n2_b    = (const float*)d_in[13];
  const float* pm1_w   = (const float*)d_in[14];
  const float* pm1_b   = (const float*)d_in[15];
  const float* pm2_w   = (const float*)d_in[16];
  const float* pm2_b   = (const float*)d_in[17];
  const float* cm1_w   = (const float*)d_in[18];
  const float* cm1_b   = (const float*)d_in[19];
  const float* cm2_w   = (const float*)d_in[20];
  const float* cm2_b   = (const float*)d_in[21];
  float* out = (float*)d_out;

  uint8_t* ws = (uint8_t*)d_ws;
  short* Wt  = (short*)(ws);                    // 2304*768*2   = 3,538,944
  float* h1g = (float*)(ws);                    // ALIAS (Wt dead after GEMM)
  short* big = (short*)(ws + 3538944);          // 32768*2304*2 = 150,994,944
  float* wm  = (float*)(ws + 154533888);        // 27,648
  float* ca  = (float*)(ws + 154561536);        // 884,736
  float* w1  = (float*)(ws + 155446272);        // 884,736
  float* lnb = (float*)(ws + 156331008);        // 884,736 -> total 157,215,744 B

  // x as bf16 lives in d_out (96 MB >= 50.3 MB); conv overwrites it at the end.
  short* xb = (short*)d_out;

  xbf_kernel<<<dim3(MM * CC / (256 * 8)), 256, 0, stream>>>(x, xb);
  transpose_w_kernel<<<dim3(KNN / 32, CC / 32), 256, 0, stream>>>(kv_w, projq_w, Wt);
  gemm_bt_kernel<<<dim3((MM / 128) * (KNN / 128)), 256, 0, stream>>>(xb, Wt, big);
  row_ln_kernel<<<dim3(KKK), 256, 0, stream>>>(kern, wm, ln_g, ln_b, 1e-6f);
  attn_kernel<<<dim3(BB, NHH), 256, 0, stream>>>(wm, big, ca);
  proj_res_kernel<<<dim3(144, 3), 256, 0, stream>>>(ca, proj_w, proj_b, kern, w1);
  row_ln_kernel<<<dim3(BB * KKK), 256, 0, stream>>>(w1, lnb, n1_g, n1_b, 1e-5f);
  token_mix_kernel<<<dim3(24, 32), 256, 0, stream>>>(lnb, pm1_w, pm1_b, pm2_w, pm2_b, w1);
  row_ln_kernel<<<dim3(BB * KKK), 256, 0, stream>>>(w1, lnb, n2_g, n2_b, 1e-5f);
  chan_mix_a_kernel<<<dim3(72, 6), 256, 0, stream>>>(lnb, cm1_w, cm1_b, h1g);
  chan_mix_b_kernel<<<dim3(144, 3), 256, 0, stream>>>(h1g, cm2_w, cm2_b, w1);
  conv_kernel<<<dim3(3, 32, 32), 256, 0, stream>>>(big, w1, out);
}

// Round 5
// 679.172 us; speedup vs baseline: 2.2284x; 1.0756x over previous
//
#include <hip/hip_runtime.h>
#include <hip/hip_bf16.h>
#include <cstdint>
#include <cstddef>

typedef __attribute__((ext_vector_type(8))) short bf16x8;
typedef __attribute__((ext_vector_type(4))) float f32x4;

#define BB 32
#define NN 1024
#define CC 768
#define NHH 12
#define HDD 64
#define KKK 9
#define MM (BB * NN)   /* 32768 */
#define KNN (3 * CC)   /* 2304 = 2C (kv) + C (xq) */
#define PMDD 1536
#define CMDD 1536
#define BK 64

__device__ __forceinline__ float bfbits2f(short s) {
  union { uint32_t u; float f; } cv;
  cv.u = ((uint32_t)(uint16_t)s) << 16;
  return cv.f;
}
__device__ __forceinline__ short f2bf(float f) {
  union { float f; uint32_t u; } cv;
  cv.f = f;
  uint32_t u = cv.u;
  uint32_t r = (u + 0x7fffu + ((u >> 16) & 1u)) >> 16;
  return (short)r;
}
__device__ __forceinline__ float gelu_f(float x) {
  return 0.5f * x * (1.0f + erff(x * 0.7071067811865476f));
}

typedef const __attribute__((address_space(1))) uint32_t* gp1_t;
typedef __attribute__((address_space(3))) uint32_t* lp3_t;
__device__ __forceinline__ void gload16(const short* g, const short* l) {
  __builtin_amdgcn_global_load_lds((gp1_t)(uintptr_t)(const void*)g,
                                   (lp3_t)(uint32_t)(uintptr_t)(const void*)l,
                                   16, 0, 0);
}

// ---------------- x -> bf16 prepass ----------------------------------------
__global__ __launch_bounds__(256) void xbf_kernel(
    const float* __restrict__ x, short* __restrict__ xb)
{
  const int i = (blockIdx.x * 256 + threadIdx.x) * 8;
  f32x4 a = *(const f32x4*)&x[i];
  f32x4 b = *(const f32x4*)&x[i + 4];
  bf16x8 o;
#pragma unroll
  for (int e = 0; e < 4; e++) { o[e] = f2bf(a[e]); o[e + 4] = f2bf(b[e]); }
  *(bf16x8*)&xb[i] = o;
}

// ---------------- weight transpose (tiled): Wt[j][c] = W^T (bf16) ----------
__global__ __launch_bounds__(256) void transpose_w_kernel(
    const float* __restrict__ kv_w,     // [768][1536]
    const float* __restrict__ projq_w,  // [768][768]
    short* __restrict__ Wt)             // [2304][768] bf16 bits
{
  __shared__ float tile[32][33];
  const int j0 = blockIdx.x * 32;
  const int c0 = blockIdx.y * 32;
  const int tx = threadIdx.x & 31, ty = threadIdx.x >> 5;
  const float* src; int ldj, jj;
  if (j0 < 2 * CC) { src = kv_w; ldj = 2 * CC; jj = j0; }
  else             { src = projq_w; ldj = CC; jj = j0 - 2 * CC; }
#pragma unroll
  for (int r = 0; r < 4; r++) {
    int cl = ty + r * 8;
    tile[cl][tx] = src[(size_t)(c0 + cl) * ldj + jj + tx];
  }
  __syncthreads();
#pragma unroll
  for (int r = 0; r < 4; r++) {
    int jl = ty + r * 8;
    Wt[(size_t)(j0 + jl) * CC + c0 + tx] = f2bf(tile[tx][jl]);
  }
}

// ---------------- fused GEMM: big = x @ [kv_w | projq_w]  (bf16 MFMA) ------
// 128x128 tile, BK=64, global_load_lds w16, XOR-swizzled (slot ^= row&7):
// LDS linear; inverse swizzle applied on the per-lane GLOBAL source address,
// forward swizzle applied on the ds_read address (guide rule #21).
__global__ __launch_bounds__(256) void gemm_bt_kernel(
    const short* __restrict__ A,     // [MM][768] bf16
    const short* __restrict__ Bt,    // [2304][768] bf16 (B^T)
    short* __restrict__ C)           // [MM][2304] bf16
{
  __shared__ short As[128 * BK];
  __shared__ short Bs[128 * BK];
  const int tid = threadIdx.x;
  const int wave = tid >> 6, lane = tid & 63;
  // XCD-aware swizzle, n-fastest logical order (4608 = 8 * 576, bijective)
  const int lid = blockIdx.x;
  const int wid = (lid & 7) * 576 + (lid >> 3);
  const int bn = (wid % 18) * 128;
  const int bm = (wid / 18) * 128;
  const int wmo = (wave >> 1) * 64;
  const int wno = (wave & 1) * 64;
  const int lrow = lane & 15;
  const int kgrp = lane >> 4;      // 0..3
  // staging: 8 threads/row (16B slots), 32 rows per issue, 4 issues per tile
  const int sr = tid >> 3;         // 0..31
  const int ss = tid & 7;          // slot 0..7
  const int slotG = ss ^ (sr & 7); // inverse-swizzled source slot
  const short* gA = A + (size_t)(bm + sr) * CC + slotG * 8;
  const short* gB = Bt + (size_t)(bn + sr) * CC + slotG * 8;
  const short* lA = &As[sr * BK + ss * 8];
  const short* lB = &Bs[sr * BK + ss * 8];
  // swizzled read slots for the two K-halves
  const int rs0 = kgrp ^ (lrow & 7);
  const int rs1 = (4 + kgrp) ^ (lrow & 7);
  f32x4 acc[4][4];
#pragma unroll
  for (int i = 0; i < 4; i++)
#pragma unroll
    for (int j = 0; j < 4; j++) acc[i][j] = (f32x4){0.f, 0.f, 0.f, 0.f};
  for (int k0 = 0; k0 < CC; k0 += BK) {
    __syncthreads();
#pragma unroll
    for (int i = 0; i < 4; i++) {
      gload16(gA + (size_t)(i * 32) * CC + k0, lA + i * 32 * BK);
      gload16(gB + (size_t)(i * 32) * CC + k0, lB + i * 32 * BK);
    }
    __syncthreads();
#pragma unroll
    for (int kh = 0; kh < 2; kh++) {
      const int rs = kh ? rs1 : rs0;
      bf16x8 af[4], bfr[4];
#pragma unroll
      for (int i = 0; i < 4; i++)
        af[i] = *(const bf16x8*)&As[(wmo + i * 16 + lrow) * BK + rs * 8];
#pragma unroll
      for (int j = 0; j < 4; j++)
        bfr[j] = *(const bf16x8*)&Bs[(wno + j * 16 + lrow) * BK + rs * 8];
#pragma unroll
      for (int i = 0; i < 4; i++)
#pragma unroll
        for (int j = 0; j < 4; j++)
          acc[i][j] = __builtin_amdgcn_mfma_f32_16x16x32_bf16(af[i], bfr[j], acc[i][j], 0, 0, 0);
    }
  }
#pragma unroll
  for (int i = 0; i < 4; i++)
#pragma unroll
    for (int j = 0; j < 4; j++)
#pragma unroll
      for (int r = 0; r < 4; r++) {
        const int row = bm + wmo + i * 16 + kgrp * 4 + r;
        const int col = bn + wno + j * 16 + lrow;
        C[(size_t)row * KNN + col] = f2bf(acc[i][j][r]);
      }
}

// ---------------- row LayerNorm over C=768 (fp32 in/out) -------------------
__global__ __launch_bounds__(256) void row_ln_kernel(
    const float* __restrict__ in, float* __restrict__ out,
    const float* __restrict__ g, const float* __restrict__ bb, float eps)
{
  const int row = blockIdx.x;
  const int tid = threadIdx.x;
  __shared__ float red[256];
  const size_t base = (size_t)row * CC;
  float x0 = in[base + tid];
  float x1 = in[base + tid + 256];
  float x2 = in[base + tid + 512];
  red[tid] = x0 + x1 + x2;
  __syncthreads();
  for (int st = 128; st > 0; st >>= 1) { if (tid < st) red[tid] += red[tid + st]; __syncthreads(); }
  float mean = red[0] * (1.0f / 768.0f);
  __syncthreads();
  float d0 = x0 - mean, d1 = x1 - mean, d2 = x2 - mean;
  red[tid] = d0 * d0 + d1 * d1 + d2 * d2;
  __syncthreads();
  for (int st = 128; st > 0; st >>= 1) { if (tid < st) red[tid] += red[tid + st]; __syncthreads(); }
  float rstd = rsqrtf(red[0] * (1.0f / 768.0f) + eps);
  out[base + tid]       = d0 * rstd * g[tid]       + bb[tid];
  out[base + tid + 256] = d1 * rstd * g[tid + 256] + bb[tid + 256];
  out[base + tid + 512] = d2 * rstd * g[tid + 512] + bb[tid + 512];
}

// ---------------- attention: 9 queries x 1024 keys per (b,h) ---------------
// wave-parallel softmax: wave w owns q in {w, w+4, w+8}, shfl_xor reductions.
__global__ __launch_bounds__(256) void attn_kernel(
    const float* __restrict__ wm,       // [9][768]
    const short* __restrict__ big,      // [32768][2304] bf16 (kv | xq)
    float* __restrict__ ca)             // [32][9][768]
{
  const int b = blockIdx.x;
  const int h = blockIdx.y;
  const int tid = threadIdx.x;
  const int wave = tid >> 6, lane = tid & 63;
  __shared__ float wmh[KKK][HDD];
  __shared__ float sc[KKK][NN];
  __shared__ float part[4][KKK][HDD];
  for (int i = tid; i < KKK * HDD; i += 256) {
    int q = i >> 6, d = i & 63;
    wmh[q][d] = wm[q * CC + h * HDD + d];
  }
  __syncthreads();
  // scores
  for (int n = tid; n < NN; n += 256) {
    const short* kp = &big[(size_t)(b * NN + n) * KNN + h * HDD];
    float acc[KKK];
#pragma unroll
    for (int q = 0; q < KKK; q++) acc[q] = 0.f;
    for (int d0 = 0; d0 < HDD; d0 += 8) {
      bf16x8 kv8 = *(const bf16x8*)&kp[d0];
#pragma unroll
      for (int e = 0; e < 8; e++) {
        float kf = bfbits2f(kv8[e]);
#pragma unroll
        for (int q = 0; q < KKK; q++) acc[q] += wmh[q][d0 + e] * kf;
      }
    }
#pragma unroll
    for (int q = 0; q < KKK; q++) sc[q][n] = acc[q] * 0.125f;
  }
  __syncthreads();
  // softmax: no block barriers, wave-local shuffles only
  for (int q = wave; q < KKK; q += 4) {
    float m = -1e30f;
#pragma unroll
    for (int i = 0; i < 16; i++) m = fmaxf(m, sc[q][lane + i * 64]);
#pragma unroll
    for (int off = 32; off > 0; off >>= 1) m = fmaxf(m, __shfl_xor(m, off));
    float s = 0.f;
#pragma unroll
    for (int i = 0; i < 16; i++) {
      float e = expf(sc[q][lane + i * 64] - m);
      sc[q][lane + i * 64] = e;
      s += e;
    }
#pragma unroll
    for (int off = 32; off > 0; off >>= 1) s += __shfl_xor(s, off);
    float inv = 1.0f / s;
#pragma unroll
    for (int i = 0; i < 16; i++) sc[q][lane + i * 64] *= inv;
  }
  __syncthreads();
  // PV
  const int d = tid & 63, prt = tid >> 6;
  float acc[KKK];
#pragma unroll
  for (int q = 0; q < KKK; q++) acc[q] = 0.f;
  for (int n = prt * 256; n < prt * 256 + 256; n++) {
    float vf = bfbits2f(big[(size_t)(b * NN + n) * KNN + CC + h * HDD + d]);
#pragma unroll
    for (int q = 0; q < KKK; q++) acc[q] += sc[q][n] * vf;
  }
#pragma unroll
  for (int q = 0; q < KKK; q++) part[prt][q][d] = acc[q];
  __syncthreads();
  for (int i = tid; i < KKK * HDD; i += 256) {
    int q = i >> 6, dd = i & 63;
    ca[(size_t)(b * KKK + q) * CC + h * HDD + dd] =
        part[0][q][dd] + part[1][q][dd] + part[2][q][dd] + part[3][q][dd];
  }
}

// ---------------- proj + residual ------------------------------------------
__global__ __launch_bounds__(256) void proj_res_kernel(
    const float* __restrict__ ca,      // [288][768]
    const float* __restrict__ proj_w,  // [768][768]
    const float* __restrict__ proj_b,  // [768]
    const float* __restrict__ kern,    // [9][768]
    float* __restrict__ w1)            // [288][768]
{
  const int r0 = blockIdx.x * 2;
  const int c = blockIdx.y * 256 + threadIdx.x;
  const int tid = threadIdx.x;
  __shared__ float car[2][CC];
  for (int i = tid; i < 2 * CC; i += 256)
    car[i / CC][i % CC] = ca[(size_t)(r0 + i / CC) * CC + (i % CC)];
  __syncthreads();
  float a0 = 0.f, a1 = 0.f;
  for (int k = 0; k < CC; k++) {
    float w = proj_w[(size_t)k * CC + c];
    a0 += car[0][k] * w;
    a1 += car[1][k] * w;
  }
  const int q0 = r0 % KKK, q1 = (r0 + 1) % KKK;
  w1[(size_t)r0 * CC + c]       = a0 + proj_b[c] + kern[q0 * CC + c];
  w1[(size_t)(r0 + 1) * CC + c] = a1 + proj_b[c] + kern[q1 * CC + c];
}

// ---------------- token mixer ----------------------------------------------
__global__ __launch_bounds__(256) void token_mix_kernel(
    const float* __restrict__ ln1,     // [288][768]
    const float* __restrict__ pm1_w,   // [9][1536]
    const float* __restrict__ pm1_b,   // [1536]
    const float* __restrict__ pm2_w,   // [1536][9]
    const float* __restrict__ pm2_b,   // [9]
    float* __restrict__ w1)
{
  const int tid = threadIdx.x;
  const int cl = tid & 31;
  const int jg = tid >> 5;
  const int c = blockIdx.x * 32 + cl;
  const int b = blockIdx.y;
  __shared__ float part[8][KKK][32];
  float u[KKK], o[KKK];
#pragma unroll
  for (int q = 0; q < KKK; q++) {
    u[q] = ln1[(size_t)(b * KKK + q) * CC + c];
    o[q] = 0.f;
  }
  for (int j = jg; j < PMDD; j += 8) {
    float hs = pm1_b[j];
#pragma unroll
    for (int q = 0; q < KKK; q++) hs += u[q] * pm1_w[q * PMDD + j];
    float gv = gelu_f(hs);
    const float* p2 = &pm2_w[(size_t)j * KKK];
#pragma unroll
    for (int q = 0; q < KKK; q++) o[q] += gv * p2[q];
  }
#pragma unroll
  for (int q = 0; q < KKK; q++) part[jg][q][cl] = o[q];
  __syncthreads();
  for (int i = tid; i < KKK * 32; i += 256) {
    int q = i >> 5, ccl = i & 31;
    float s = 0.f;
#pragma unroll
    for (int g = 0; g < 8; g++) s += part[g][q][ccl];
    w1[(size_t)(b * KKK + q) * CC + blockIdx.x * 32 + ccl] += s + pm2_b[q];
  }
}

// ---------------- channel mixer A ------------------------------------------
__global__ __launch_bounds__(256) void chan_mix_a_kernel(
    const float* __restrict__ ln2,     // [288][768]
    const float* __restrict__ cm1_w,   // [768][1536]
    const float* __restrict__ cm1_b,   // [1536]
    float* __restrict__ h1g)           // [288][1536]
{
  const int r0 = blockIdx.x * 4;
  const int j = blockIdx.y * 256 + threadIdx.x;
  const int tid = threadIdx.x;
  __shared__ float xr[4][CC];
  for (int i = tid; i < 4 * CC; i += 256)
    xr[i / CC][i % CC] = ln2[(size_t)(r0 + i / CC) * CC + (i % CC)];
  __syncthreads();
  float a0, a1, a2, a3;
  a0 = a1 = a2 = a3 = cm1_b[j];
  for (int k = 0; k < CC; k++) {
    float w = cm1_w[(size_t)k * CMDD + j];
    a0 += xr[0][k] * w;
    a1 += xr[1][k] * w;
    a2 += xr[2][k] * w;
    a3 += xr[3][k] * w;
  }
  h1g[(size_t)(r0 + 0) * CMDD + j] = gelu_f(a0);
  h1g[(size_t)(r0 + 1) * CMDD + j] = gelu_f(a1);
  h1g[(size_t)(r0 + 2) * CMDD + j] = gelu_f(a2);
  h1g[(size_t)(r0 + 3) * CMDD + j] = gelu_f(a3);
}

// ---------------- channel mixer B ------------------------------------------
__global__ __launch_bounds__(256) void chan_mix_b_kernel(
    const float* __restrict__ h1g,     // [288][1536]
    const float* __restrict__ cm2_w,   // [1536][768]
    const float* __restrict__ cm2_b,   // [768]
    float* __restrict__ w1)
{
  const int r0 = blockIdx.x * 2;
  const int c = blockIdx.y * 256 + threadIdx.x;
  const int tid = threadIdx.x;
  __shared__ float hr[2][CMDD];
  for (int i = tid; i < 2 * CMDD; i += 256)
    hr[i / CMDD][i % CMDD] = h1g[(size_t)(r0 + i / CMDD) * CMDD + (i % CMDD)];
  __syncthreads();
  float a0 = cm2_b[c], a1 = a0;
  for (int jj = 0; jj < CMDD; jj++) {
    float w = cm2_w[(size_t)jj * CC + c];
    a0 += hr[0][jj] * w;
    a1 += hr[1][jj] * w;
  }
  w1[(size_t)r0 * CC + c]       += a0;
  w1[(size_t)(r0 + 1) * CC + c] += a1;
}

// ---------------- dynamic depthwise 3x3 conv (sliding window) --------------
__global__ __launch_bounds__(256) void conv_kernel(
    const short* __restrict__ big,   // xq (bf16) at column offset 1536
    const float* __restrict__ w1,    // [32][9][768] filters
    float* __restrict__ out)         // [32][1024][768] fp32
{
  const int cchunk = blockIdx.x;
  const int y = blockIdx.y;
  const int b = blockIdx.z;
  const int c = cchunk * 256 + threadIdx.x;
  float f[KKK];
#pragma unroll
  for (int q = 0; q < KKK; q++) f[q] = w1[(size_t)(b * KKK + q) * CC + c];
  const short* rp[3];
  bool rv[3];
#pragma unroll
  for (int ky = 0; ky < 3; ky++) {
    int yy = y + ky - 1;
    rv[ky] = (yy >= 0 && yy < 32);
    rp[ky] = big + (size_t)(b * NN + (rv[ky] ? yy : 0) * 32) * KNN + 2 * CC + c;
  }
  float c0[3] = {0.f, 0.f, 0.f}, c1[3], c2[3];
#pragma unroll
  for (int ky = 0; ky < 3; ky++) c1[ky] = rv[ky] ? bfbits2f(rp[ky][0]) : 0.f;
  float* op = &out[(size_t)(b * NN + y * 32) * CC + c];
  for (int x = 0; x < 32; x++) {
#pragma unroll
    for (int ky = 0; ky < 3; ky++)
      c2[ky] = (x + 1 < 32 && rv[ky]) ? bfbits2f(rp[ky][(size_t)(x + 1) * KNN]) : 0.f;
    float acc = 0.f;
#pragma unroll
    for (int ky = 0; ky < 3; ky++)
      acc += f[ky * 3 + 0] * c0[ky] + f[ky * 3 + 1] * c1[ky] + f[ky * 3 + 2] * c2[ky];
    op[(size_t)x * CC] = acc;
#pragma unroll
    for (int ky = 0; ky < 3; ky++) { c0[ky] = c1[ky]; c1[ky] = c2[ky]; }
  }
}

// ---------------------------------------------------------------------------
extern "C" void kernel_launch(void* const* d_in, const int* in_sizes, int n_in,
                              void* d_out, int out_size, void* d_ws, size_t ws_size,
                              hipStream_t stream) {
  (void)in_sizes; (void)n_in; (void)out_size; (void)ws_size;
  const float* x       = (const float*)d_in[0];
  const float* kern    = (const float*)d_in[3];
  const float* ln_g    = (const float*)d_in[4];
  const float* ln_b    = (const float*)d_in[5];
  const float* kv_w    = (const float*)d_in[6];
  const float* proj_w  = (const float*)d_in[7];
  const float* proj_b  = (const float*)d_in[8];
  const float* projq_w = (const float*)d_in[9];
  const float* n1_g    = (const float*)d_in[10];
  const float* n1_b    = (const float*)d_in[11];
  const float* n2_g    = (const float*)d_in[12];
  const float* n2_b    = (const float*)d_in[13];
  const float* pm1_w   = (const float*)d_in[14];
  const float* pm1_b   = (const float*)d_in[15];
  const float* pm2_w   = (const float*)d_in[16];
  const float* pm2_b   = (const float*)d_in[17];
  const float* cm1_w   = (const float*)d_in[18];
  const float* cm1_b   = (const float*)d_in[19];
  const float* cm2_w   = (const float*)d_in[20];
  const float* cm2_b   = (const float*)d_in[21];
  float* out = (float*)d_out;

  uint8_t* ws = (uint8_t*)d_ws;
  short* Wt  = (short*)(ws);                    // 2304*768*2   = 3,538,944
  float* h1g = (float*)(ws);                    // ALIAS (Wt dead after GEMM)
  short* big = (short*)(ws + 3538944);          // 32768*2304*2 = 150,994,944
  float* wm  = (float*)(ws + 154533888);        // 27,648
  float* ca  = (float*)(ws + 154561536);        // 884,736
  float* w1  = (float*)(ws + 155446272);        // 884,736
  float* lnb = (float*)(ws + 156331008);        // 884,736 -> total 157,215,744 B

  // x as bf16 lives in d_out (96 MB >= 50.3 MB); conv overwrites it at the end.
  short* xb = (short*)d_out;

  xbf_kernel<<<dim3(MM * CC / (256 * 8)), 256, 0, stream>>>(x, xb);
  transpose_w_kernel<<<dim3(KNN / 32, CC / 32), 256, 0, stream>>>(kv_w, projq_w, Wt);
  gemm_bt_kernel<<<dim3((MM / 128) * (KNN / 128)), 256, 0, stream>>>(xb, Wt, big);
  row_ln_kernel<<<dim3(KKK), 256, 0, stream>>>(kern, wm, ln_g, ln_b, 1e-6f);
  attn_kernel<<<dim3(BB, NHH), 256, 0, stream>>>(wm, big, ca);
  proj_res_kernel<<<dim3(144, 3), 256, 0, stream>>>(ca, proj_w, proj_b, kern, w1);
  row_ln_kernel<<<dim3(BB * KKK), 256, 0, stream>>>(w1, lnb, n1_g, n1_b, 1e-5f);
  token_mix_kernel<<<dim3(24, 32), 256, 0, stream>>>(lnb, pm1_w, pm1_b, pm2_w, pm2_b, w1);
  row_ln_kernel<<<dim3(BB * KKK), 256, 0, stream>>>(w1, lnb, n2_g, n2_b, 1e-5f);
  chan_mix_a_kernel<<<dim3(72, 6), 256, 0, stream>>>(lnb, cm1_w, cm1_b, h1g);
  chan_mix_b_kernel<<<dim3(144, 3), 256, 0, stream>>>(h1g, cm2_w, cm2_b, w1);
  conv_kernel<<<dim3(3, 32, 32), 256, 0, stream>>>(big, w1, out);
}

// Round 6
// 615.495 us; speedup vs baseline: 2.4590x; 1.1035x over previous
//
#include <hip/hip_runtime.h>
#include <hip/hip_bf16.h>
#include <cstdint>
#include <cstddef>

typedef __attribute__((ext_vector_type(8))) short bf16x8;
typedef __attribute__((ext_vector_type(4))) float f32x4;

#define BB 32
#define NN 1024
#define CC 768
#define NHH 12
#define HDD 64
#define KKK 9
#define MM (BB * NN)   /* 32768 */
#define KNN (3 * CC)   /* 2304 = 2C (kv) + C (xq) */
#define PMDD 1536
#define CMDD 1536
#define BK 64

__device__ __forceinline__ float bfbits2f(short s) {
  union { uint32_t u; float f; } cv;
  cv.u = ((uint32_t)(uint16_t)s) << 16;
  return cv.f;
}
__device__ __forceinline__ short f2bf(float f) {
  union { float f; uint32_t u; } cv;
  cv.f = f;
  uint32_t u = cv.u;
  uint32_t r = (u + 0x7fffu + ((u >> 16) & 1u)) >> 16;
  return (short)r;
}
__device__ __forceinline__ float gelu_f(float x) {
  return 0.5f * x * (1.0f + erff(x * 0.7071067811865476f));
}

typedef const __attribute__((address_space(1))) uint32_t* gp1_t;
typedef __attribute__((address_space(3))) uint32_t* lp3_t;
__device__ __forceinline__ void gload16(const short* g, const short* l) {
  __builtin_amdgcn_global_load_lds((gp1_t)(uintptr_t)(const void*)g,
                                   (lp3_t)(uint32_t)(uintptr_t)(const void*)l,
                                   16, 0, 0);
}

// ---------------- x -> bf16 prepass ----------------------------------------
__global__ __launch_bounds__(256) void xbf_kernel(
    const float* __restrict__ x, short* __restrict__ xb)
{
  const int i = (blockIdx.x * 256 + threadIdx.x) * 8;
  f32x4 a = *(const f32x4*)&x[i];
  f32x4 b = *(const f32x4*)&x[i + 4];
  bf16x8 o;
#pragma unroll
  for (int e = 0; e < 4; e++) { o[e] = f2bf(a[e]); o[e + 4] = f2bf(b[e]); }
  *(bf16x8*)&xb[i] = o;
}

// ---------------- weight transpose (tiled): Wt[j][c] = W^T (bf16) ----------
__global__ __launch_bounds__(256) void transpose_w_kernel(
    const float* __restrict__ kv_w,     // [768][1536]
    const float* __restrict__ projq_w,  // [768][768]
    short* __restrict__ Wt)             // [2304][768] bf16 bits
{
  __shared__ float tile[32][33];
  const int j0 = blockIdx.x * 32;
  const int c0 = blockIdx.y * 32;
  const int tx = threadIdx.x & 31, ty = threadIdx.x >> 5;
  const float* src; int ldj, jj;
  if (j0 < 2 * CC) { src = kv_w; ldj = 2 * CC; jj = j0; }
  else             { src = projq_w; ldj = CC; jj = j0 - 2 * CC; }
#pragma unroll
  for (int r = 0; r < 4; r++) {
    int cl = ty + r * 8;
    tile[cl][tx] = src[(size_t)(c0 + cl) * ldj + jj + tx];
  }
  __syncthreads();
#pragma unroll
  for (int r = 0; r < 4; r++) {
    int jl = ty + r * 8;
    Wt[(size_t)(j0 + jl) * CC + c0 + tx] = f2bf(tile[tx][jl]);
  }
}

// ---------------- fused GEMM: big = x @ [kv_w | projq_w]  (bf16 MFMA) ------
__global__ __launch_bounds__(256) void gemm_bt_kernel(
    const short* __restrict__ A,     // [MM][768] bf16
    const short* __restrict__ Bt,    // [2304][768] bf16 (B^T)
    short* __restrict__ C)           // [MM][2304] bf16
{
  __shared__ short As[128 * BK];
  __shared__ short Bs[128 * BK];
  const int tid = threadIdx.x;
  const int wave = tid >> 6, lane = tid & 63;
  const int lid = blockIdx.x;
  const int wid = (lid & 7) * 576 + (lid >> 3);
  const int bn = (wid % 18) * 128;
  const int bm = (wid / 18) * 128;
  const int wmo = (wave >> 1) * 64;
  const int wno = (wave & 1) * 64;
  const int lrow = lane & 15;
  const int kgrp = lane >> 4;
  const int sr = tid >> 3;
  const int ss = tid & 7;
  const int slotG = ss ^ (sr & 7);
  const short* gA = A + (size_t)(bm + sr) * CC + slotG * 8;
  const short* gB = Bt + (size_t)(bn + sr) * CC + slotG * 8;
  const short* lA = &As[sr * BK + ss * 8];
  const short* lB = &Bs[sr * BK + ss * 8];
  const int rs0 = kgrp ^ (lrow & 7);
  const int rs1 = (4 + kgrp) ^ (lrow & 7);
  f32x4 acc[4][4];
#pragma unroll
  for (int i = 0; i < 4; i++)
#pragma unroll
    for (int j = 0; j < 4; j++) acc[i][j] = (f32x4){0.f, 0.f, 0.f, 0.f};
  for (int k0 = 0; k0 < CC; k0 += BK) {
    __syncthreads();
#pragma unroll
    for (int i = 0; i < 4; i++) {
      gload16(gA + (size_t)(i * 32) * CC + k0, lA + i * 32 * BK);
      gload16(gB + (size_t)(i * 32) * CC + k0, lB + i * 32 * BK);
    }
    __syncthreads();
#pragma unroll
    for (int kh = 0; kh < 2; kh++) {
      const int rs = kh ? rs1 : rs0;
      bf16x8 af[4], bfr[4];
#pragma unroll
      for (int i = 0; i < 4; i++)
        af[i] = *(const bf16x8*)&As[(wmo + i * 16 + lrow) * BK + rs * 8];
#pragma unroll
      for (int j = 0; j < 4; j++)
        bfr[j] = *(const bf16x8*)&Bs[(wno + j * 16 + lrow) * BK + rs * 8];
#pragma unroll
      for (int i = 0; i < 4; i++)
#pragma unroll
        for (int j = 0; j < 4; j++)
          acc[i][j] = __builtin_amdgcn_mfma_f32_16x16x32_bf16(af[i], bfr[j], acc[i][j], 0, 0, 0);
    }
  }
#pragma unroll
  for (int i = 0; i < 4; i++)
#pragma unroll
    for (int j = 0; j < 4; j++)
#pragma unroll
      for (int r = 0; r < 4; r++) {
        const int row = bm + wmo + i * 16 + kgrp * 4 + r;
        const int col = bn + wno + j * 16 + lrow;
        C[(size_t)row * KNN + col] = f2bf(acc[i][j][r]);
      }
}

// ---------------- row LayerNorm over C=768 (fp32 in/out) -------------------
__global__ __launch_bounds__(256) void row_ln_kernel(
    const float* __restrict__ in, float* __restrict__ out,
    const float* __restrict__ g, const float* __restrict__ bb, float eps)
{
  const int row = blockIdx.x;
  const int tid = threadIdx.x;
  __shared__ float red[256];
  const size_t base = (size_t)row * CC;
  float x0 = in[base + tid];
  float x1 = in[base + tid + 256];
  float x2 = in[base + tid + 512];
  red[tid] = x0 + x1 + x2;
  __syncthreads();
  for (int st = 128; st > 0; st >>= 1) { if (tid < st) red[tid] += red[tid + st]; __syncthreads(); }
  float mean = red[0] * (1.0f / 768.0f);
  __syncthreads();
  float d0 = x0 - mean, d1 = x1 - mean, d2 = x2 - mean;
  red[tid] = d0 * d0 + d1 * d1 + d2 * d2;
  __syncthreads();
  for (int st = 128; st > 0; st >>= 1) { if (tid < st) red[tid] += red[tid + st]; __syncthreads(); }
  float rstd = rsqrtf(red[0] * (1.0f / 768.0f) + eps);
  out[base + tid]       = d0 * rstd * g[tid]       + bb[tid];
  out[base + tid + 256] = d1 * rstd * g[tid + 256] + bb[tid + 256];
  out[base + tid + 512] = d2 * rstd * g[tid + 512] + bb[tid + 512];
}

// ---------------- attention: 9 queries x 1024 keys per (b,h) ---------------
__global__ __launch_bounds__(256) void attn_kernel(
    const float* __restrict__ wm,       // [9][768]
    const short* __restrict__ big,      // [32768][2304] bf16 (kv | xq)
    float* __restrict__ ca)             // [32][9][768]
{
  const int b = blockIdx.x;
  const int h = blockIdx.y;
  const int tid = threadIdx.x;
  const int wave = tid >> 6, lane = tid & 63;
  __shared__ float wmh[KKK][HDD];
  __shared__ float sc[KKK][NN];
  __shared__ float part[4][KKK][HDD];
  for (int i = tid; i < KKK * HDD; i += 256) {
    int q = i >> 6, d = i & 63;
    wmh[q][d] = wm[q * CC + h * HDD + d];
  }
  __syncthreads();
  for (int n = tid; n < NN; n += 256) {
    const short* kp = &big[(size_t)(b * NN + n) * KNN + h * HDD];
    float acc[KKK];
#pragma unroll
    for (int q = 0; q < KKK; q++) acc[q] = 0.f;
    for (int d0 = 0; d0 < HDD; d0 += 8) {
      bf16x8 kv8 = *(const bf16x8*)&kp[d0];
#pragma unroll
      for (int e = 0; e < 8; e++) {
        float kf = bfbits2f(kv8[e]);
#pragma unroll
        for (int q = 0; q < KKK; q++) acc[q] += wmh[q][d0 + e] * kf;
      }
    }
#pragma unroll
    for (int q = 0; q < KKK; q++) sc[q][n] = acc[q] * 0.125f;
  }
  __syncthreads();
  for (int q = wave; q < KKK; q += 4) {
    float m = -1e30f;
#pragma unroll
    for (int i = 0; i < 16; i++) m = fmaxf(m, sc[q][lane + i * 64]);
#pragma unroll
    for (int off = 32; off > 0; off >>= 1) m = fmaxf(m, __shfl_xor(m, off));
    float s = 0.f;
#pragma unroll
    for (int i = 0; i < 16; i++) {
      float e = expf(sc[q][lane + i * 64] - m);
      sc[q][lane + i * 64] = e;
      s += e;
    }
#pragma unroll
    for (int off = 32; off > 0; off >>= 1) s += __shfl_xor(s, off);
    float inv = 1.0f / s;
#pragma unroll
    for (int i = 0; i < 16; i++) sc[q][lane + i * 64] *= inv;
  }
  __syncthreads();
  const int d = tid & 63, prt = tid >> 6;
  float acc[KKK];
#pragma unroll
  for (int q = 0; q < KKK; q++) acc[q] = 0.f;
  for (int n = prt * 256; n < prt * 256 + 256; n++) {
    float vf = bfbits2f(big[(size_t)(b * NN + n) * KNN + CC + h * HDD + d]);
#pragma unroll
    for (int q = 0; q < KKK; q++) acc[q] += sc[q][n] * vf;
  }
#pragma unroll
  for (int q = 0; q < KKK; q++) part[prt][q][d] = acc[q];
  __syncthreads();
  for (int i = tid; i < KKK * HDD; i += 256) {
    int q = i >> 6, dd = i & 63;
    ca[(size_t)(b * KKK + q) * CC + h * HDD + dd] =
        part[0][q][dd] + part[1][q][dd] + part[2][q][dd] + part[3][q][dd];
  }
}

// ---------------- proj + residual ------------------------------------------
__global__ __launch_bounds__(256) void proj_res_kernel(
    const float* __restrict__ ca,      // [288][768]
    const float* __restrict__ proj_w,  // [768][768]
    const float* __restrict__ proj_b,  // [768]
    const float* __restrict__ kern,    // [9][768]
    float* __restrict__ w1)            // [288][768]
{
  const int r0 = blockIdx.x * 2;
  const int c = blockIdx.y * 256 + threadIdx.x;
  const int tid = threadIdx.x;
  __shared__ float car[2][CC];
  for (int i = tid; i < 2 * CC; i += 256)
    car[i / CC][i % CC] = ca[(size_t)(r0 + i / CC) * CC + (i % CC)];
  __syncthreads();
  float a0 = 0.f, a1 = 0.f;
  for (int k = 0; k < CC; k++) {
    float w = proj_w[(size_t)k * CC + c];
    a0 += car[0][k] * w;
    a1 += car[1][k] * w;
  }
  const int q0 = r0 % KKK, q1 = (r0 + 1) % KKK;
  w1[(size_t)r0 * CC + c]       = a0 + proj_b[c] + kern[q0 * CC + c];
  w1[(size_t)(r0 + 1) * CC + c] = a1 + proj_b[c] + kern[q1 * CC + c];
}

// ---------------- token mixer: wave-uniform j, scalar weight loads ---------
// grid (3, 32, 8): c = bx*256+tid (one channel per lane), 192 j's per block.
// Writes partials part[jc][b][q][c] (aliased into d_out; xb dead after GEMM).
__global__ __launch_bounds__(256) void token_mix_kernel(
    const float* __restrict__ ln1,     // [288][768]
    const float* __restrict__ pm1_w,   // [9][1536]
    const float* __restrict__ pm1_b,   // [1536]
    const float* __restrict__ pm2_w,   // [1536][9]
    float* __restrict__ part)          // [8][32][9][768]
{
  const int tid = threadIdx.x;
  const int c = blockIdx.x * 256 + tid;
  const int b = blockIdx.y;
  const int jc = blockIdx.z;
  float u[KKK], o[KKK];
#pragma unroll
  for (int q = 0; q < KKK; q++) {
    u[q] = ln1[(size_t)(b * KKK + q) * CC + c];
    o[q] = 0.f;
  }
  const int j0 = jc * (PMDD / 8);
  for (int j = j0; j < j0 + PMDD / 8; j++) {
    float hs = pm1_b[j];                    // wave-uniform -> s_load
#pragma unroll
    for (int q = 0; q < KKK; q++) hs += u[q] * pm1_w[q * PMDD + j];
    float gv = gelu_f(hs);
    const float* p2 = &pm2_w[(size_t)j * KKK];
#pragma unroll
    for (int q = 0; q < KKK; q++) o[q] += gv * p2[q];
  }
  float* pp = &part[(size_t)((jc * BB + b) * KKK) * CC + c];
#pragma unroll
  for (int q = 0; q < KKK; q++) pp[(size_t)q * CC] = o[q];
}

// ---------------- token mixer reduce: w1 += sum_g part + pm2_b -------------
__global__ __launch_bounds__(256) void token_reduce_kernel(
    const float* __restrict__ part,    // [8][32][9][768]
    const float* __restrict__ pm2_b,   // [9]
    float* __restrict__ w1)            // [288][768]
{
  const int idx = blockIdx.x * 256 + threadIdx.x;   // 0..221183
  const int row = idx / CC;                         // b*9+q
  const int q = row % KKK;
  float s = 0.f;
#pragma unroll
  for (int g = 0; g < 8; g++)
    s += part[(size_t)g * BB * KKK * CC + idx];
  w1[idx] += s + pm2_b[q];
}

// ---------------- channel mixer A ------------------------------------------
__global__ __launch_bounds__(256) void chan_mix_a_kernel(
    const float* __restrict__ ln2,     // [288][768]
    const float* __restrict__ cm1_w,   // [768][1536]
    const float* __restrict__ cm1_b,   // [1536]
    float* __restrict__ h1g)           // [288][1536]
{
  const int r0 = blockIdx.x * 4;
  const int j = blockIdx.y * 256 + threadIdx.x;
  const int tid = threadIdx.x;
  __shared__ float xr[4][CC];
  for (int i = tid; i < 4 * CC; i += 256)
    xr[i / CC][i % CC] = ln2[(size_t)(r0 + i / CC) * CC + (i % CC)];
  __syncthreads();
  float a0, a1, a2, a3;
  a0 = a1 = a2 = a3 = cm1_b[j];
  for (int k = 0; k < CC; k++) {
    float w = cm1_w[(size_t)k * CMDD + j];
    a0 += xr[0][k] * w;
    a1 += xr[1][k] * w;
    a2 += xr[2][k] * w;
    a3 += xr[3][k] * w;
  }
  h1g[(size_t)(r0 + 0) * CMDD + j] = gelu_f(a0);
  h1g[(size_t)(r0 + 1) * CMDD + j] = gelu_f(a1);
  h1g[(size_t)(r0 + 2) * CMDD + j] = gelu_f(a2);
  h1g[(size_t)(r0 + 3) * CMDD + j] = gelu_f(a3);
}

// ---------------- channel mixer B ------------------------------------------
__global__ __launch_bounds__(256) void chan_mix_b_kernel(
    const float* __restrict__ h1g,     // [288][1536]
    const float* __restrict__ cm2_w,   // [1536][768]
    const float* __restrict__ cm2_b,   // [768]
    float* __restrict__ w1)
{
  const int r0 = blockIdx.x * 2;
  const int c = blockIdx.y * 256 + threadIdx.x;
  const int tid = threadIdx.x;
  __shared__ float hr[2][CMDD];
  for (int i = tid; i < 2 * CMDD; i += 256)
    hr[i / CMDD][i % CMDD] = h1g[(size_t)(r0 + i / CMDD) * CMDD + (i % CMDD)];
  __syncthreads();
  float a0 = cm2_b[c], a1 = a0;
  for (int jj = 0; jj < CMDD; jj++) {
    float w = cm2_w[(size_t)jj * CC + c];
    a0 += hr[0][jj] * w;
    a1 += hr[1][jj] * w;
  }
  w1[(size_t)r0 * CC + c]       += a0;
  w1[(size_t)(r0 + 1) * CC + c] += a1;
}

// ---------------- dynamic depthwise 3x3 conv (sliding window) --------------
__global__ __launch_bounds__(256) void conv_kernel(
    const short* __restrict__ big,   // xq (bf16) at column offset 1536
    const float* __restrict__ w1,    // [32][9][768] filters
    float* __restrict__ out)         // [32][1024][768] fp32
{
  const int cchunk = blockIdx.x;
  const int y = blockIdx.y;
  const int b = blockIdx.z;
  const int c = cchunk * 256 + threadIdx.x;
  float f[KKK];
#pragma unroll
  for (int q = 0; q < KKK; q++) f[q] = w1[(size_t)(b * KKK + q) * CC + c];
  const short* rp[3];
  bool rv[3];
#pragma unroll
  for (int ky = 0; ky < 3; ky++) {
    int yy = y + ky - 1;
    rv[ky] = (yy >= 0 && yy < 32);
    rp[ky] = big + (size_t)(b * NN + (rv[ky] ? yy : 0) * 32) * KNN + 2 * CC + c;
  }
  float c0[3] = {0.f, 0.f, 0.f}, c1[3], c2[3];
#pragma unroll
  for (int ky = 0; ky < 3; ky++) c1[ky] = rv[ky] ? bfbits2f(rp[ky][0]) : 0.f;
  float* op = &out[(size_t)(b * NN + y * 32) * CC + c];
  for (int x = 0; x < 32; x++) {
#pragma unroll
    for (int ky = 0; ky < 3; ky++)
      c2[ky] = (x + 1 < 32 && rv[ky]) ? bfbits2f(rp[ky][(size_t)(x + 1) * KNN]) : 0.f;
    float acc = 0.f;
#pragma unroll
    for (int ky = 0; ky < 3; ky++)
      acc += f[ky * 3 + 0] * c0[ky] + f[ky * 3 + 1] * c1[ky] + f[ky * 3 + 2] * c2[ky];
    op[(size_t)x * CC] = acc;
#pragma unroll
    for (int ky = 0; ky < 3; ky++) { c0[ky] = c1[ky]; c1[ky] = c2[ky]; }
  }
}

// ---------------------------------------------------------------------------
extern "C" void kernel_launch(void* const* d_in, const int* in_sizes, int n_in,
                              void* d_out, int out_size, void* d_ws, size_t ws_size,
                              hipStream_t stream) {
  (void)in_sizes; (void)n_in; (void)out_size; (void)ws_size;
  const float* x       = (const float*)d_in[0];
  const float* kern    = (const float*)d_in[3];
  const float* ln_g    = (const float*)d_in[4];
  const float* ln_b    = (const float*)d_in[5];
  const float* kv_w    = (const float*)d_in[6];
  const float* proj_w  = (const float*)d_in[7];
  const float* proj_b  = (const float*)d_in[8];
  const float* projq_w = (const float*)d_in[9];
  const float* n1_g    = (const float*)d_in[10];
  const float* n1_b    = (const float*)d_in[11];
  const float* n2_g    = (const float*)d_in[12];
  const float* n2_b    = (const float*)d_in[13];
  const float* pm1_w   = (const float*)d_in[14];
  const float* pm1_b   = (const float*)d_in[15];
  const float* pm2_w   = (const float*)d_in[16];
  const float* pm2_b   = (const float*)d_in[17];
  const float* cm1_w   = (const float*)d_in[18];
  const float* cm1_b   = (const float*)d_in[19];
  const float* cm2_w   = (const float*)d_in[20];
  const float* cm2_b   = (const float*)d_in[21];
  float* out = (float*)d_out;

  uint8_t* ws = (uint8_t*)d_ws;
  short* Wt  = (short*)(ws);                    // 2304*768*2   = 3,538,944
  float* h1g = (float*)(ws);                    // ALIAS (Wt dead after GEMM)
  short* big = (short*)(ws + 3538944);          // 32768*2304*2 = 150,994,944
  float* wm  = (float*)(ws + 154533888);        // 27,648
  float* ca  = (float*)(ws + 154561536);        // 884,736
  float* w1  = (float*)(ws + 155446272);        // 884,736
  float* lnb = (float*)(ws + 156331008);        // 884,736 -> total 157,215,744 B

  // d_out doubles as scratch before conv: xb (bf16 x) then token-mix partials.
  short* xb = (short*)d_out;
  float* tpart = (float*)d_out;                 // [8][32][9][768] = 7,077,888 B

  xbf_kernel<<<dim3(MM * CC / (256 * 8)), 256, 0, stream>>>(x, xb);
  transpose_w_kernel<<<dim3(KNN / 32, CC / 32), 256, 0, stream>>>(kv_w, projq_w, Wt);
  gemm_bt_kernel<<<dim3((MM / 128) * (KNN / 128)), 256, 0, stream>>>(xb, Wt, big);
  row_ln_kernel<<<dim3(KKK), 256, 0, stream>>>(kern, wm, ln_g, ln_b, 1e-6f);
  attn_kernel<<<dim3(BB, NHH), 256, 0, stream>>>(wm, big, ca);
  proj_res_kernel<<<dim3(144, 3), 256, 0, stream>>>(ca, proj_w, proj_b, kern, w1);
  row_ln_kernel<<<dim3(BB * KKK), 256, 0, stream>>>(w1, lnb, n1_g, n1_b, 1e-5f);
  token_mix_kernel<<<dim3(3, 32, 8), 256, 0, stream>>>(lnb, pm1_w, pm1_b, pm2_w, tpart);
  token_reduce_kernel<<<dim3(864), 256, 0, stream>>>(tpart, pm2_b, w1);
  row_ln_kernel<<<dim3(BB * KKK), 256, 0, stream>>>(w1, lnb, n2_g, n2_b, 1e-5f);
  chan_mix_a_kernel<<<dim3(72, 6), 256, 0, stream>>>(lnb, cm1_w, cm1_b, h1g);
  chan_mix_b_kernel<<<dim3(144, 3), 256, 0, stream>>>(h1g, cm2_w, cm2_b, w1);
  conv_kernel<<<dim3(3, 32, 32), 256, 0, stream>>>(big, w1, out);
}

// Round 7
// 612.176 us; speedup vs baseline: 2.4723x; 1.0054x over previous
//
#include <hip/hip_runtime.h>
#include <hip/hip_bf16.h>
#include <cstdint>
#include <cstddef>

typedef __attribute__((ext_vector_type(8))) short bf16x8;
typedef __attribute__((ext_vector_type(4))) float f32x4;

#define BB 32
#define NN 1024
#define CC 768
#define NHH 12
#define HDD 64
#define KKK 9
#define MM (BB * NN)   /* 32768 */
#define KNN (3 * CC)   /* 2304 = 2C (kv) + C (xq) */
#define PMDD 1536
#define CMDD 1536
#define GBK 64

__device__ __forceinline__ float bfbits2f(short s) {
  union { uint32_t u; float f; } cv;
  cv.u = ((uint32_t)(uint16_t)s) << 16;
  return cv.f;
}
__device__ __forceinline__ short f2bf(float f) {
  union { float f; uint32_t u; } cv;
  cv.f = f;
  uint32_t u = cv.u;
  uint32_t r = (u + 0x7fffu + ((u >> 16) & 1u)) >> 16;
  return (short)r;
}
__device__ __forceinline__ float gelu_f(float x) {
  return 0.5f * x * (1.0f + erff(x * 0.7071067811865476f));
}

typedef const __attribute__((address_space(1))) uint32_t* gp1_t;
typedef __attribute__((address_space(3))) uint32_t* lp3_t;
__device__ __forceinline__ void gload16(const short* g, const short* l) {
  __builtin_amdgcn_global_load_lds((gp1_t)(uintptr_t)(const void*)g,
                                   (lp3_t)(uint32_t)(uintptr_t)(const void*)l,
                                   16, 0, 0);
}

// ---------------- prep: x->bf16  +  weight transpose -----------------------
__global__ __launch_bounds__(256) void prep_kernel(
    const float* __restrict__ x, short* __restrict__ xb,
    const float* __restrict__ kv_w, const float* __restrict__ projq_w,
    short* __restrict__ Wt)
{
  if (blockIdx.x < MM * CC / (256 * 8)) {
    const int i = (blockIdx.x * 256 + threadIdx.x) * 8;
    f32x4 a = *(const f32x4*)&x[i];
    f32x4 b = *(const f32x4*)&x[i + 4];
    bf16x8 o;
#pragma unroll
    for (int e = 0; e < 4; e++) { o[e] = f2bf(a[e]); o[e + 4] = f2bf(b[e]); }
    *(bf16x8*)&xb[i] = o;
    return;
  }
  __shared__ float tile[32][33];
  const int b2 = blockIdx.x - MM * CC / (256 * 8);
  const int j0 = (b2 % 72) * 32;
  const int c0 = (b2 / 72) * 32;
  const int tx = threadIdx.x & 31, ty = threadIdx.x >> 5;
  const float* src; int ldj, jj;
  if (j0 < 2 * CC) { src = kv_w; ldj = 2 * CC; jj = j0; }
  else             { src = projq_w; ldj = CC; jj = j0 - 2 * CC; }
#pragma unroll
  for (int r = 0; r < 4; r++) {
    int cl = ty + r * 8;
    tile[cl][tx] = src[(size_t)(c0 + cl) * ldj + jj + tx];
  }
  __syncthreads();
#pragma unroll
  for (int r = 0; r < 4; r++) {
    int jl = ty + r * 8;
    Wt[(size_t)(j0 + jl) * CC + c0 + tx] = f2bf(tile[tx][jl]);
  }
}

// ---------------- fused GEMM: 256x256 tile, dbuf issue-early ---------------
__global__ __launch_bounds__(512, 1) void gemm256_kernel(
    const short* __restrict__ A,     // [MM][768] bf16
    const short* __restrict__ Bt,    // [2304][768] bf16 (B^T)
    short* __restrict__ C)           // [MM][2304] bf16
{
  __shared__ short As[2][256 * GBK];   // 64 KB
  __shared__ short Bs[2][256 * GBK];   // 64 KB
  const int tid = threadIdx.x;
  const int wave = tid >> 6, lane = tid & 63;
  // XCD swizzle: 1152 = 8 * 144 (bijective), n-fastest
  const int lid = blockIdx.x;
  const int wid = (lid & 7) * 144 + (lid >> 3);
  const int bn = (wid % 9) * 256;
  const int bm = (wid / 9) * 256;
  const int wm2 = wave >> 2;         // 0..1
  const int wn4 = wave & 3;          // 0..3
  const int lrow = lane & 15;
  const int kgrp = lane >> 4;        // 0..3
  // staging: 8 slots/row, rounds of 64 rows
  const int sr = tid >> 3;           // 0..63
  const int ss = tid & 7;            // slot 0..7
  f32x4 acc[8][4];
#pragma unroll
  for (int i = 0; i < 8; i++)
#pragma unroll
    for (int j = 0; j < 4; j++) acc[i][j] = (f32x4){0.f, 0.f, 0.f, 0.f};

  // frag read slots (XOR swizzle, row period 8)
  const int asw = lrow & 7;

#define STAGE256(buf, k0)                                                      \
  {                                                                            \
    _Pragma("unroll")                                                          \
    for (int i = 0; i < 4; i++) {                                              \
      const int r = i * 64 + sr;                                               \
      const int sg = ss ^ (r & 7);                                             \
      gload16(A + (size_t)(bm + r) * CC + (k0) + sg * 8,                       \
              &As[buf][r * GBK + ss * 8]);                                     \
      gload16(Bt + (size_t)(bn + r) * CC + (k0) + sg * 8,                      \
              &Bs[buf][r * GBK + ss * 8]);                                     \
    }                                                                          \
  }

  int cur = 0;
  STAGE256(0, 0);
  __syncthreads();
  for (int t = 0; t < 12; ++t) {
    if (t < 11) STAGE256(cur ^ 1, (t + 1) * GBK);
#pragma unroll
    for (int ks = 0; ks < 2; ks++) {
      const int slot = (4 * ks + kgrp) ^ asw;
      bf16x8 af[8], bfr[4];
#pragma unroll
      for (int m = 0; m < 8; m++)
        af[m] = *(const bf16x8*)&As[cur][(wm2 * 128 + m * 16 + lrow) * GBK + slot * 8];
#pragma unroll
      for (int n = 0; n < 4; n++)
        bfr[n] = *(const bf16x8*)&Bs[cur][(wn4 * 64 + n * 16 + lrow) * GBK + slot * 8];
      __builtin_amdgcn_s_setprio(1);
#pragma unroll
      for (int m = 0; m < 8; m++)
#pragma unroll
        for (int n = 0; n < 4; n++)
          acc[m][n] = __builtin_amdgcn_mfma_f32_16x16x32_bf16(af[m], bfr[n], acc[m][n], 0, 0, 0);
      __builtin_amdgcn_s_setprio(0);
    }
    __syncthreads();
    cur ^= 1;
  }
#pragma unroll
  for (int m = 0; m < 8; m++)
#pragma unroll
    for (int n = 0; n < 4; n++)
#pragma unroll
      for (int r = 0; r < 4; r++) {
        const int row = bm + wm2 * 128 + m * 16 + kgrp * 4 + r;
        const int col = bn + wn4 * 64 + n * 16 + lrow;
        C[(size_t)row * KNN + col] = f2bf(acc[m][n][r]);
      }
#undef STAGE256
}

// ---------------- row LayerNorm over C=768 (fp32 in/out) -------------------
__global__ __launch_bounds__(256) void row_ln_kernel(
    const float* __restrict__ in, float* __restrict__ out,
    const float* __restrict__ g, const float* __restrict__ bb, float eps)
{
  const int row = blockIdx.x;
  const int tid = threadIdx.x;
  __shared__ float red[256];
  const size_t base = (size_t)row * CC;
  float x0 = in[base + tid];
  float x1 = in[base + tid + 256];
  float x2 = in[base + tid + 512];
  red[tid] = x0 + x1 + x2;
  __syncthreads();
  for (int st = 128; st > 0; st >>= 1) { if (tid < st) red[tid] += red[tid + st]; __syncthreads(); }
  float mean = red[0] * (1.0f / 768.0f);
  __syncthreads();
  float d0 = x0 - mean, d1 = x1 - mean, d2 = x2 - mean;
  red[tid] = d0 * d0 + d1 * d1 + d2 * d2;
  __syncthreads();
  for (int st = 128; st > 0; st >>= 1) { if (tid < st) red[tid] += red[tid + st]; __syncthreads(); }
  float rstd = rsqrtf(red[0] * (1.0f / 768.0f) + eps);
  out[base + tid]       = d0 * rstd * g[tid]       + bb[tid];
  out[base + tid + 256] = d1 * rstd * g[tid + 256] + bb[tid + 256];
  out[base + tid + 512] = d2 * rstd * g[tid + 512] + bb[tid + 512];
}

// ---------------- attention: 9 queries x 1024 keys per (b,h) ---------------
__global__ __launch_bounds__(256) void attn_kernel(
    const float* __restrict__ wm,       // [9][768]
    const short* __restrict__ big,      // [32768][2304] bf16 (kv | xq)
    float* __restrict__ ca)             // [32][9][768]
{
  const int b = blockIdx.x;
  const int h = blockIdx.y;
  const int tid = threadIdx.x;
  const int wave = tid >> 6, lane = tid & 63;
  __shared__ float wmh[KKK][HDD];
  __shared__ float sc[KKK][NN];
  __shared__ float part[4][KKK][HDD];
  for (int i = tid; i < KKK * HDD; i += 256) {
    int q = i >> 6, d = i & 63;
    wmh[q][d] = wm[q * CC + h * HDD + d];
  }
  __syncthreads();
  for (int n = tid; n < NN; n += 256) {
    const short* kp = &big[(size_t)(b * NN + n) * KNN + h * HDD];
    float acc[KKK];
#pragma unroll
    for (int q = 0; q < KKK; q++) acc[q] = 0.f;
    for (int d0 = 0; d0 < HDD; d0 += 8) {
      bf16x8 kv8 = *(const bf16x8*)&kp[d0];
#pragma unroll
      for (int e = 0; e < 8; e++) {
        float kf = bfbits2f(kv8[e]);
#pragma unroll
        for (int q = 0; q < KKK; q++) acc[q] += wmh[q][d0 + e] * kf;
      }
    }
#pragma unroll
    for (int q = 0; q < KKK; q++) sc[q][n] = acc[q] * 0.125f;
  }
  __syncthreads();
  for (int q = wave; q < KKK; q += 4) {
    float m = -1e30f;
#pragma unroll
    for (int i = 0; i < 16; i++) m = fmaxf(m, sc[q][lane + i * 64]);
#pragma unroll
    for (int off = 32; off > 0; off >>= 1) m = fmaxf(m, __shfl_xor(m, off));
    float s = 0.f;
#pragma unroll
    for (int i = 0; i < 16; i++) {
      float e = expf(sc[q][lane + i * 64] - m);
      sc[q][lane + i * 64] = e;
      s += e;
    }
#pragma unroll
    for (int off = 32; off > 0; off >>= 1) s += __shfl_xor(s, off);
    float inv = 1.0f / s;
#pragma unroll
    for (int i = 0; i < 16; i++) sc[q][lane + i * 64] *= inv;
  }
  __syncthreads();
  const int d = tid & 63, prt = tid >> 6;
  float acc[KKK];
#pragma unroll
  for (int q = 0; q < KKK; q++) acc[q] = 0.f;
  for (int n = prt * 256; n < prt * 256 + 256; n++) {
    float vf = bfbits2f(big[(size_t)(b * NN + n) * KNN + CC + h * HDD + d]);
#pragma unroll
    for (int q = 0; q < KKK; q++) acc[q] += sc[q][n] * vf;
  }
#pragma unroll
  for (int q = 0; q < KKK; q++) part[prt][q][d] = acc[q];
  __syncthreads();
  for (int i = tid; i < KKK * HDD; i += 256) {
    int q = i >> 6, dd = i & 63;
    ca[(size_t)(b * KKK + q) * CC + h * HDD + dd] =
        part[0][q][dd] + part[1][q][dd] + part[2][q][dd] + part[3][q][dd];
  }
}

// ---------------- proj + residual + LN1 (fused, block per row) -------------
__global__ __launch_bounds__(256) void proj_ln_kernel(
    const float* __restrict__ ca,      // [288][768]
    const float* __restrict__ proj_w,  // [768][768]
    const float* __restrict__ proj_b,  // [768]
    const float* __restrict__ kern,    // [9][768]
    const float* __restrict__ g, const float* __restrict__ bb,
    float* __restrict__ w1,            // [288][768]
    float* __restrict__ lnb)           // [288][768]
{
  const int row = blockIdx.x;
  const int q = row % KKK;
  const int tid = threadIdx.x;
  __shared__ float car[CC];
  __shared__ float red[256];
  for (int i = tid; i < CC; i += 256) car[i] = ca[(size_t)row * CC + i];
  __syncthreads();
  float a0 = 0.f, a1 = 0.f, a2 = 0.f;
  for (int k = 0; k < CC; k++) {
    float av = car[k];
    const float* pw = &proj_w[(size_t)k * CC];
    a0 += av * pw[tid];
    a1 += av * pw[tid + 256];
    a2 += av * pw[tid + 512];
  }
  float v0 = a0 + proj_b[tid]       + kern[q * CC + tid];
  float v1 = a1 + proj_b[tid + 256] + kern[q * CC + tid + 256];
  float v2 = a2 + proj_b[tid + 512] + kern[q * CC + tid + 512];
  const size_t base = (size_t)row * CC;
  w1[base + tid] = v0; w1[base + tid + 256] = v1; w1[base + tid + 512] = v2;
  // LN1
  red[tid] = v0 + v1 + v2;
  __syncthreads();
  for (int st = 128; st > 0; st >>= 1) { if (tid < st) red[tid] += red[tid + st]; __syncthreads(); }
  float mean = red[0] * (1.0f / 768.0f);
  __syncthreads();
  float d0 = v0 - mean, d1 = v1 - mean, d2 = v2 - mean;
  red[tid] = d0 * d0 + d1 * d1 + d2 * d2;
  __syncthreads();
  for (int st = 128; st > 0; st >>= 1) { if (tid < st) red[tid] += red[tid + st]; __syncthreads(); }
  float rstd = rsqrtf(red[0] * (1.0f / 768.0f) + 1e-5f);
  lnb[base + tid]       = d0 * rstd * g[tid]       + bb[tid];
  lnb[base + tid + 256] = d1 * rstd * g[tid + 256] + bb[tid + 256];
  lnb[base + tid + 512] = d2 * rstd * g[tid + 512] + bb[tid + 512];
}

// ---------------- token mixer: wave-uniform j, scalar weight loads ---------
__global__ __launch_bounds__(256) void token_mix_kernel(
    const float* __restrict__ ln1,     // [288][768]
    const float* __restrict__ pm1_w,   // [9][1536]
    const float* __restrict__ pm1_b,   // [1536]
    const float* __restrict__ pm2_w,   // [1536][9]
    float* __restrict__ part)          // [8][32][9][768]
{
  const int tid = threadIdx.x;
  const int c = blockIdx.x * 256 + tid;
  const int b = blockIdx.y;
  const int jc = blockIdx.z;
  float u[KKK], o[KKK];
#pragma unroll
  for (int q = 0; q < KKK; q++) {
    u[q] = ln1[(size_t)(b * KKK + q) * CC + c];
    o[q] = 0.f;
  }
  const int j0 = jc * (PMDD / 8);
  for (int j = j0; j < j0 + PMDD / 8; j++) {
    float hs = pm1_b[j];
#pragma unroll
    for (int q = 0; q < KKK; q++) hs += u[q] * pm1_w[q * PMDD + j];
    float gv = gelu_f(hs);
    const float* p2 = &pm2_w[(size_t)j * KKK];
#pragma unroll
    for (int q = 0; q < KKK; q++) o[q] += gv * p2[q];
  }
  float* pp = &part[(size_t)((jc * BB + b) * KKK) * CC + c];
#pragma unroll
  for (int q = 0; q < KKK; q++) pp[(size_t)q * CC] = o[q];
}

// ---------------- token reduce + LN2 (fused, block per row) ----------------
__global__ __launch_bounds__(256) void token_reduce_ln_kernel(
    const float* __restrict__ part,    // [8][32][9][768]
    const float* __restrict__ pm2_b,   // [9]
    const float* __restrict__ g, const float* __restrict__ bb,
    float* __restrict__ w1,            // [288][768] (in/out)
    float* __restrict__ lnb)           // [288][768]
{
  const int row = blockIdx.x;
  const int q = row % KKK;
  const int tid = threadIdx.x;
  __shared__ float red[256];
  const size_t base = (size_t)row * CC;
  float v[3];
#pragma unroll
  for (int j = 0; j < 3; j++) {
    const int c = tid + j * 256;
    float s = 0.f;
#pragma unroll
    for (int gg = 0; gg < 8; gg++)
      s += part[(size_t)gg * BB * KKK * CC + base + c];
    v[j] = w1[base + c] + s + pm2_b[q];
    w1[base + c] = v[j];
  }
  red[tid] = v[0] + v[1] + v[2];
  __syncthreads();
  for (int st = 128; st > 0; st >>= 1) { if (tid < st) red[tid] += red[tid + st]; __syncthreads(); }
  float mean = red[0] * (1.0f / 768.0f);
  __syncthreads();
  float d0 = v[0] - mean, d1 = v[1] - mean, d2 = v[2] - mean;
  red[tid] = d0 * d0 + d1 * d1 + d2 * d2;
  __syncthreads();
  for (int st = 128; st > 0; st >>= 1) { if (tid < st) red[tid] += red[tid + st]; __syncthreads(); }
  float rstd = rsqrtf(red[0] * (1.0f / 768.0f) + 1e-5f);
  lnb[base + tid]       = d0 * rstd * g[tid]       + bb[tid];
  lnb[base + tid + 256] = d1 * rstd * g[tid + 256] + bb[tid + 256];
  lnb[base + tid + 512] = d2 * rstd * g[tid + 512] + bb[tid + 512];
}

// ---------------- channel mixer A ------------------------------------------
__global__ __launch_bounds__(256) void chan_mix_a_kernel(
    const float* __restrict__ ln2,     // [288][768]
    const float* __restrict__ cm1_w,   // [768][1536]
    const float* __restrict__ cm1_b,   // [1536]
    float* __restrict__ h1g)           // [288][1536]
{
  const int r0 = blockIdx.x * 4;
  const int j = blockIdx.y * 256 + threadIdx.x;
  const int tid = threadIdx.x;
  __shared__ float xr[4][CC];
  for (int i = tid; i < 4 * CC; i += 256)
    xr[i / CC][i % CC] = ln2[(size_t)(r0 + i / CC) * CC + (i % CC)];
  __syncthreads();
  float a0, a1, a2, a3;
  a0 = a1 = a2 = a3 = cm1_b[j];
  for (int k = 0; k < CC; k++) {
    float w = cm1_w[(size_t)k * CMDD + j];
    a0 += xr[0][k] * w;
    a1 += xr[1][k] * w;
    a2 += xr[2][k] * w;
    a3 += xr[3][k] * w;
  }
  h1g[(size_t)(r0 + 0) * CMDD + j] = gelu_f(a0);
  h1g[(size_t)(r0 + 1) * CMDD + j] = gelu_f(a1);
  h1g[(size_t)(r0 + 2) * CMDD + j] = gelu_f(a2);
  h1g[(size_t)(r0 + 3) * CMDD + j] = gelu_f(a3);
}

// ---------------- channel mixer B ------------------------------------------
__global__ __launch_bounds__(256) void chan_mix_b_kernel(
    const float* __restrict__ h1g,     // [288][1536]
    const float* __restrict__ cm2_w,   // [1536][768]
    const float* __restrict__ cm2_b,   // [768]
    float* __restrict__ w1)
{
  const int r0 = blockIdx.x * 2;
  const int c = blockIdx.y * 256 + threadIdx.x;
  const int tid = threadIdx.x;
  __shared__ float hr[2][CMDD];
  for (int i = tid; i < 2 * CMDD; i += 256)
    hr[i / CMDD][i % CMDD] = h1g[(size_t)(r0 + i / CMDD) * CMDD + (i % CMDD)];
  __syncthreads();
  float a0 = cm2_b[c], a1 = a0;
  for (int jj = 0; jj < CMDD; jj++) {
    float w = cm2_w[(size_t)jj * CC + c];
    a0 += hr[0][jj] * w;
    a1 += hr[1][jj] * w;
  }
  w1[(size_t)r0 * CC + c]       += a0;
  w1[(size_t)(r0 + 1) * CC + c] += a1;
}

// ---------------- dynamic depthwise 3x3 conv (sliding window) --------------
__global__ __launch_bounds__(256) void conv_kernel(
    const short* __restrict__ big,   // xq (bf16) at column offset 1536
    const float* __restrict__ w1,    // [32][9][768] filters
    float* __restrict__ out)         // [32][1024][768] fp32
{
  const int cchunk = blockIdx.x;
  const int y = blockIdx.y;
  const int b = blockIdx.z;
  const int c = cchunk * 256 + threadIdx.x;
  float f[KKK];
#pragma unroll
  for (int q = 0; q < KKK; q++) f[q] = w1[(size_t)(b * KKK + q) * CC + c];
  const short* rp[3];
  bool rv[3];
#pragma unroll
  for (int ky = 0; ky < 3; ky++) {
    int yy = y + ky - 1;
    rv[ky] = (yy >= 0 && yy < 32);
    rp[ky] = big + (size_t)(b * NN + (rv[ky] ? yy : 0) * 32) * KNN + 2 * CC + c;
  }
  float c0[3] = {0.f, 0.f, 0.f}, c1[3], c2[3];
#pragma unroll
  for (int ky = 0; ky < 3; ky++) c1[ky] = rv[ky] ? bfbits2f(rp[ky][0]) : 0.f;
  float* op = &out[(size_t)(b * NN + y * 32) * CC + c];
  for (int x = 0; x < 32; x++) {
#pragma unroll
    for (int ky = 0; ky < 3; ky++)
      c2[ky] = (x + 1 < 32 && rv[ky]) ? bfbits2f(rp[ky][(size_t)(x + 1) * KNN]) : 0.f;
    float acc = 0.f;
#pragma unroll
    for (int ky = 0; ky < 3; ky++)
      acc += f[ky * 3 + 0] * c0[ky] + f[ky * 3 + 1] * c1[ky] + f[ky * 3 + 2] * c2[ky];
    op[(size_t)x * CC] = acc;
#pragma unroll
    for (int ky = 0; ky < 3; ky++) { c0[ky] = c1[ky]; c1[ky] = c2[ky]; }
  }
}

// ---------------------------------------------------------------------------
extern "C" void kernel_launch(void* const* d_in, const int* in_sizes, int n_in,
                              void* d_out, int out_size, void* d_ws, size_t ws_size,
                              hipStream_t stream) {
  (void)in_sizes; (void)n_in; (void)out_size; (void)ws_size;
  const float* x       = (const float*)d_in[0];
  const float* kern    = (const float*)d_in[3];
  const float* ln_g    = (const float*)d_in[4];
  const float* ln_b    = (const float*)d_in[5];
  const float* kv_w    = (const float*)d_in[6];
  const float* proj_w  = (const float*)d_in[7];
  const float* proj_b  = (const float*)d_in[8];
  const float* projq_w = (const float*)d_in[9];
  const float* n1_g    = (const float*)d_in[10];
  const float* n1_b    = (const float*)d_in[11];
  const float* n2_g    = (const float*)d_in[12];
  const float* n2_b    = (const float*)d_in[13];
  const float* pm1_w   = (const float*)d_in[14];
  const float* pm1_b   = (const float*)d_in[15];
  const float* pm2_w   = (const float*)d_in[16];
  const float* pm2_b   = (const float*)d_in[17];
  const float* cm1_w   = (const float*)d_in[18];
  const float* cm1_b   = (const float*)d_in[19];
  const float* cm2_w   = (const float*)d_in[20];
  const float* cm2_b   = (const float*)d_in[21];
  float* out = (float*)d_out;

  uint8_t* ws = (uint8_t*)d_ws;
  short* Wt  = (short*)(ws);                    // 2304*768*2   = 3,538,944
  float* h1g = (float*)(ws);                    // ALIAS (Wt dead after GEMM)
  short* big = (short*)(ws + 3538944);          // 32768*2304*2 = 150,994,944
  float* wm  = (float*)(ws + 154533888);        // 27,648
  float* ca  = (float*)(ws + 154561536);        // 884,736
  float* w1  = (float*)(ws + 155446272);        // 884,736
  float* lnb = (float*)(ws + 156331008);        // 884,736 -> total 157,215,744 B

  // d_out doubles as scratch before conv: xb (bf16 x) then token-mix partials.
  short* xb = (short*)d_out;
  float* tpart = (float*)d_out;                 // [8][32][9][768] = 7,077,888 B

  prep_kernel<<<dim3(MM * CC / (256 * 8) + 72 * 24), 256, 0, stream>>>(
      x, xb, kv_w, projq_w, Wt);
  gemm256_kernel<<<dim3((MM / 256) * (KNN / 256)), 512, 0, stream>>>(xb, Wt, big);
  row_ln_kernel<<<dim3(KKK), 256, 0, stream>>>(kern, wm, ln_g, ln_b, 1e-6f);
  attn_kernel<<<dim3(BB, NHH), 256, 0, stream>>>(wm, big, ca);
  proj_ln_kernel<<<dim3(BB * KKK), 256, 0, stream>>>(ca, proj_w, proj_b, kern,
                                                     n1_g, n1_b, w1, lnb);
  token_mix_kernel<<<dim3(3, 32, 8), 256, 0, stream>>>(lnb, pm1_w, pm1_b, pm2_w, tpart);
  token_reduce_ln_kernel<<<dim3(BB * KKK), 256, 0, stream>>>(tpart, pm2_b,
                                                             n2_g, n2_b, w1, lnb);
  chan_mix_a_kernel<<<dim3(72, 6), 256, 0, stream>>>(lnb, cm1_w, cm1_b, h1g);
  chan_mix_b_kernel<<<dim3(144, 3), 256, 0, stream>>>(h1g, cm2_w, cm2_b, w1);
  conv_kernel<<<dim3(3, 32, 32), 256, 0, stream>>>(big, w1, out);
}

// Round 8
// 506.348 us; speedup vs baseline: 2.9890x; 1.2090x over previous
//
#include <hip/hip_runtime.h>
#include <hip/hip_bf16.h>
#include <cstdint>
#include <cstddef>

typedef __attribute__((ext_vector_type(8))) short bf16x8;
typedef __attribute__((ext_vector_type(4))) float f32x4;

#define BB 32
#define NN 1024
#define CC 768
#define NHH 12
#define HDD 64
#define KKK 9
#define MM (BB * NN)   /* 32768 */
#define KNN (3 * CC)   /* 2304 = 2C (kv) + C (xq) */
#define PMDD 1536
#define CMDD 1536
#define BK 64

__device__ __forceinline__ float bfbits2f(short s) {
  union { uint32_t u; float f; } cv;
  cv.u = ((uint32_t)(uint16_t)s) << 16;
  return cv.f;
}
__device__ __forceinline__ short f2bf(float f) {
  union { float f; uint32_t u; } cv;
  cv.f = f;
  uint32_t u = cv.u;
  uint32_t r = (u + 0x7fffu + ((u >> 16) & 1u)) >> 16;
  return (short)r;
}
__device__ __forceinline__ float gelu_f(float x) {
  return 0.5f * x * (1.0f + erff(x * 0.7071067811865476f));
}

typedef const __attribute__((address_space(1))) uint32_t* gp1_t;
typedef __attribute__((address_space(3))) uint32_t* lp3_t;
__device__ __forceinline__ void gload16(const short* g, const short* l) {
  __builtin_amdgcn_global_load_lds((gp1_t)(uintptr_t)(const void*)g,
                                   (lp3_t)(uint32_t)(uintptr_t)(const void*)l,
                                   16, 0, 0);
}

// ---------------- prep: x->bf16  +  Wt (big-GEMM weight) transpose ---------
__global__ __launch_bounds__(256) void prep_kernel(
    const float* __restrict__ x, short* __restrict__ xb,
    const float* __restrict__ kv_w, const float* __restrict__ projq_w,
    short* __restrict__ Wt)
{
  if (blockIdx.x < MM * CC / (256 * 8)) {
    const int i = (blockIdx.x * 256 + threadIdx.x) * 8;
    f32x4 a = *(const f32x4*)&x[i];
    f32x4 b = *(const f32x4*)&x[i + 4];
    bf16x8 o;
#pragma unroll
    for (int e = 0; e < 4; e++) { o[e] = f2bf(a[e]); o[e + 4] = f2bf(b[e]); }
    *(bf16x8*)&xb[i] = o;
    return;
  }
  __shared__ float tile[32][33];
  const int b2 = blockIdx.x - MM * CC / (256 * 8);
  const int j0 = (b2 % 72) * 32;
  const int c0 = (b2 / 72) * 32;
  const int tx = threadIdx.x & 31, ty = threadIdx.x >> 5;
  const float* src; int ldj, jj;
  if (j0 < 2 * CC) { src = kv_w; ldj = 2 * CC; jj = j0; }
  else             { src = projq_w; ldj = CC; jj = j0 - 2 * CC; }
#pragma unroll
  for (int r = 0; r < 4; r++) {
    int cl = ty + r * 8;
    tile[cl][tx] = src[(size_t)(c0 + cl) * ldj + jj + tx];
  }
  __syncthreads();
#pragma unroll
  for (int r = 0; r < 4; r++) {
    int jl = ty + r * 8;
    Wt[(size_t)(j0 + jl) * CC + c0 + tx] = f2bf(tile[tx][jl]);
  }
}

// ---------------- wtrans2: bf16 transposes of proj_w, cm1_w, cm2_w ---------
// (runs after big GEMM; destinations live in dead d_out scratch)
__global__ __launch_bounds__(256) void wtrans2_kernel(
    const float* __restrict__ proj_w,  // [768][768]
    const float* __restrict__ cm1_w,   // [768][1536]
    const float* __restrict__ cm2_w,   // [1536][768]
    short* __restrict__ WpT,           // [768][768]
    short* __restrict__ Wc1T,          // [1536][768]
    short* __restrict__ Wc2T)          // [768][1536]
{
  __shared__ float tile[32][33];
  int b = blockIdx.x;
  const float* src; short* dst; int ldj, ldc, j0, c0;
  if (b < 576)        { src = proj_w; dst = WpT;  ldj = 768;  ldc = 768;
                        j0 = (b % 24) * 32; c0 = (b / 24) * 32; }
  else if (b < 1728)  { b -= 576; src = cm1_w; dst = Wc1T; ldj = 1536; ldc = 768;
                        j0 = (b % 48) * 32; c0 = (b / 48) * 32; }
  else                { b -= 1728; src = cm2_w; dst = Wc2T; ldj = 768; ldc = 1536;
                        j0 = (b % 24) * 32; c0 = (b / 24) * 32; }
  const int tx = threadIdx.x & 31, ty = threadIdx.x >> 5;
#pragma unroll
  for (int r = 0; r < 4; r++) {
    int cl = ty + r * 8;
    tile[cl][tx] = src[(size_t)(c0 + cl) * ldj + j0 + tx];
  }
  __syncthreads();
#pragma unroll
  for (int r = 0; r < 4; r++) {
    int jl = ty + r * 8;
    dst[(size_t)(j0 + jl) * ldc + c0 + tx] = f2bf(tile[tx][jl]);
  }
}

// ---------------- big GEMM: 128x128, BK=64, swizzled (round-6 proven) ------
__global__ __launch_bounds__(256) void gemm_bt_kernel(
    const short* __restrict__ A,     // [MM][768] bf16
    const short* __restrict__ Bt,    // [2304][768] bf16 (B^T)
    short* __restrict__ C)           // [MM][2304] bf16
{
  __shared__ short As[128 * BK];
  __shared__ short Bs[128 * BK];
  const int tid = threadIdx.x;
  const int wave = tid >> 6, lane = tid & 63;
  const int lid = blockIdx.x;
  const int wid = (lid & 7) * 576 + (lid >> 3);
  const int bn = (wid % 18) * 128;
  const int bm = (wid / 18) * 128;
  const int wmo = (wave >> 1) * 64;
  const int wno = (wave & 1) * 64;
  const int lrow = lane & 15;
  const int kgrp = lane >> 4;
  const int sr = tid >> 3;
  const int ss = tid & 7;
  const int slotG = ss ^ (sr & 7);
  const short* gA = A + (size_t)(bm + sr) * CC + slotG * 8;
  const short* gB = Bt + (size_t)(bn + sr) * CC + slotG * 8;
  const short* lA = &As[sr * BK + ss * 8];
  const short* lB = &Bs[sr * BK + ss * 8];
  const int rs0 = kgrp ^ (lrow & 7);
  const int rs1 = (4 + kgrp) ^ (lrow & 7);
  f32x4 acc[4][4];
#pragma unroll
  for (int i = 0; i < 4; i++)
#pragma unroll
    for (int j = 0; j < 4; j++) acc[i][j] = (f32x4){0.f, 0.f, 0.f, 0.f};
  for (int k0 = 0; k0 < CC; k0 += BK) {
    __syncthreads();
#pragma unroll
    for (int i = 0; i < 4; i++) {
      gload16(gA + (size_t)(i * 32) * CC + k0, lA + i * 32 * BK);
      gload16(gB + (size_t)(i * 32) * CC + k0, lB + i * 32 * BK);
    }
    __syncthreads();
#pragma unroll
    for (int kh = 0; kh < 2; kh++) {
      const int rs = kh ? rs1 : rs0;
      bf16x8 af[4], bfr[4];
#pragma unroll
      for (int i = 0; i < 4; i++)
        af[i] = *(const bf16x8*)&As[(wmo + i * 16 + lrow) * BK + rs * 8];
#pragma unroll
      for (int j = 0; j < 4; j++)
        bfr[j] = *(const bf16x8*)&Bs[(wno + j * 16 + lrow) * BK + rs * 8];
#pragma unroll
      for (int i = 0; i < 4; i++)
#pragma unroll
        for (int j = 0; j < 4; j++)
          acc[i][j] = __builtin_amdgcn_mfma_f32_16x16x32_bf16(af[i], bfr[j], acc[i][j], 0, 0, 0);
    }
  }
#pragma unroll
  for (int i = 0; i < 4; i++)
#pragma unroll
    for (int j = 0; j < 4; j++)
#pragma unroll
      for (int r = 0; r < 4; r++) {
        const int row = bm + wmo + i * 16 + kgrp * 4 + r;
        const int col = bn + wno + j * 16 + lrow;
        C[(size_t)row * KNN + col] = f2bf(acc[i][j][r]);
      }
}

// ---------------- mini MFMA GEMM: M-tile 96, N-tile 128, BK=64 -------------
// EP 0: Cf = acc + bias + kern[row%9]      (proj)
// EP 1: Cb = bf16(gelu(acc + bias))        (chan_mix_a)
// EP 2: Cf += acc + bias                   (chan_mix_b)
template <int EP>
__global__ __launch_bounds__(256) void mfma96_kernel(
    const short* __restrict__ A,    // [288][K] bf16
    const short* __restrict__ Bt,   // [N][K] bf16
    int K, int ldn,
    const float* __restrict__ bias, // [ldn]
    const float* __restrict__ kern, // EP0
    float* __restrict__ Cf,
    short* __restrict__ Cb)
{
  __shared__ short As[96 * BK];
  __shared__ short Bs[128 * BK];
  const int tid = threadIdx.x;
  const int wave = tid >> 6, lane = tid & 63;
  const int bm = blockIdx.x * 96;
  const int bn = blockIdx.y * 128;
  const int wmo = (wave >> 1) * 48;
  const int wno = (wave & 1) * 64;
  const int lrow = lane & 15;
  const int kgrp = lane >> 4;
  const int sr = tid >> 3;     // 0..31
  const int ss = tid & 7;
  const int rs0 = kgrp ^ (lrow & 7);
  const int rs1 = (4 + kgrp) ^ (lrow & 7);
  f32x4 acc[3][4];
#pragma unroll
  for (int i = 0; i < 3; i++)
#pragma unroll
    for (int j = 0; j < 4; j++) acc[i][j] = (f32x4){0.f, 0.f, 0.f, 0.f};
  for (int k0 = 0; k0 < K; k0 += BK) {
    __syncthreads();
#pragma unroll
    for (int i = 0; i < 3; i++) {
      const int r = i * 32 + sr;
      const int sg = ss ^ (r & 7);
      gload16(A + (size_t)(bm + r) * K + k0 + sg * 8, &As[r * BK + ss * 8]);
    }
#pragma unroll
    for (int i = 0; i < 4; i++) {
      const int r = i * 32 + sr;
      const int sg = ss ^ (r & 7);
      gload16(Bt + (size_t)(bn + r) * K + k0 + sg * 8, &Bs[r * BK + ss * 8]);
    }
    __syncthreads();
#pragma unroll
    for (int kh = 0; kh < 2; kh++) {
      const int rs = kh ? rs1 : rs0;
      bf16x8 af[3], bfr[4];
#pragma unroll
      for (int m = 0; m < 3; m++)
        af[m] = *(const bf16x8*)&As[(wmo + m * 16 + lrow) * BK + rs * 8];
#pragma unroll
      for (int n = 0; n < 4; n++)
        bfr[n] = *(const bf16x8*)&Bs[(wno + n * 16 + lrow) * BK + rs * 8];
#pragma unroll
      for (int m = 0; m < 3; m++)
#pragma unroll
        for (int n = 0; n < 4; n++)
          acc[m][n] = __builtin_amdgcn_mfma_f32_16x16x32_bf16(af[m], bfr[n], acc[m][n], 0, 0, 0);
    }
  }
#pragma unroll
  for (int m = 0; m < 3; m++)
#pragma unroll
    for (int n = 0; n < 4; n++)
#pragma unroll
      for (int r = 0; r < 4; r++) {
        const int row = bm + wmo + m * 16 + kgrp * 4 + r;
        const int col = bn + wno + n * 16 + lrow;
        float v = acc[m][n][r] + bias[col];
        if (EP == 0) Cf[(size_t)row * ldn + col] = v + kern[(row % KKK) * ldn + col];
        if (EP == 1) Cb[(size_t)row * ldn + col] = f2bf(gelu_f(v));
        if (EP == 2) Cf[(size_t)row * ldn + col] += v;
      }
}

// ---------------- row LayerNorm (fp32 in, fp32 out) ------------------------
__global__ __launch_bounds__(256) void row_ln_kernel(
    const float* __restrict__ in, float* __restrict__ out,
    const float* __restrict__ g, const float* __restrict__ bb, float eps)
{
  const int row = blockIdx.x;
  const int tid = threadIdx.x;
  __shared__ float red[256];
  const size_t base = (size_t)row * CC;
  float x0 = in[base + tid];
  float x1 = in[base + tid + 256];
  float x2 = in[base + tid + 512];
  red[tid] = x0 + x1 + x2;
  __syncthreads();
  for (int st = 128; st > 0; st >>= 1) { if (tid < st) red[tid] += red[tid + st]; __syncthreads(); }
  float mean = red[0] * (1.0f / 768.0f);
  __syncthreads();
  float d0 = x0 - mean, d1 = x1 - mean, d2 = x2 - mean;
  red[tid] = d0 * d0 + d1 * d1 + d2 * d2;
  __syncthreads();
  for (int st = 128; st > 0; st >>= 1) { if (tid < st) red[tid] += red[tid + st]; __syncthreads(); }
  float rstd = rsqrtf(red[0] * (1.0f / 768.0f) + eps);
  out[base + tid]       = d0 * rstd * g[tid]       + bb[tid];
  out[base + tid + 256] = d1 * rstd * g[tid + 256] + bb[tid + 256];
  out[base + tid + 512] = d2 * rstd * g[tid + 512] + bb[tid + 512];
}

// ---------------- row LayerNorm (fp32 in, bf16 out) ------------------------
__global__ __launch_bounds__(256) void row_ln_bf_kernel(
    const float* __restrict__ in, short* __restrict__ out,
    const float* __restrict__ g, const float* __restrict__ bb, float eps)
{
  const int row = blockIdx.x;
  const int tid = threadIdx.x;
  __shared__ float red[256];
  const size_t base = (size_t)row * CC;
  float x0 = in[base + tid];
  float x1 = in[base + tid + 256];
  float x2 = in[base + tid + 512];
  red[tid] = x0 + x1 + x2;
  __syncthreads();
  for (int st = 128; st > 0; st >>= 1) { if (tid < st) red[tid] += red[tid + st]; __syncthreads(); }
  float mean = red[0] * (1.0f / 768.0f);
  __syncthreads();
  float d0 = x0 - mean, d1 = x1 - mean, d2 = x2 - mean;
  red[tid] = d0 * d0 + d1 * d1 + d2 * d2;
  __syncthreads();
  for (int st = 128; st > 0; st >>= 1) { if (tid < st) red[tid] += red[tid + st]; __syncthreads(); }
  float rstd = rsqrtf(red[0] * (1.0f / 768.0f) + eps);
  out[base + tid]       = f2bf(d0 * rstd * g[tid]       + bb[tid]);
  out[base + tid + 256] = f2bf(d1 * rstd * g[tid + 256] + bb[tid + 256]);
  out[base + tid + 512] = f2bf(d2 * rstd * g[tid + 512] + bb[tid + 512]);
}

// ---------------- attention: 9 queries x 1024 keys per (b,h) ---------------
__global__ __launch_bounds__(256) void attn_kernel(
    const float* __restrict__ wm,       // [9][768]
    const short* __restrict__ big,      // [32768][2304] bf16 (kv | xq)
    short* __restrict__ ca)             // [32][9][768] bf16
{
  const int b = blockIdx.x;
  const int h = blockIdx.y;
  const int tid = threadIdx.x;
  const int wave = tid >> 6, lane = tid & 63;
  __shared__ float wmh[KKK][HDD];
  __shared__ float sc[KKK][NN];
  __shared__ float part[4][KKK][HDD];
  for (int i = tid; i < KKK * HDD; i += 256) {
    int q = i >> 6, d = i & 63;
    wmh[q][d] = wm[q * CC + h * HDD + d];
  }
  __syncthreads();
  for (int n = tid; n < NN; n += 256) {
    const short* kp = &big[(size_t)(b * NN + n) * KNN + h * HDD];
    float acc[KKK];
#pragma unroll
    for (int q = 0; q < KKK; q++) acc[q] = 0.f;
    for (int d0 = 0; d0 < HDD; d0 += 8) {
      bf16x8 kv8 = *(const bf16x8*)&kp[d0];
#pragma unroll
      for (int e = 0; e < 8; e++) {
        float kf = bfbits2f(kv8[e]);
#pragma unroll
        for (int q = 0; q < KKK; q++) acc[q] += wmh[q][d0 + e] * kf;
      }
    }
#pragma unroll
    for (int q = 0; q < KKK; q++) sc[q][n] = acc[q] * 0.125f;
  }
  __syncthreads();
  for (int q = wave; q < KKK; q += 4) {
    float m = -1e30f;
#pragma unroll
    for (int i = 0; i < 16; i++) m = fmaxf(m, sc[q][lane + i * 64]);
#pragma unroll
    for (int off = 32; off > 0; off >>= 1) m = fmaxf(m, __shfl_xor(m, off));
    float s = 0.f;
#pragma unroll
    for (int i = 0; i < 16; i++) {
      float e = expf(sc[q][lane + i * 64] - m);
      sc[q][lane + i * 64] = e;
      s += e;
    }
#pragma unroll
    for (int off = 32; off > 0; off >>= 1) s += __shfl_xor(s, off);
    float inv = 1.0f / s;
#pragma unroll
    for (int i = 0; i < 16; i++) sc[q][lane + i * 64] *= inv;
  }
  __syncthreads();
  const int d = tid & 63, prt = tid >> 6;
  float acc[KKK];
#pragma unroll
  for (int q = 0; q < KKK; q++) acc[q] = 0.f;
  for (int n = prt * 256; n < prt * 256 + 256; n++) {
    float vf = bfbits2f(big[(size_t)(b * NN + n) * KNN + CC + h * HDD + d]);
#pragma unroll
    for (int q = 0; q < KKK; q++) acc[q] += sc[q][n] * vf;
  }
#pragma unroll
  for (int q = 0; q < KKK; q++) part[prt][q][d] = acc[q];
  __syncthreads();
  for (int i = tid; i < KKK * HDD; i += 256) {
    int q = i >> 6, dd = i & 63;
    ca[(size_t)(b * KKK + q) * CC + h * HDD + dd] =
        f2bf(part[0][q][dd] + part[1][q][dd] + part[2][q][dd] + part[3][q][dd]);
  }
}

// ---------------- token mixer (bf16 input) ---------------------------------
__global__ __launch_bounds__(256) void token_mix_kernel(
    const short* __restrict__ ln1,     // [288][768] bf16
    const float* __restrict__ pm1_w,   // [9][1536]
    const float* __restrict__ pm1_b,   // [1536]
    const float* __restrict__ pm2_w,   // [1536][9]
    float* __restrict__ part)          // [8][32][9][768]
{
  const int tid = threadIdx.x;
  const int c = blockIdx.x * 256 + tid;
  const int b = blockIdx.y;
  const int jc = blockIdx.z;
  float u[KKK], o[KKK];
#pragma unroll
  for (int q = 0; q < KKK; q++) {
    u[q] = bfbits2f(ln1[(size_t)(b * KKK + q) * CC + c]);
    o[q] = 0.f;
  }
  const int j0 = jc * (PMDD / 8);
  for (int j = j0; j < j0 + PMDD / 8; j++) {
    float hs = pm1_b[j];
#pragma unroll
    for (int q = 0; q < KKK; q++) hs += u[q] * pm1_w[q * PMDD + j];
    float gv = gelu_f(hs);
    const float* p2 = &pm2_w[(size_t)j * KKK];
#pragma unroll
    for (int q = 0; q < KKK; q++) o[q] += gv * p2[q];
  }
  float* pp = &part[(size_t)((jc * BB + b) * KKK) * CC + c];
#pragma unroll
  for (int q = 0; q < KKK; q++) pp[(size_t)q * CC] = o[q];
}

// ---------------- token reduce + LN2 (bf16 LN output) ----------------------
__global__ __launch_bounds__(256) void token_reduce_ln_kernel(
    const float* __restrict__ part,    // [8][32][9][768]
    const float* __restrict__ pm2_b,   // [9]
    const float* __restrict__ g, const float* __restrict__ bb,
    float* __restrict__ w1,            // [288][768] (in/out)
    short* __restrict__ lnb)           // [288][768] bf16
{
  const int row = blockIdx.x;
  const int q = row % KKK;
  const int tid = threadIdx.x;
  __shared__ float red[256];
  const size_t base = (size_t)row * CC;
  float v[3];
#pragma unroll
  for (int j = 0; j < 3; j++) {
    const int c = tid + j * 256;
    float s = 0.f;
#pragma unroll
    for (int gg = 0; gg < 8; gg++)
      s += part[(size_t)gg * BB * KKK * CC + base + c];
    v[j] = w1[base + c] + s + pm2_b[q];
    w1[base + c] = v[j];
  }
  red[tid] = v[0] + v[1] + v[2];
  __syncthreads();
  for (int st = 128; st > 0; st >>= 1) { if (tid < st) red[tid] += red[tid + st]; __syncthreads(); }
  float mean = red[0] * (1.0f / 768.0f);
  __syncthreads();
  float d0 = v[0] - mean, d1 = v[1] - mean, d2 = v[2] - mean;
  red[tid] = d0 * d0 + d1 * d1 + d2 * d2;
  __syncthreads();
  for (int st = 128; st > 0; st >>= 1) { if (tid < st) red[tid] += red[tid + st]; __syncthreads(); }
  float rstd = rsqrtf(red[0] * (1.0f / 768.0f) + 1e-5f);
  lnb[base + tid]       = f2bf(d0 * rstd * g[tid]       + bb[tid]);
  lnb[base + tid + 256] = f2bf(d1 * rstd * g[tid + 256] + bb[tid + 256]);
  lnb[base + tid + 512] = f2bf(d2 * rstd * g[tid + 512] + bb[tid + 512]);
}

// ---------------- dynamic depthwise 3x3 conv (sliding window) --------------
__global__ __launch_bounds__(256) void conv_kernel(
    const short* __restrict__ big,   // xq (bf16) at column offset 1536
    const float* __restrict__ w1,    // [32][9][768] filters
    float* __restrict__ out)         // [32][1024][768] fp32
{
  const int cchunk = blockIdx.x;
  const int y = blockIdx.y;
  const int b = blockIdx.z;
  const int c = cchunk * 256 + threadIdx.x;
  float f[KKK];
#pragma unroll
  for (int q = 0; q < KKK; q++) f[q] = w1[(size_t)(b * KKK + q) * CC + c];
  const short* rp[3];
  bool rv[3];
#pragma unroll
  for (int ky = 0; ky < 3; ky++) {
    int yy = y + ky - 1;
    rv[ky] = (yy >= 0 && yy < 32);
    rp[ky] = big + (size_t)(b * NN + (rv[ky] ? yy : 0) * 32) * KNN + 2 * CC + c;
  }
  float c0[3] = {0.f, 0.f, 0.f}, c1[3], c2[3];
#pragma unroll
  for (int ky = 0; ky < 3; ky++) c1[ky] = rv[ky] ? bfbits2f(rp[ky][0]) : 0.f;
  float* op = &out[(size_t)(b * NN + y * 32) * CC + c];
  for (int x = 0; x < 32; x++) {
#pragma unroll
    for (int ky = 0; ky < 3; ky++)
      c2[ky] = (x + 1 < 32 && rv[ky]) ? bfbits2f(rp[ky][(size_t)(x + 1) * KNN]) : 0.f;
    float acc = 0.f;
#pragma unroll
    for (int ky = 0; ky < 3; ky++)
      acc += f[ky * 3 + 0] * c0[ky] + f[ky * 3 + 1] * c1[ky] + f[ky * 3 + 2] * c2[ky];
    op[(size_t)x * CC] = acc;
#pragma unroll
    for (int ky = 0; ky < 3; ky++) { c0[ky] = c1[ky]; c1[ky] = c2[ky]; }
  }
}

// ---------------------------------------------------------------------------
extern "C" void kernel_launch(void* const* d_in, const int* in_sizes, int n_in,
                              void* d_out, int out_size, void* d_ws, size_t ws_size,
                              hipStream_t stream) {
  (void)in_sizes; (void)n_in; (void)out_size; (void)ws_size;
  const float* x       = (const float*)d_in[0];
  const float* kern    = (const float*)d_in[3];
  const float* ln_g    = (const float*)d_in[4];
  const float* ln_b    = (const float*)d_in[5];
  const float* kv_w    = (const float*)d_in[6];
  const float* proj_w  = (const float*)d_in[7];
  const float* proj_b  = (const float*)d_in[8];
  const float* projq_w = (const float*)d_in[9];
  const float* n1_g    = (const float*)d_in[10];
  const float* n1_b    = (const float*)d_in[11];
  const float* n2_g    = (const float*)d_in[12];
  const float* n2_b    = (const float*)d_in[13];
  const float* pm1_w   = (const float*)d_in[14];
  const float* pm1_b   = (const float*)d_in[15];
  const float* pm2_w   = (const float*)d_in[16];
  const float* pm2_b   = (const float*)d_in[17];
  const float* cm1_w   = (const float*)d_in[18];
  const float* cm1_b   = (const float*)d_in[19];
  const float* cm2_w   = (const float*)d_in[20];
  const float* cm2_b   = (const float*)d_in[21];
  float* out = (float*)d_out;

  uint8_t* ws = (uint8_t*)d_ws;
  short* Wt   = (short*)(ws);                    // 3,538,944 (dead after GEMM)
  short* h1   = (short*)(ws);                    // ALIAS: 288*1536*2 = 884,736
  short* big  = (short*)(ws + 3538944);          // 150,994,944
  float* wm   = (float*)(ws + 154533888);        // 27,648
  short* cab  = (short*)(ws + 154561536);        // 442,368 (bf16 ca)
  float* w1   = (float*)(ws + 155446272);        // 884,736
  short* ln1b = (short*)(ws + 156331008);        // 442,368
  short* ln2b = (short*)(ws + 156773376);        // 442,368 -> total 157,215,744

  // d_out scratch: xb until GEMM; tpart (0..7MB) during token_mix;
  // small-GEMM weights at 8/11/14 MB (written after GEMM, dead before conv).
  short* xb    = (short*)d_out;
  float* tpart = (float*)d_out;                  // 7,077,888 B
  short* Wc1T  = (short*)((uint8_t*)d_out + 8388608);   // [1536][768]
  short* Wc2T  = (short*)((uint8_t*)d_out + 11534336);  // [768][1536]
  short* WpT   = (short*)((uint8_t*)d_out + 14680064);  // [768][768]

  prep_kernel<<<dim3(MM * CC / (256 * 8) + 72 * 24), 256, 0, stream>>>(
      x, xb, kv_w, projq_w, Wt);
  gemm_bt_kernel<<<dim3((MM / 128) * (KNN / 128)), 256, 0, stream>>>(xb, Wt, big);
  wtrans2_kernel<<<dim3(2880), 256, 0, stream>>>(proj_w, cm1_w, cm2_w, WpT, Wc1T, Wc2T);
  row_ln_kernel<<<dim3(KKK), 256, 0, stream>>>(kern, wm, ln_g, ln_b, 1e-6f);
  attn_kernel<<<dim3(BB, NHH), 256, 0, stream>>>(wm, big, cab);
  mfma96_kernel<0><<<dim3(3, 6), 256, 0, stream>>>(cab, WpT, CC, CC,
                                                   proj_b, kern, w1, nullptr);
  row_ln_bf_kernel<<<dim3(BB * KKK), 256, 0, stream>>>(w1, ln1b, n1_g, n1_b, 1e-5f);
  token_mix_kernel<<<dim3(3, 32, 8), 256, 0, stream>>>(ln1b, pm1_w, pm1_b, pm2_w, tpart);
  token_reduce_ln_kernel<<<dim3(BB * KKK), 256, 0, stream>>>(tpart, pm2_b,
                                                             n2_g, n2_b, w1, ln2b);
  mfma96_kernel<1><<<dim3(3, 12), 256, 0, stream>>>(ln2b, Wc1T, CC, CMDD,
                                                    cm1_b, nullptr, nullptr, h1);
  mfma96_kernel<2><<<dim3(3, 6), 256, 0, stream>>>(h1, Wc2T, CMDD, CC,
                                                   cm2_b, nullptr, w1, nullptr);
  conv_kernel<<<dim3(3, 32, 32), 256, 0, stream>>>(big, w1, out);
}

// Round 9
// 477.151 us; speedup vs baseline: 3.1719x; 1.0612x over previous
//
#include <hip/hip_runtime.h>
#include <hip/hip_bf16.h>
#include <cstdint>
#include <cstddef>

typedef __attribute__((ext_vector_type(8))) short bf16x8;
typedef __attribute__((ext_vector_type(4))) float f32x4;

#define BB 32
#define NN 1024
#define CC 768
#define NHH 12
#define HDD 64
#define KKK 9
#define MM (BB * NN)   /* 32768 */
#define KNN (3 * CC)   /* 2304 = 2C (kv) + C (xq) */
#define PMDD 1536
#define CMDD 1536
#define BK 64

__device__ __forceinline__ float bfbits2f(short s) {
  union { uint32_t u; float f; } cv;
  cv.u = ((uint32_t)(uint16_t)s) << 16;
  return cv.f;
}
__device__ __forceinline__ short f2bf(float f) {
  union { float f; uint32_t u; } cv;
  cv.f = f;
  uint32_t u = cv.u;
  uint32_t r = (u + 0x7fffu + ((u >> 16) & 1u)) >> 16;
  return (short)r;
}
__device__ __forceinline__ float gelu_f(float x) {
  return 0.5f * x * (1.0f + erff(x * 0.7071067811865476f));
}

typedef const __attribute__((address_space(1))) uint32_t* gp1_t;
typedef __attribute__((address_space(3))) uint32_t* lp3_t;
__device__ __forceinline__ void gload16(const short* g, const short* l) {
  __builtin_amdgcn_global_load_lds((gp1_t)(uintptr_t)(const void*)g,
                                   (lp3_t)(uint32_t)(uintptr_t)(const void*)l,
                                   16, 0, 0);
}

// ---------------- prep: x->bf16  +  Wt (big-GEMM weight) transpose ---------
__global__ __launch_bounds__(256) void prep_kernel(
    const float* __restrict__ x, short* __restrict__ xb,
    const float* __restrict__ kv_w, const float* __restrict__ projq_w,
    short* __restrict__ Wt)
{
  if (blockIdx.x < MM * CC / (256 * 8)) {
    const int i = (blockIdx.x * 256 + threadIdx.x) * 8;
    f32x4 a = *(const f32x4*)&x[i];
    f32x4 b = *(const f32x4*)&x[i + 4];
    bf16x8 o;
#pragma unroll
    for (int e = 0; e < 4; e++) { o[e] = f2bf(a[e]); o[e + 4] = f2bf(b[e]); }
    *(bf16x8*)&xb[i] = o;
    return;
  }
  __shared__ float tile[32][33];
  const int b2 = blockIdx.x - MM * CC / (256 * 8);
  const int j0 = (b2 % 72) * 32;
  const int c0 = (b2 / 72) * 32;
  const int tx = threadIdx.x & 31, ty = threadIdx.x >> 5;
  const float* src; int ldj, jj;
  if (j0 < 2 * CC) { src = kv_w; ldj = 2 * CC; jj = j0; }
  else             { src = projq_w; ldj = CC; jj = j0 - 2 * CC; }
#pragma unroll
  for (int r = 0; r < 4; r++) {
    int cl = ty + r * 8;
    tile[cl][tx] = src[(size_t)(c0 + cl) * ldj + jj + tx];
  }
  __syncthreads();
#pragma unroll
  for (int r = 0; r < 4; r++) {
    int jl = ty + r * 8;
    Wt[(size_t)(j0 + jl) * CC + c0 + tx] = f2bf(tile[tx][jl]);
  }
}

// ---------------- wtrans2: bf16 transposes of proj_w, cm1_w, cm2_w ---------
__global__ __launch_bounds__(256) void wtrans2_kernel(
    const float* __restrict__ proj_w,  // [768][768]
    const float* __restrict__ cm1_w,   // [768][1536]
    const float* __restrict__ cm2_w,   // [1536][768]
    short* __restrict__ WpT,           // [768][768]
    short* __restrict__ Wc1T,          // [1536][768]
    short* __restrict__ Wc2T)          // [768][1536]
{
  __shared__ float tile[32][33];
  int b = blockIdx.x;
  const float* src; short* dst; int ldj, ldc, j0, c0;
  if (b < 576)        { src = proj_w; dst = WpT;  ldj = 768;  ldc = 768;
                        j0 = (b % 24) * 32; c0 = (b / 24) * 32; }
  else if (b < 1728)  { b -= 576; src = cm1_w; dst = Wc1T; ldj = 1536; ldc = 768;
                        j0 = (b % 48) * 32; c0 = (b / 48) * 32; }
  else                { b -= 1728; src = cm2_w; dst = Wc2T; ldj = 768; ldc = 1536;
                        j0 = (b % 24) * 32; c0 = (b / 24) * 32; }
  const int tx = threadIdx.x & 31, ty = threadIdx.x >> 5;
#pragma unroll
  for (int r = 0; r < 4; r++) {
    int cl = ty + r * 8;
    tile[cl][tx] = src[(size_t)(c0 + cl) * ldj + j0 + tx];
  }
  __syncthreads();
#pragma unroll
  for (int r = 0; r < 4; r++) {
    int jl = ty + r * 8;
    dst[(size_t)(j0 + jl) * ldc + c0 + tx] = f2bf(tile[tx][jl]);
  }
}

// ---------------- big GEMM: 128x128, BK=64, swizzled (proven) --------------
__global__ __launch_bounds__(256) void gemm_bt_kernel(
    const short* __restrict__ A,     // [MM][768] bf16
    const short* __restrict__ Bt,    // [2304][768] bf16 (B^T)
    short* __restrict__ C)           // [MM][2304] bf16
{
  __shared__ short As[128 * BK];
  __shared__ short Bs[128 * BK];
  const int tid = threadIdx.x;
  const int wave = tid >> 6, lane = tid & 63;
  const int lid = blockIdx.x;
  const int wid = (lid & 7) * 576 + (lid >> 3);
  const int bn = (wid % 18) * 128;
  const int bm = (wid / 18) * 128;
  const int wmo = (wave >> 1) * 64;
  const int wno = (wave & 1) * 64;
  const int lrow = lane & 15;
  const int kgrp = lane >> 4;
  const int sr = tid >> 3;
  const int ss = tid & 7;
  const int slotG = ss ^ (sr & 7);
  const short* gA = A + (size_t)(bm + sr) * CC + slotG * 8;
  const short* gB = Bt + (size_t)(bn + sr) * CC + slotG * 8;
  const short* lA = &As[sr * BK + ss * 8];
  const short* lB = &Bs[sr * BK + ss * 8];
  const int rs0 = kgrp ^ (lrow & 7);
  const int rs1 = (4 + kgrp) ^ (lrow & 7);
  f32x4 acc[4][4];
#pragma unroll
  for (int i = 0; i < 4; i++)
#pragma unroll
    for (int j = 0; j < 4; j++) acc[i][j] = (f32x4){0.f, 0.f, 0.f, 0.f};
  for (int k0 = 0; k0 < CC; k0 += BK) {
    __syncthreads();
#pragma unroll
    for (int i = 0; i < 4; i++) {
      gload16(gA + (size_t)(i * 32) * CC + k0, lA + i * 32 * BK);
      gload16(gB + (size_t)(i * 32) * CC + k0, lB + i * 32 * BK);
    }
    __syncthreads();
#pragma unroll
    for (int kh = 0; kh < 2; kh++) {
      const int rs = kh ? rs1 : rs0;
      bf16x8 af[4], bfr[4];
#pragma unroll
      for (int i = 0; i < 4; i++)
        af[i] = *(const bf16x8*)&As[(wmo + i * 16 + lrow) * BK + rs * 8];
#pragma unroll
      for (int j = 0; j < 4; j++)
        bfr[j] = *(const bf16x8*)&Bs[(wno + j * 16 + lrow) * BK + rs * 8];
#pragma unroll
      for (int i = 0; i < 4; i++)
#pragma unroll
        for (int j = 0; j < 4; j++)
          acc[i][j] = __builtin_amdgcn_mfma_f32_16x16x32_bf16(af[i], bfr[j], acc[i][j], 0, 0, 0);
    }
  }
#pragma unroll
  for (int i = 0; i < 4; i++)
#pragma unroll
    for (int j = 0; j < 4; j++)
#pragma unroll
      for (int r = 0; r < 4; r++) {
        const int row = bm + wmo + i * 16 + kgrp * 4 + r;
        const int col = bn + wno + j * 16 + lrow;
        C[(size_t)row * KNN + col] = f2bf(acc[i][j][r]);
      }
}

// ---------------- mini MFMA GEMM: M-tile 96, N-tile 128, BK=64 -------------
template <int EP>
__global__ __launch_bounds__(256) void mfma96_kernel(
    const short* __restrict__ A,    // [288][K] bf16
    const short* __restrict__ Bt,   // [N][K] bf16
    int K, int ldn,
    const float* __restrict__ bias, // [ldn]
    const float* __restrict__ kern, // EP0
    float* __restrict__ Cf,
    short* __restrict__ Cb)
{
  __shared__ short As[96 * BK];
  __shared__ short Bs[128 * BK];
  const int tid = threadIdx.x;
  const int wave = tid >> 6, lane = tid & 63;
  const int bm = blockIdx.x * 96;
  const int bn = blockIdx.y * 128;
  const int wmo = (wave >> 1) * 48;
  const int wno = (wave & 1) * 64;
  const int lrow = lane & 15;
  const int kgrp = lane >> 4;
  const int sr = tid >> 3;
  const int ss = tid & 7;
  const int rs0 = kgrp ^ (lrow & 7);
  const int rs1 = (4 + kgrp) ^ (lrow & 7);
  f32x4 acc[3][4];
#pragma unroll
  for (int i = 0; i < 3; i++)
#pragma unroll
    for (int j = 0; j < 4; j++) acc[i][j] = (f32x4){0.f, 0.f, 0.f, 0.f};
  for (int k0 = 0; k0 < K; k0 += BK) {
    __syncthreads();
#pragma unroll
    for (int i = 0; i < 3; i++) {
      const int r = i * 32 + sr;
      const int sg = ss ^ (r & 7);
      gload16(A + (size_t)(bm + r) * K + k0 + sg * 8, &As[r * BK + ss * 8]);
    }
#pragma unroll
    for (int i = 0; i < 4; i++) {
      const int r = i * 32 + sr;
      const int sg = ss ^ (r & 7);
      gload16(Bt + (size_t)(bn + r) * K + k0 + sg * 8, &Bs[r * BK + ss * 8]);
    }
    __syncthreads();
#pragma unroll
    for (int kh = 0; kh < 2; kh++) {
      const int rs = kh ? rs1 : rs0;
      bf16x8 af[3], bfr[4];
#pragma unroll
      for (int m = 0; m < 3; m++)
        af[m] = *(const bf16x8*)&As[(wmo + m * 16 + lrow) * BK + rs * 8];
#pragma unroll
      for (int n = 0; n < 4; n++)
        bfr[n] = *(const bf16x8*)&Bs[(wno + n * 16 + lrow) * BK + rs * 8];
#pragma unroll
      for (int m = 0; m < 3; m++)
#pragma unroll
        for (int n = 0; n < 4; n++)
          acc[m][n] = __builtin_amdgcn_mfma_f32_16x16x32_bf16(af[m], bfr[n], acc[m][n], 0, 0, 0);
    }
  }
#pragma unroll
  for (int m = 0; m < 3; m++)
#pragma unroll
    for (int n = 0; n < 4; n++)
#pragma unroll
      for (int r = 0; r < 4; r++) {
        const int row = bm + wmo + m * 16 + kgrp * 4 + r;
        const int col = bn + wno + n * 16 + lrow;
        float v = acc[m][n][r] + bias[col];
        if (EP == 0) Cf[(size_t)row * ldn + col] = v + kern[(row % KKK) * ldn + col];
        if (EP == 1) Cb[(size_t)row * ldn + col] = f2bf(gelu_f(v));
        if (EP == 2) Cf[(size_t)row * ldn + col] += v;
      }
}

// ---------------- row LayerNorm (fp32 in, fp32 out) ------------------------
__global__ __launch_bounds__(256) void row_ln_kernel(
    const float* __restrict__ in, float* __restrict__ out,
    const float* __restrict__ g, const float* __restrict__ bb, float eps)
{
  const int row = blockIdx.x;
  const int tid = threadIdx.x;
  __shared__ float red[256];
  const size_t base = (size_t)row * CC;
  float x0 = in[base + tid];
  float x1 = in[base + tid + 256];
  float x2 = in[base + tid + 512];
  red[tid] = x0 + x1 + x2;
  __syncthreads();
  for (int st = 128; st > 0; st >>= 1) { if (tid < st) red[tid] += red[tid + st]; __syncthreads(); }
  float mean = red[0] * (1.0f / 768.0f);
  __syncthreads();
  float d0 = x0 - mean, d1 = x1 - mean, d2 = x2 - mean;
  red[tid] = d0 * d0 + d1 * d1 + d2 * d2;
  __syncthreads();
  for (int st = 128; st > 0; st >>= 1) { if (tid < st) red[tid] += red[tid + st]; __syncthreads(); }
  float rstd = rsqrtf(red[0] * (1.0f / 768.0f) + eps);
  out[base + tid]       = d0 * rstd * g[tid]       + bb[tid];
  out[base + tid + 256] = d1 * rstd * g[tid + 256] + bb[tid + 256];
  out[base + tid + 512] = d2 * rstd * g[tid + 512] + bb[tid + 512];
}

// ---------------- row LayerNorm (fp32 in, bf16 out) ------------------------
__global__ __launch_bounds__(256) void row_ln_bf_kernel(
    const float* __restrict__ in, short* __restrict__ out,
    const float* __restrict__ g, const float* __restrict__ bb, float eps)
{
  const int row = blockIdx.x;
  const int tid = threadIdx.x;
  __shared__ float red[256];
  const size_t base = (size_t)row * CC;
  float x0 = in[base + tid];
  float x1 = in[base + tid + 256];
  float x2 = in[base + tid + 512];
  red[tid] = x0 + x1 + x2;
  __syncthreads();
  for (int st = 128; st > 0; st >>= 1) { if (tid < st) red[tid] += red[tid + st]; __syncthreads(); }
  float mean = red[0] * (1.0f / 768.0f);
  __syncthreads();
  float d0 = x0 - mean, d1 = x1 - mean, d2 = x2 - mean;
  red[tid] = d0 * d0 + d1 * d1 + d2 * d2;
  __syncthreads();
  for (int st = 128; st > 0; st >>= 1) { if (tid < st) red[tid] += red[tid + st]; __syncthreads(); }
  float rstd = rsqrtf(red[0] * (1.0f / 768.0f) + eps);
  out[base + tid]       = f2bf(d0 * rstd * g[tid]       + bb[tid]);
  out[base + tid + 256] = f2bf(d1 * rstd * g[tid + 256] + bb[tid + 256]);
  out[base + tid + 512] = f2bf(d2 * rstd * g[tid + 512] + bb[tid + 512]);
}

// ---------------- attention: 9 queries x 1024 keys per (b,h) ---------------
__global__ __launch_bounds__(256) void attn_kernel(
    const float* __restrict__ wm,       // [9][768]
    const short* __restrict__ big,      // [32768][2304] bf16 (kv | xq)
    short* __restrict__ ca)             // [32][9][768] bf16
{
  const int b = blockIdx.x;
  const int h = blockIdx.y;
  const int tid = threadIdx.x;
  const int wave = tid >> 6, lane = tid & 63;
  __shared__ float wmh[KKK][HDD];
  __shared__ float sc[KKK][NN];
  __shared__ float part[4][KKK][HDD];
  for (int i = tid; i < KKK * HDD; i += 256) {
    int q = i >> 6, d = i & 63;
    wmh[q][d] = wm[q * CC + h * HDD + d];
  }
  __syncthreads();
  for (int n = tid; n < NN; n += 256) {
    const short* kp = &big[(size_t)(b * NN + n) * KNN + h * HDD];
    float acc[KKK];
#pragma unroll
    for (int q = 0; q < KKK; q++) acc[q] = 0.f;
    for (int d0 = 0; d0 < HDD; d0 += 8) {
      bf16x8 kv8 = *(const bf16x8*)&kp[d0];
#pragma unroll
      for (int e = 0; e < 8; e++) {
        float kf = bfbits2f(kv8[e]);
#pragma unroll
        for (int q = 0; q < KKK; q++) acc[q] += wmh[q][d0 + e] * kf;
      }
    }
#pragma unroll
    for (int q = 0; q < KKK; q++) sc[q][n] = acc[q] * 0.125f;
  }
  __syncthreads();
  for (int q = wave; q < KKK; q += 4) {
    float m = -1e30f;
#pragma unroll
    for (int i = 0; i < 16; i++) m = fmaxf(m, sc[q][lane + i * 64]);
#pragma unroll
    for (int off = 32; off > 0; off >>= 1) m = fmaxf(m, __shfl_xor(m, off));
    float s = 0.f;
#pragma unroll
    for (int i = 0; i < 16; i++) {
      float e = expf(sc[q][lane + i * 64] - m);
      sc[q][lane + i * 64] = e;
      s += e;
    }
#pragma unroll
    for (int off = 32; off > 0; off >>= 1) s += __shfl_xor(s, off);
    float inv = 1.0f / s;
#pragma unroll
    for (int i = 0; i < 16; i++) sc[q][lane + i * 64] *= inv;
  }
  __syncthreads();
  const int d = tid & 63, prt = tid >> 6;
  float acc[KKK];
#pragma unroll
  for (int q = 0; q < KKK; q++) acc[q] = 0.f;
  for (int n = prt * 256; n < prt * 256 + 256; n++) {
    float vf = bfbits2f(big[(size_t)(b * NN + n) * KNN + CC + h * HDD + d]);
#pragma unroll
    for (int q = 0; q < KKK; q++) acc[q] += sc[q][n] * vf;
  }
#pragma unroll
  for (int q = 0; q < KKK; q++) part[prt][q][d] = acc[q];
  __syncthreads();
  for (int i = tid; i < KKK * HDD; i += 256) {
    int q = i >> 6, dd = i & 63;
    ca[(size_t)(b * KKK + q) * CC + h * HDD + dd] =
        f2bf(part[0][q][dd] + part[1][q][dd] + part[2][q][dd] + part[3][q][dd]);
  }
}

// ---------------- token mixer (bf16 input) ---------------------------------
__global__ __launch_bounds__(256) void token_mix_kernel(
    const short* __restrict__ ln1,     // [288][768] bf16
    const float* __restrict__ pm1_w,   // [9][1536]
    const float* __restrict__ pm1_b,   // [1536]
    const float* __restrict__ pm2_w,   // [1536][9]
    float* __restrict__ part)          // [8][32][9][768]
{
  const int tid = threadIdx.x;
  const int c = blockIdx.x * 256 + tid;
  const int b = blockIdx.y;
  const int jc = blockIdx.z;
  float u[KKK], o[KKK];
#pragma unroll
  for (int q = 0; q < KKK; q++) {
    u[q] = bfbits2f(ln1[(size_t)(b * KKK + q) * CC + c]);
    o[q] = 0.f;
  }
  const int j0 = jc * (PMDD / 8);
  for (int j = j0; j < j0 + PMDD / 8; j++) {
    float hs = pm1_b[j];
#pragma unroll
    for (int q = 0; q < KKK; q++) hs += u[q] * pm1_w[q * PMDD + j];
    float gv = gelu_f(hs);
    const float* p2 = &pm2_w[(size_t)j * KKK];
#pragma unroll
    for (int q = 0; q < KKK; q++) o[q] += gv * p2[q];
  }
  float* pp = &part[(size_t)((jc * BB + b) * KKK) * CC + c];
#pragma unroll
  for (int q = 0; q < KKK; q++) pp[(size_t)q * CC] = o[q];
}

// ---------------- token reduce + LN2 (bf16 LN output) ----------------------
__global__ __launch_bounds__(256) void token_reduce_ln_kernel(
    const float* __restrict__ part,    // [8][32][9][768]
    const float* __restrict__ pm2_b,   // [9]
    const float* __restrict__ g, const float* __restrict__ bb,
    float* __restrict__ w1,            // [288][768] (in/out)
    short* __restrict__ lnb)           // [288][768] bf16
{
  const int row = blockIdx.x;
  const int q = row % KKK;
  const int tid = threadIdx.x;
  __shared__ float red[256];
  const size_t base = (size_t)row * CC;
  float v[3];
#pragma unroll
  for (int j = 0; j < 3; j++) {
    const int c = tid + j * 256;
    float s = 0.f;
#pragma unroll
    for (int gg = 0; gg < 8; gg++)
      s += part[(size_t)gg * BB * KKK * CC + base + c];
    v[j] = w1[base + c] + s + pm2_b[q];
    w1[base + c] = v[j];
  }
  red[tid] = v[0] + v[1] + v[2];
  __syncthreads();
  for (int st = 128; st > 0; st >>= 1) { if (tid < st) red[tid] += red[tid + st]; __syncthreads(); }
  float mean = red[0] * (1.0f / 768.0f);
  __syncthreads();
  float d0 = v[0] - mean, d1 = v[1] - mean, d2 = v[2] - mean;
  red[tid] = d0 * d0 + d1 * d1 + d2 * d2;
  __syncthreads();
  for (int st = 128; st > 0; st >>= 1) { if (tid < st) red[tid] += red[tid + st]; __syncthreads(); }
  float rstd = rsqrtf(red[0] * (1.0f / 768.0f) + 1e-5f);
  lnb[base + tid]       = f2bf(d0 * rstd * g[tid]       + bb[tid]);
  lnb[base + tid + 256] = f2bf(d1 * rstd * g[tid + 256] + bb[tid + 256]);
  lnb[base + tid + 512] = f2bf(d2 * rstd * g[tid + 512] + bb[tid + 512]);
}

// ---------------- conv: LDS-staged read-once, sliding window ---------------
// grid (6, 32, 4): 128-c chunk, batch, 8-y chunk. 3 rotating row buffers.
__global__ __launch_bounds__(256) void conv_lds_kernel(
    const short* __restrict__ big,   // xq (bf16) at column offset 1536
    const float* __restrict__ w1,    // [32][9][768] filters
    float* __restrict__ out)         // [32][1024][768] fp32
{
  __shared__ short rows[3][32][132];   // padded: ~25 KB
  const int c0 = blockIdx.x * 128;
  const int b = blockIdx.y;
  const int y0 = blockIdx.z * 8;
  const int tid = threadIdx.x;
  // load mapping: xl = tid>>3 (0..31), cg = tid&7 (16 c each)
  const int xl = tid >> 3, cg = tid & 7;
  // compute mapping: cl = tid&127, xh = tid>>7 (x halves of 16)
  const int cl = tid & 127, xh = tid >> 7;
  float f[KKK];
#pragma unroll
  for (int q = 0; q < KKK; q++) f[q] = w1[(size_t)(b * KKK + q) * CC + c0 + cl];

#define LOAD_ROW(yy, slot)                                                     \
  {                                                                            \
    short* dst = &rows[slot][xl][cg * 16];                                     \
    if ((yy) >= 0 && (yy) < 32) {                                              \
      const short* src =                                                       \
          &big[(size_t)(b * NN + (yy) * 32 + xl) * KNN + 2 * CC + c0 + cg * 16];\
      *(bf16x8*)dst = *(const bf16x8*)src;                                     \
      *(bf16x8*)(dst + 8) = *(const bf16x8*)(src + 8);                         \
    } else {                                                                   \
      bf16x8 z = {0, 0, 0, 0, 0, 0, 0, 0};                                     \
      *(bf16x8*)dst = z;                                                       \
      *(bf16x8*)(dst + 8) = z;                                                 \
    }                                                                          \
  }

  int sPrev = 0, sCur = 1, sNext = 2;
  LOAD_ROW(y0 - 1, 0);
  LOAD_ROW(y0, 1);
  for (int y = y0; y < y0 + 8; ++y) {
    LOAD_ROW(y + 1, sNext);
    __syncthreads();
    // sliding-window compute: 16 x positions per thread
    const int xb = xh * 16;
    float v0[3], v1[3];
#pragma unroll
    for (int ky = 0; ky < 3; ky++) {
      const int s = (ky == 0) ? sPrev : (ky == 1 ? sCur : sNext);
      v1[ky] = bfbits2f(rows[s][xb][cl]);
      v0[ky] = (xb == 0) ? 0.f : bfbits2f(rows[s][xb - 1][cl]);
    }
    float* op = &out[(size_t)(b * NN + y * 32 + xb) * CC + c0 + cl];
#pragma unroll
    for (int i = 0; i < 16; i++) {
      const int x = xb + i;
      float v2[3];
#pragma unroll
      for (int ky = 0; ky < 3; ky++) {
        const int s = (ky == 0) ? sPrev : (ky == 1 ? sCur : sNext);
        v2[ky] = (x + 1 < 32) ? bfbits2f(rows[s][x + 1][cl]) : 0.f;
      }
      float acc = 0.f;
#pragma unroll
      for (int ky = 0; ky < 3; ky++)
        acc += f[ky * 3] * v0[ky] + f[ky * 3 + 1] * v1[ky] + f[ky * 3 + 2] * v2[ky];
      op[(size_t)i * CC] = acc;
#pragma unroll
      for (int ky = 0; ky < 3; ky++) { v0[ky] = v1[ky]; v1[ky] = v2[ky]; }
    }
    __syncthreads();
    const int t = sPrev; sPrev = sCur; sCur = sNext; sNext = t;
  }
#undef LOAD_ROW
}

// ---------------------------------------------------------------------------
extern "C" void kernel_launch(void* const* d_in, const int* in_sizes, int n_in,
                              void* d_out, int out_size, void* d_ws, size_t ws_size,
                              hipStream_t stream) {
  (void)in_sizes; (void)n_in; (void)out_size; (void)ws_size;
  const float* x       = (const float*)d_in[0];
  const float* kern    = (const float*)d_in[3];
  const float* ln_g    = (const float*)d_in[4];
  const float* ln_b    = (const float*)d_in[5];
  const float* kv_w    = (const float*)d_in[6];
  const float* proj_w  = (const float*)d_in[7];
  const float* proj_b  = (const float*)d_in[8];
  const float* projq_w = (const float*)d_in[9];
  const float* n1_g    = (const float*)d_in[10];
  const float* n1_b    = (const float*)d_in[11];
  const float* n2_g    = (const float*)d_in[12];
  const float* n2_b    = (const float*)d_in[13];
  const float* pm1_w   = (const float*)d_in[14];
  const float* pm1_b   = (const float*)d_in[15];
  const float* pm2_w   = (const float*)d_in[16];
  const float* pm2_b   = (const float*)d_in[17];
  const float* cm1_w   = (const float*)d_in[18];
  const float* cm1_b   = (const float*)d_in[19];
  const float* cm2_w   = (const float*)d_in[20];
  const float* cm2_b   = (const float*)d_in[21];
  float* out = (float*)d_out;

  uint8_t* ws = (uint8_t*)d_ws;
  short* Wt   = (short*)(ws);                    // 3,538,944 (dead after GEMM)
  short* h1   = (short*)(ws);                    // ALIAS: 884,736
  short* big  = (short*)(ws + 3538944);          // 150,994,944
  float* wm   = (float*)(ws + 154533888);        // 27,648
  short* cab  = (short*)(ws + 154561536);        // 442,368
  float* w1   = (float*)(ws + 155446272);        // 884,736
  short* ln1b = (short*)(ws + 156331008);        // 442,368
  short* ln2b = (short*)(ws + 156773376);        // 442,368 -> 157,215,744

  short* xb    = (short*)d_out;
  float* tpart = (float*)d_out;                  // 7,077,888 B
  short* Wc1T  = (short*)((uint8_t*)d_out + 8388608);   // [1536][768]
  short* Wc2T  = (short*)((uint8_t*)d_out + 11534336);  // [768][1536]
  short* WpT   = (short*)((uint8_t*)d_out + 14680064);  // [768][768]

  prep_kernel<<<dim3(MM * CC / (256 * 8) + 72 * 24), 256, 0, stream>>>(
      x, xb, kv_w, projq_w, Wt);
  gemm_bt_kernel<<<dim3((MM / 128) * (KNN / 128)), 256, 0, stream>>>(xb, Wt, big);
  wtrans2_kernel<<<dim3(2880), 256, 0, stream>>>(proj_w, cm1_w, cm2_w, WpT, Wc1T, Wc2T);
  row_ln_kernel<<<dim3(KKK), 256, 0, stream>>>(kern, wm, ln_g, ln_b, 1e-6f);
  attn_kernel<<<dim3(BB, NHH), 256, 0, stream>>>(wm, big, cab);
  mfma96_kernel<0><<<dim3(3, 6), 256, 0, stream>>>(cab, WpT, CC, CC,
                                                   proj_b, kern, w1, nullptr);
  row_ln_bf_kernel<<<dim3(BB * KKK), 256, 0, stream>>>(w1, ln1b, n1_g, n1_b, 1e-5f);
  token_mix_kernel<<<dim3(3, 32, 8), 256, 0, stream>>>(ln1b, pm1_w, pm1_b, pm2_w, tpart);
  token_reduce_ln_kernel<<<dim3(BB * KKK), 256, 0, stream>>>(tpart, pm2_b,
                                                             n2_g, n2_b, w1, ln2b);
  mfma96_kernel<1><<<dim3(3, 12), 256, 0, stream>>>(ln2b, Wc1T, CC, CMDD,
                                                    cm1_b, nullptr, nullptr, h1);
  mfma96_kernel<2><<<dim3(3, 6), 256, 0, stream>>>(h1, Wc2T, CMDD, CC,
                                                   cm2_b, nullptr, w1, nullptr);
  conv_lds_kernel<<<dim3(6, 32, 4), 256, 0, stream>>>(big, w1, out);
}

// Round 10
// 422.339 us; speedup vs baseline: 3.5836x; 1.1298x over previous
//
#include <hip/hip_runtime.h>
#include <hip/hip_bf16.h>
#include <cstdint>
#include <cstddef>

typedef __attribute__((ext_vector_type(8))) short bf16x8;
typedef __attribute__((ext_vector_type(4))) float f32x4;

#define BB 32
#define NN 1024
#define CC 768
#define NHH 12
#define HDD 64
#define KKK 9
#define MM (BB * NN)   /* 32768 */
#define KNN (3 * CC)   /* 2304 = 2C (kv) + C (xq) */
#define PMDD 1536
#define CMDD 1536
#define BK 64

#define XBF_BLOCKS 12288   /* MM*CC/(256*8) */
#define WT_BLOCKS 1728     /* 72*24 */
#define WT2_BLOCKS 2880
#define WM_BLOCKS 9

__device__ __forceinline__ float bfbits2f(short s) {
  union { uint32_t u; float f; } cv;
  cv.u = ((uint32_t)(uint16_t)s) << 16;
  return cv.f;
}
__device__ __forceinline__ short f2bf(float f) {
  union { float f; uint32_t u; } cv;
  cv.f = f;
  uint32_t u = cv.u;
  uint32_t r = (u + 0x7fffu + ((u >> 16) & 1u)) >> 16;
  return (short)r;
}
__device__ __forceinline__ float gelu_f(float x) {
  return 0.5f * x * (1.0f + erff(x * 0.7071067811865476f));
}

typedef const __attribute__((address_space(1))) uint32_t* gp1_t;
typedef __attribute__((address_space(3))) uint32_t* lp3_t;
__device__ __forceinline__ void gload16(const short* g, const short* l) {
  __builtin_amdgcn_global_load_lds((gp1_t)(uintptr_t)(const void*)g,
                                   (lp3_t)(uint32_t)(uintptr_t)(const void*)l,
                                   16, 0, 0);
}

// ---- prep: x->bf16 + Wt transpose + small-W transposes + wm LayerNorm -----
__global__ __launch_bounds__(256) void prep_kernel(
    const float* __restrict__ x, short* __restrict__ xb,
    const float* __restrict__ kv_w, const float* __restrict__ projq_w,
    short* __restrict__ Wt,
    const float* __restrict__ proj_w, const float* __restrict__ cm1_w,
    const float* __restrict__ cm2_w,
    short* __restrict__ WpT, short* __restrict__ Wc1T, short* __restrict__ Wc2T,
    const float* __restrict__ kern, const float* __restrict__ ln_g,
    const float* __restrict__ ln_b, float* __restrict__ wm)
{
  __shared__ float smem[32 * 33];
  const int bx = blockIdx.x;
  const int tid = threadIdx.x;
  if (bx < XBF_BLOCKS) {
    const int i = (bx * 256 + tid) * 8;
    f32x4 a = *(const f32x4*)&x[i];
    f32x4 b = *(const f32x4*)&x[i + 4];
    bf16x8 o;
#pragma unroll
    for (int e = 0; e < 4; e++) { o[e] = f2bf(a[e]); o[e + 4] = f2bf(b[e]); }
    *(bf16x8*)&xb[i] = o;
    return;
  }
  if (bx < XBF_BLOCKS + WT_BLOCKS + WT2_BLOCKS) {
    // tiled bf16 transpose
    const float* src; short* dst; int ldj, ldc, j0, c0;
    if (bx < XBF_BLOCKS + WT_BLOCKS) {
      int b2 = bx - XBF_BLOCKS;
      j0 = (b2 % 72) * 32; c0 = (b2 / 72) * 32; ldc = CC; dst = Wt;
      if (j0 < 2 * CC) { src = kv_w; ldj = 2 * CC; }
      else             { src = projq_w; ldj = CC; j0 -= 2 * CC; dst = Wt + 2 * CC * CC; }
      // note: dst row offset handled below via (j0 + jl); re-add base:
      // simpler: recompute absolute j for Wt
      const int tx = tid & 31, ty = tid >> 5;
#pragma unroll
      for (int r = 0; r < 4; r++) {
        int cl = ty + r * 8;
        smem[cl * 33 + tx] = src[(size_t)(c0 + cl) * ldj + j0 + tx];
      }
      __syncthreads();
#pragma unroll
      for (int r = 0; r < 4; r++) {
        int jl = ty + r * 8;
        dst[(size_t)(j0 + jl) * CC + c0 + tx] = f2bf(smem[tx * 33 + jl]);
      }
      return;
    }
    int b2 = bx - XBF_BLOCKS - WT_BLOCKS;
    if (b2 < 576)        { src = proj_w; dst = WpT;  ldj = 768;  ldc = 768;
                           j0 = (b2 % 24) * 32; c0 = (b2 / 24) * 32; }
    else if (b2 < 1728)  { b2 -= 576; src = cm1_w; dst = Wc1T; ldj = 1536; ldc = 768;
                           j0 = (b2 % 48) * 32; c0 = (b2 / 48) * 32; }
    else                 { b2 -= 1728; src = cm2_w; dst = Wc2T; ldj = 768; ldc = 1536;
                           j0 = (b2 % 24) * 32; c0 = (b2 / 24) * 32; }
    const int tx = tid & 31, ty = tid >> 5;
#pragma unroll
    for (int r = 0; r < 4; r++) {
      int cl = ty + r * 8;
      smem[cl * 33 + tx] = src[(size_t)(c0 + cl) * ldj + j0 + tx];
    }
    __syncthreads();
#pragma unroll
    for (int r = 0; r < 4; r++) {
      int jl = ty + r * 8;
      dst[(size_t)(j0 + jl) * ldc + c0 + tx] = f2bf(smem[tx * 33 + jl]);
    }
    return;
  }
  // wm = LayerNorm(kern) rows
  {
    float* red = smem;
    const int row = bx - (XBF_BLOCKS + WT_BLOCKS + WT2_BLOCKS);
    const size_t base = (size_t)row * CC;
    float x0 = kern[base + tid];
    float x1 = kern[base + tid + 256];
    float x2 = kern[base + tid + 512];
    red[tid] = x0 + x1 + x2;
    __syncthreads();
    for (int st = 128; st > 0; st >>= 1) { if (tid < st) red[tid] += red[tid + st]; __syncthreads(); }
    float mean = red[0] * (1.0f / 768.0f);
    __syncthreads();
    float d0 = x0 - mean, d1 = x1 - mean, d2 = x2 - mean;
    red[tid] = d0 * d0 + d1 * d1 + d2 * d2;
    __syncthreads();
    for (int st = 128; st > 0; st >>= 1) { if (tid < st) red[tid] += red[tid + st]; __syncthreads(); }
    float rstd = rsqrtf(red[0] * (1.0f / 768.0f) + 1e-6f);
    wm[base + tid]       = d0 * rstd * ln_g[tid]       + ln_b[tid];
    wm[base + tid + 256] = d1 * rstd * ln_g[tid + 256] + ln_b[tid + 256];
    wm[base + tid + 512] = d2 * rstd * ln_g[tid + 512] + ln_b[tid + 512];
  }
}

// ---------------- big GEMM: 128x128, BK=64, swizzled (proven) --------------
__global__ __launch_bounds__(256) void gemm_bt_kernel(
    const short* __restrict__ A,     // [MM][768] bf16
    const short* __restrict__ Bt,    // [2304][768] bf16 (B^T)
    short* __restrict__ C)           // [MM][2304] bf16
{
  __shared__ short As[128 * BK];
  __shared__ short Bs[128 * BK];
  const int tid = threadIdx.x;
  const int wave = tid >> 6, lane = tid & 63;
  const int lid = blockIdx.x;
  const int wid = (lid & 7) * 576 + (lid >> 3);
  const int bn = (wid % 18) * 128;
  const int bm = (wid / 18) * 128;
  const int wmo = (wave >> 1) * 64;
  const int wno = (wave & 1) * 64;
  const int lrow = lane & 15;
  const int kgrp = lane >> 4;
  const int sr = tid >> 3;
  const int ss = tid & 7;
  const int slotG = ss ^ (sr & 7);
  const short* gA = A + (size_t)(bm + sr) * CC + slotG * 8;
  const short* gB = Bt + (size_t)(bn + sr) * CC + slotG * 8;
  const short* lA = &As[sr * BK + ss * 8];
  const short* lB = &Bs[sr * BK + ss * 8];
  const int rs0 = kgrp ^ (lrow & 7);
  const int rs1 = (4 + kgrp) ^ (lrow & 7);
  f32x4 acc[4][4];
#pragma unroll
  for (int i = 0; i < 4; i++)
#pragma unroll
    for (int j = 0; j < 4; j++) acc[i][j] = (f32x4){0.f, 0.f, 0.f, 0.f};
  for (int k0 = 0; k0 < CC; k0 += BK) {
    __syncthreads();
#pragma unroll
    for (int i = 0; i < 4; i++) {
      gload16(gA + (size_t)(i * 32) * CC + k0, lA + i * 32 * BK);
      gload16(gB + (size_t)(i * 32) * CC + k0, lB + i * 32 * BK);
    }
    __syncthreads();
#pragma unroll
    for (int kh = 0; kh < 2; kh++) {
      const int rs = kh ? rs1 : rs0;
      bf16x8 af[4], bfr[4];
#pragma unroll
      for (int i = 0; i < 4; i++)
        af[i] = *(const bf16x8*)&As[(wmo + i * 16 + lrow) * BK + rs * 8];
#pragma unroll
      for (int j = 0; j < 4; j++)
        bfr[j] = *(const bf16x8*)&Bs[(wno + j * 16 + lrow) * BK + rs * 8];
#pragma unroll
      for (int i = 0; i < 4; i++)
#pragma unroll
        for (int j = 0; j < 4; j++)
          acc[i][j] = __builtin_amdgcn_mfma_f32_16x16x32_bf16(af[i], bfr[j], acc[i][j], 0, 0, 0);
    }
  }
#pragma unroll
  for (int i = 0; i < 4; i++)
#pragma unroll
    for (int j = 0; j < 4; j++)
#pragma unroll
      for (int r = 0; r < 4; r++) {
        const int row = bm + wmo + i * 16 + kgrp * 4 + r;
        const int col = bn + wno + j * 16 + lrow;
        C[(size_t)row * KNN + col] = f2bf(acc[i][j][r]);
      }
}

// ---------------- mini MFMA GEMM: M-tile 96, N-tile 128, BK=64 -------------
template <int EP>
__global__ __launch_bounds__(256) void mfma96_kernel(
    const short* __restrict__ A,    // [288][K] bf16
    const short* __restrict__ Bt,   // [N][K] bf16
    int K, int ldn,
    const float* __restrict__ bias, // [ldn]
    const float* __restrict__ kern, // EP0
    float* __restrict__ Cf,
    short* __restrict__ Cb)
{
  __shared__ short As[96 * BK];
  __shared__ short Bs[128 * BK];
  const int tid = threadIdx.x;
  const int wave = tid >> 6, lane = tid & 63;
  const int bm = blockIdx.x * 96;
  const int bn = blockIdx.y * 128;
  const int wmo = (wave >> 1) * 48;
  const int wno = (wave & 1) * 64;
  const int lrow = lane & 15;
  const int kgrp = lane >> 4;
  const int sr = tid >> 3;
  const int ss = tid & 7;
  const int rs0 = kgrp ^ (lrow & 7);
  const int rs1 = (4 + kgrp) ^ (lrow & 7);
  f32x4 acc[3][4];
#pragma unroll
  for (int i = 0; i < 3; i++)
#pragma unroll
    for (int j = 0; j < 4; j++) acc[i][j] = (f32x4){0.f, 0.f, 0.f, 0.f};
  for (int k0 = 0; k0 < K; k0 += BK) {
    __syncthreads();
#pragma unroll
    for (int i = 0; i < 3; i++) {
      const int r = i * 32 + sr;
      const int sg = ss ^ (r & 7);
      gload16(A + (size_t)(bm + r) * K + k0 + sg * 8, &As[r * BK + ss * 8]);
    }
#pragma unroll
    for (int i = 0; i < 4; i++) {
      const int r = i * 32 + sr;
      const int sg = ss ^ (r & 7);
      gload16(Bt + (size_t)(bn + r) * K + k0 + sg * 8, &Bs[r * BK + ss * 8]);
    }
    __syncthreads();
#pragma unroll
    for (int kh = 0; kh < 2; kh++) {
      const int rs = kh ? rs1 : rs0;
      bf16x8 af[3], bfr[4];
#pragma unroll
      for (int m = 0; m < 3; m++)
        af[m] = *(const bf16x8*)&As[(wmo + m * 16 + lrow) * BK + rs * 8];
#pragma unroll
      for (int n = 0; n < 4; n++)
        bfr[n] = *(const bf16x8*)&Bs[(wno + n * 16 + lrow) * BK + rs * 8];
#pragma unroll
      for (int m = 0; m < 3; m++)
#pragma unroll
        for (int n = 0; n < 4; n++)
          acc[m][n] = __builtin_amdgcn_mfma_f32_16x16x32_bf16(af[m], bfr[n], acc[m][n], 0, 0, 0);
    }
  }
#pragma unroll
  for (int m = 0; m < 3; m++)
#pragma unroll
    for (int n = 0; n < 4; n++)
#pragma unroll
      for (int r = 0; r < 4; r++) {
        const int row = bm + wmo + m * 16 + kgrp * 4 + r;
        const int col = bn + wno + n * 16 + lrow;
        float v = acc[m][n][r] + bias[col];
        if (EP == 0) Cf[(size_t)row * ldn + col] = v + kern[(row % KKK) * ldn + col];
        if (EP == 1) Cb[(size_t)row * ldn + col] = f2bf(gelu_f(v));
        if (EP == 2) Cf[(size_t)row * ldn + col] += v;
      }
}

// ---------------- row LayerNorm (fp32 in, bf16 out) ------------------------
__global__ __launch_bounds__(256) void row_ln_bf_kernel(
    const float* __restrict__ in, short* __restrict__ out,
    const float* __restrict__ g, const float* __restrict__ bb, float eps)
{
  const int row = blockIdx.x;
  const int tid = threadIdx.x;
  __shared__ float red[256];
  const size_t base = (size_t)row * CC;
  float x0 = in[base + tid];
  float x1 = in[base + tid + 256];
  float x2 = in[base + tid + 512];
  red[tid] = x0 + x1 + x2;
  __syncthreads();
  for (int st = 128; st > 0; st >>= 1) { if (tid < st) red[tid] += red[tid + st]; __syncthreads(); }
  float mean = red[0] * (1.0f / 768.0f);
  __syncthreads();
  float d0 = x0 - mean, d1 = x1 - mean, d2 = x2 - mean;
  red[tid] = d0 * d0 + d1 * d1 + d2 * d2;
  __syncthreads();
  for (int st = 128; st > 0; st >>= 1) { if (tid < st) red[tid] += red[tid + st]; __syncthreads(); }
  float rstd = rsqrtf(red[0] * (1.0f / 768.0f) + eps);
  out[base + tid]       = f2bf(d0 * rstd * g[tid]       + bb[tid]);
  out[base + tid + 256] = f2bf(d1 * rstd * g[tid + 256] + bb[tid + 256]);
  out[base + tid + 512] = f2bf(d2 * rstd * g[tid + 512] + bb[tid + 512]);
}

// ---------------- attention: low-LDS-instruction version -------------------
__global__ __launch_bounds__(256) void attn_kernel(
    const float* __restrict__ wm,       // [9][768] fp32 (read via s_load)
    const short* __restrict__ big,      // [32768][2304] bf16 (kv | xq)
    short* __restrict__ ca)             // [32][9][768] bf16
{
  const int b = blockIdx.x;
  const int h = blockIdx.y;
  const int tid = threadIdx.x;
  const int wave = tid >> 6, lane = tid & 63;
  __shared__ float sc[KKK][NN];
  __shared__ float part[4][KKK][HDD];
  // ---- scores: 4-n register blocking; wm reads are wave-uniform (s_load)
  {
    const short* kbase = &big[(size_t)(b * NN) * KNN + h * HDD];
    const float* wmh = &wm[h * HDD];
    float acc[4][KKK];
#pragma unroll
    for (int nn = 0; nn < 4; nn++)
#pragma unroll
      for (int q = 0; q < KKK; q++) acc[nn][q] = 0.f;
    for (int d0 = 0; d0 < HDD; d0 += 8) {
      float kf[4][8];
#pragma unroll
      for (int nn = 0; nn < 4; nn++) {
        bf16x8 v = *(const bf16x8*)&kbase[(size_t)(tid + nn * 256) * KNN + d0];
#pragma unroll
        for (int e = 0; e < 8; e++) kf[nn][e] = bfbits2f(v[e]);
      }
#pragma unroll
      for (int e = 0; e < 8; e++)
#pragma unroll
        for (int q = 0; q < KKK; q++) {
          float w = wmh[q * CC + d0 + e];   // uniform -> scalar load
          acc[0][q] += w * kf[0][e];
          acc[1][q] += w * kf[1][e];
          acc[2][q] += w * kf[2][e];
          acc[3][q] += w * kf[3][e];
        }
    }
#pragma unroll
    for (int nn = 0; nn < 4; nn++)
#pragma unroll
      for (int q = 0; q < KKK; q++) sc[q][tid + nn * 256] = acc[nn][q] * 0.125f;
  }
  __syncthreads();
  // ---- softmax: wave-parallel, shuffle reductions
  for (int q = wave; q < KKK; q += 4) {
    float m = -1e30f;
#pragma unroll
    for (int i = 0; i < 16; i++) m = fmaxf(m, sc[q][lane + i * 64]);
#pragma unroll
    for (int off = 32; off > 0; off >>= 1) m = fmaxf(m, __shfl_xor(m, off));
    float s = 0.f;
#pragma unroll
    for (int i = 0; i < 16; i++) {
      float e = expf(sc[q][lane + i * 64] - m);
      sc[q][lane + i * 64] = e;
      s += e;
    }
#pragma unroll
    for (int off = 32; off > 0; off >>= 1) s += __shfl_xor(s, off);
    float inv = 1.0f / s;
#pragma unroll
    for (int i = 0; i < 16; i++) sc[q][lane + i * 64] *= inv;
  }
  __syncthreads();
  // ---- PV: b128 broadcast reads of sc (4 n per read)
  const int d = tid & 63, prt = tid >> 6;
  float po[KKK];
#pragma unroll
  for (int q = 0; q < KKK; q++) po[q] = 0.f;
  const short* vbase = &big[(size_t)(b * NN) * KNN + CC + h * HDD + d];
  for (int n0 = prt * 256; n0 < prt * 256 + 256; n0 += 4) {
    f32x4 p[KKK];
#pragma unroll
    for (int q = 0; q < KKK; q++) p[q] = *(const f32x4*)&sc[q][n0];
#pragma unroll
    for (int j = 0; j < 4; j++) {
      float vf = bfbits2f(vbase[(size_t)(n0 + j) * KNN]);
#pragma unroll
      for (int q = 0; q < KKK; q++) po[q] += p[q][j] * vf;
    }
  }
#pragma unroll
  for (int q = 0; q < KKK; q++) part[prt][q][d] = po[q];
  __syncthreads();
  for (int i = tid; i < KKK * HDD; i += 256) {
    int q = i >> 6, dd = i & 63;
    ca[(size_t)(b * KKK + q) * CC + h * HDD + dd] =
        f2bf(part[0][q][dd] + part[1][q][dd] + part[2][q][dd] + part[3][q][dd]);
  }
}

// ---------------- token mixer (bf16 input) ---------------------------------
__global__ __launch_bounds__(256) void token_mix_kernel(
    const short* __restrict__ ln1,     // [288][768] bf16
    const float* __restrict__ pm1_w,   // [9][1536]
    const float* __restrict__ pm1_b,   // [1536]
    const float* __restrict__ pm2_w,   // [1536][9]
    float* __restrict__ part)          // [8][32][9][768]
{
  const int tid = threadIdx.x;
  const int c = blockIdx.x * 256 + tid;
  const int b = blockIdx.y;
  const int jc = blockIdx.z;
  float u[KKK], o[KKK];
#pragma unroll
  for (int q = 0; q < KKK; q++) {
    u[q] = bfbits2f(ln1[(size_t)(b * KKK + q) * CC + c]);
    o[q] = 0.f;
  }
  const int j0 = jc * (PMDD / 8);
  for (int j = j0; j < j0 + PMDD / 8; j++) {
    float hs = pm1_b[j];
#pragma unroll
    for (int q = 0; q < KKK; q++) hs += u[q] * pm1_w[q * PMDD + j];
    float gv = gelu_f(hs);
    const float* p2 = &pm2_w[(size_t)j * KKK];
#pragma unroll
    for (int q = 0; q < KKK; q++) o[q] += gv * p2[q];
  }
  float* pp = &part[(size_t)((jc * BB + b) * KKK) * CC + c];
#pragma unroll
  for (int q = 0; q < KKK; q++) pp[(size_t)q * CC] = o[q];
}

// ---------------- token reduce + LN2 (bf16 LN output) ----------------------
__global__ __launch_bounds__(256) void token_reduce_ln_kernel(
    const float* __restrict__ part,    // [8][32][9][768]
    const float* __restrict__ pm2_b,   // [9]
    const float* __restrict__ g, const float* __restrict__ bb,
    float* __restrict__ w1,            // [288][768] (in/out)
    short* __restrict__ lnb)           // [288][768] bf16
{
  const int row = blockIdx.x;
  const int q = row % KKK;
  const int tid = threadIdx.x;
  __shared__ float red[256];
  const size_t base = (size_t)row * CC;
  float v[3];
#pragma unroll
  for (int j = 0; j < 3; j++) {
    const int c = tid + j * 256;
    float s = 0.f;
#pragma unroll
    for (int gg = 0; gg < 8; gg++)
      s += part[(size_t)gg * BB * KKK * CC + base + c];
    v[j] = w1[base + c] + s + pm2_b[q];
    w1[base + c] = v[j];
  }
  red[tid] = v[0] + v[1] + v[2];
  __syncthreads();
  for (int st = 128; st > 0; st >>= 1) { if (tid < st) red[tid] += red[tid + st]; __syncthreads(); }
  float mean = red[0] * (1.0f / 768.0f);
  __syncthreads();
  float d0 = v[0] - mean, d1 = v[1] - mean, d2 = v[2] - mean;
  red[tid] = d0 * d0 + d1 * d1 + d2 * d2;
  __syncthreads();
  for (int st = 128; st > 0; st >>= 1) { if (tid < st) red[tid] += red[tid + st]; __syncthreads(); }
  float rstd = rsqrtf(red[0] * (1.0f / 768.0f) + 1e-5f);
  lnb[base + tid]       = f2bf(d0 * rstd * g[tid]       + bb[tid]);
  lnb[base + tid + 256] = f2bf(d1 * rstd * g[tid + 256] + bb[tid + 256]);
  lnb[base + tid + 512] = f2bf(d2 * rstd * g[tid + 512] + bb[tid + 512]);
}

// ---------------- conv: LDS-staged read-once, sliding window ---------------
__global__ __launch_bounds__(256) void conv_lds_kernel(
    const short* __restrict__ big,   // xq (bf16) at column offset 1536
    const float* __restrict__ w1,    // [32][9][768] filters
    float* __restrict__ out)         // [32][1024][768] fp32
{
  __shared__ short rows[3][32][132];
  const int c0 = blockIdx.x * 128;
  const int b = blockIdx.y;
  const int y0 = blockIdx.z * 8;
  const int tid = threadIdx.x;
  const int xl = tid >> 3, cg = tid & 7;
  const int cl = tid & 127, xh = tid >> 7;
  float f[KKK];
#pragma unroll
  for (int q = 0; q < KKK; q++) f[q] = w1[(size_t)(b * KKK + q) * CC + c0 + cl];

#define LOAD_ROW(yy, slot)                                                     \
  {                                                                            \
    short* dst = &rows[slot][xl][cg * 16];                                     \
    if ((yy) >= 0 && (yy) < 32) {                                              \
      const short* src =                                                       \
          &big[(size_t)(b * NN + (yy) * 32 + xl) * KNN + 2 * CC + c0 + cg * 16];\
      *(bf16x8*)dst = *(const bf16x8*)src;                                     \
      *(bf16x8*)(dst + 8) = *(const bf16x8*)(src + 8);                         \
    } else {                                                                   \
      bf16x8 z = {0, 0, 0, 0, 0, 0, 0, 0};                                     \
      *(bf16x8*)dst = z;                                                       \
      *(bf16x8*)(dst + 8) = z;                                                 \
    }                                                                          \
  }

  int sPrev = 0, sCur = 1, sNext = 2;
  LOAD_ROW(y0 - 1, 0);
  LOAD_ROW(y0, 1);
  for (int y = y0; y < y0 + 8; ++y) {
    LOAD_ROW(y + 1, sNext);
    __syncthreads();
    const int xb = xh * 16;
    float v0[3], v1[3];
#pragma unroll
    for (int ky = 0; ky < 3; ky++) {
      const int s = (ky == 0) ? sPrev : (ky == 1 ? sCur : sNext);
      v1[ky] = bfbits2f(rows[s][xb][cl]);
      v0[ky] = (xb == 0) ? 0.f : bfbits2f(rows[s][xb - 1][cl]);
    }
    float* op = &out[(size_t)(b * NN + y * 32 + xb) * CC + c0 + cl];
#pragma unroll
    for (int i = 0; i < 16; i++) {
      const int x = xb + i;
      float v2[3];
#pragma unroll
      for (int ky = 0; ky < 3; ky++) {
        const int s = (ky == 0) ? sPrev : (ky == 1 ? sCur : sNext);
        v2[ky] = (x + 1 < 32) ? bfbits2f(rows[s][x + 1][cl]) : 0.f;
      }
      float acc = 0.f;
#pragma unroll
      for (int ky = 0; ky < 3; ky++)
        acc += f[ky * 3] * v0[ky] + f[ky * 3 + 1] * v1[ky] + f[ky * 3 + 2] * v2[ky];
      op[(size_t)i * CC] = acc;
#pragma unroll
      for (int ky = 0; ky < 3; ky++) { v0[ky] = v1[ky]; v1[ky] = v2[ky]; }
    }
    __syncthreads();
    const int t = sPrev; sPrev = sCur; sCur = sNext; sNext = t;
  }
#undef LOAD_ROW
}

// ---------------------------------------------------------------------------
extern "C" void kernel_launch(void* const* d_in, const int* in_sizes, int n_in,
                              void* d_out, int out_size, void* d_ws, size_t ws_size,
                              hipStream_t stream) {
  (void)in_sizes; (void)n_in; (void)out_size; (void)ws_size;
  const float* x       = (const float*)d_in[0];
  const float* kern    = (const float*)d_in[3];
  const float* ln_g    = (const float*)d_in[4];
  const float* ln_b    = (const float*)d_in[5];
  const float* kv_w    = (const float*)d_in[6];
  const float* proj_w  = (const float*)d_in[7];
  const float* proj_b  = (const float*)d_in[8];
  const float* projq_w = (const float*)d_in[9];
  const float* n1_g    = (const float*)d_in[10];
  const float* n1_b    = (const float*)d_in[11];
  const float* n2_g    = (const float*)d_in[12];
  const float* n2_b    = (const float*)d_in[13];
  const float* pm1_w   = (const float*)d_in[14];
  const float* pm1_b   = (const float*)d_in[15];
  const float* pm2_w   = (const float*)d_in[16];
  const float* pm2_b   = (const float*)d_in[17];
  const float* cm1_w   = (const float*)d_in[18];
  const float* cm1_b   = (const float*)d_in[19];
  const float* cm2_w   = (const float*)d_in[20];
  const float* cm2_b   = (const float*)d_in[21];
  float* out = (float*)d_out;

  uint8_t* ws = (uint8_t*)d_ws;
  short* Wt   = (short*)(ws);                    // 3,538,944 (dead after GEMM)
  short* h1   = (short*)(ws);                    // ALIAS: 884,736
  short* big  = (short*)(ws + 3538944);          // 150,994,944
  float* wm   = (float*)(ws + 154533888);        // 27,648
  short* cab  = (short*)(ws + 154561536);        // 442,368
  float* w1   = (float*)(ws + 155446272);        // 884,736
  short* ln1b = (short*)(ws + 156331008);        // 442,368
  short* ln2b = (short*)(ws + 156773376);        // 442,368 -> 157,215,744

  // d_out scratch map (out = 100.7 MB):
  //  [0, 50.3MB): xb (bf16 x) until GEMM; then tpart [0, 7.1MB) during token_mix
  //  [60MB, 69MB): WpT / Wc1T / Wc2T (written by prep, read by minis)
  short* xb    = (short*)d_out;
  float* tpart = (float*)d_out;
  short* WpT   = (short*)((uint8_t*)d_out + 62914560);  // [768][768]   1.18 MB
  short* Wc1T  = (short*)((uint8_t*)d_out + 64094208);  // [1536][768]  2.36 MB
  short* Wc2T  = (short*)((uint8_t*)d_out + 66453504);  // [768][1536]  2.36 MB

  prep_kernel<<<dim3(XBF_BLOCKS + WT_BLOCKS + WT2_BLOCKS + WM_BLOCKS), 256, 0, stream>>>(
      x, xb, kv_w, projq_w, Wt, proj_w, cm1_w, cm2_w, WpT, Wc1T, Wc2T,
      kern, ln_g, ln_b, wm);
  gemm_bt_kernel<<<dim3((MM / 128) * (KNN / 128)), 256, 0, stream>>>(xb, Wt, big);
  attn_kernel<<<dim3(BB, NHH), 256, 0, stream>>>(wm, big, cab);
  mfma96_kernel<0><<<dim3(3, 6), 256, 0, stream>>>(cab, WpT, CC, CC,
                                                   proj_b, kern, w1, nullptr);
  row_ln_bf_kernel<<<dim3(BB * KKK), 256, 0, stream>>>(w1, ln1b, n1_g, n1_b, 1e-5f);
  token_mix_kernel<<<dim3(3, 32, 8), 256, 0, stream>>>(ln1b, pm1_w, pm1_b, pm2_w, tpart);
  token_reduce_ln_kernel<<<dim3(BB * KKK), 256, 0, stream>>>(tpart, pm2_b,
                                                             n2_g, n2_b, w1, ln2b);
  mfma96_kernel<1><<<dim3(3, 12), 256, 0, stream>>>(ln2b, Wc1T, CC, CMDD,
                                                    cm1_b, nullptr, nullptr, h1);
  mfma96_kernel<2><<<dim3(3, 6), 256, 0, stream>>>(h1, Wc2T, CMDD, CC,
                                                   cm2_b, nullptr, w1, nullptr);
  conv_lds_kernel<<<dim3(6, 32, 4), 256, 0, stream>>>(big, w1, out);
}

// Round 11
// 389.495 us; speedup vs baseline: 3.8858x; 1.0843x over previous
//
#include <hip/hip_runtime.h>
#include <hip/hip_bf16.h>
#include <cstdint>
#include <cstddef>

typedef __attribute__((ext_vector_type(8))) short bf16x8;
typedef __attribute__((ext_vector_type(4))) float f32x4;

#define BB 32
#define NN 1024
#define CC 768
#define NHH 12
#define HDD 64
#define KKK 9
#define MM (BB * NN)   /* 32768 */
#define KN2 1664       /* v(768) | xq(768) | scores(108 pad 128) */
#define PMDD 1536
#define CMDD 1536
#define BK 64

#define XBF_BLOCKS 12288   /* MM*CC/(256*8) */
#define WT_BLOCKS 1152     /* 48 j-tiles x 24 c-tiles (v+xq = 1536 rows) */
#define WT2_BLOCKS 2880
#define SW_BLOCKS 128      /* 108 score rows + 20 zero-pad rows */

__device__ __forceinline__ float bfbits2f(short s) {
  union { uint32_t u; float f; } cv;
  cv.u = ((uint32_t)(uint16_t)s) << 16;
  return cv.f;
}
__device__ __forceinline__ short f2bf(float f) {
  union { float f; uint32_t u; } cv;
  cv.f = f;
  uint32_t u = cv.u;
  uint32_t r = (u + 0x7fffu + ((u >> 16) & 1u)) >> 16;
  return (short)r;
}
__device__ __forceinline__ float gelu_f(float x) {
  return 0.5f * x * (1.0f + erff(x * 0.7071067811865476f));
}

typedef const __attribute__((address_space(1))) uint32_t* gp1_t;
typedef __attribute__((address_space(3))) uint32_t* lp3_t;
__device__ __forceinline__ void gload16(const short* g, const short* l) {
  __builtin_amdgcn_global_load_lds((gp1_t)(uintptr_t)(const void*)g,
                                   (lp3_t)(uint32_t)(uintptr_t)(const void*)l,
                                   16, 0, 0);
}

// ---- prep: x->bf16 + Wt build (v^T|xq^T|S_w) + small-W transposes ---------
__global__ __launch_bounds__(256) void prep_kernel(
    const float* __restrict__ x, short* __restrict__ xb,
    const float* __restrict__ kv_w, const float* __restrict__ projq_w,
    short* __restrict__ Wt,
    const float* __restrict__ proj_w, const float* __restrict__ cm1_w,
    const float* __restrict__ cm2_w,
    short* __restrict__ WpT, short* __restrict__ Wc1T, short* __restrict__ Wc2T,
    const float* __restrict__ kern, const float* __restrict__ ln_g,
    const float* __restrict__ ln_b)
{
  __shared__ float smem[1056];
  const int bx = blockIdx.x;
  const int tid = threadIdx.x;
  if (bx < XBF_BLOCKS) {
    const int i = (bx * 256 + tid) * 8;
    f32x4 a = *(const f32x4*)&x[i];
    f32x4 b = *(const f32x4*)&x[i + 4];
    bf16x8 o;
#pragma unroll
    for (int e = 0; e < 4; e++) { o[e] = f2bf(a[e]); o[e + 4] = f2bf(b[e]); }
    *(bf16x8*)&xb[i] = o;
    return;
  }
  if (bx < XBF_BLOCKS + WT_BLOCKS) {
    // Wt rows 0..1535: v^T (kv_w cols 768..1535) then projq^T
    int b2 = bx - XBF_BLOCKS;
    int j0 = (b2 % 48) * 32;
    int c0 = (b2 / 48) * 32;
    const float* src; int ldj, jj;
    if (j0 < 768) { src = kv_w; ldj = 1536; jj = 768 + j0; }
    else          { src = projq_w; ldj = 768; jj = j0 - 768; }
    const int tx = tid & 31, ty = tid >> 5;
#pragma unroll
    for (int r = 0; r < 4; r++) {
      int cl = ty + r * 8;
      smem[cl * 33 + tx] = src[(size_t)(c0 + cl) * ldj + jj + tx];
    }
    __syncthreads();
#pragma unroll
    for (int r = 0; r < 4; r++) {
      int jl = ty + r * 8;
      Wt[(size_t)(j0 + jl) * CC + c0 + tx] = f2bf(smem[tx * 33 + jl]);
    }
    return;
  }
  if (bx < XBF_BLOCKS + WT_BLOCKS + WT2_BLOCKS) {
    int b2 = bx - XBF_BLOCKS - WT_BLOCKS;
    const float* src; short* dst; int ldj, ldc, j0, c0;
    if (b2 < 576)        { src = proj_w; dst = WpT;  ldj = 768;  ldc = 768;
                           j0 = (b2 % 24) * 32; c0 = (b2 / 24) * 32; }
    else if (b2 < 1728)  { b2 -= 576; src = cm1_w; dst = Wc1T; ldj = 1536; ldc = 768;
                           j0 = (b2 % 48) * 32; c0 = (b2 / 48) * 32; }
    else                 { b2 -= 1728; src = cm2_w; dst = Wc2T; ldj = 768; ldc = 1536;
                           j0 = (b2 % 24) * 32; c0 = (b2 / 24) * 32; }
    const int tx = tid & 31, ty = tid >> 5;
#pragma unroll
    for (int r = 0; r < 4; r++) {
      int cl = ty + r * 8;
      smem[cl * 33 + tx] = src[(size_t)(c0 + cl) * ldj + j0 + tx];
    }
    __syncthreads();
#pragma unroll
    for (int r = 0; r < 4; r++) {
      int jl = ty + r * 8;
      dst[(size_t)(j0 + jl) * ldc + c0 + tx] = f2bf(smem[tx * 33 + jl]);
    }
    return;
  }
  // SW blocks: Wt rows 1536+s = SCALE * (LN(kern)[q] row_h) @ Wk_h^T
  {
    const int s = bx - (XBF_BLOCKS + WT_BLOCKS + WT2_BLOCKS);
    if (s >= 108) {  // zero pad rows 1644..1663
      const size_t r = (size_t)(1536 + s) * CC;
      Wt[r + tid] = 0; Wt[r + tid + 256] = 0; Wt[r + tid + 512] = 0;
      return;
    }
    const int h = s / 9, q = s % 9;
    float* red = smem;
    const size_t base = (size_t)q * CC;
    float x0 = kern[base + tid];
    float x1 = kern[base + tid + 256];
    float x2 = kern[base + tid + 512];
    red[tid] = x0 + x1 + x2;
    __syncthreads();
    for (int st = 128; st > 0; st >>= 1) { if (tid < st) red[tid] += red[tid + st]; __syncthreads(); }
    float mean = red[0] * (1.0f / 768.0f);
    __syncthreads();
    float d0 = x0 - mean, d1 = x1 - mean, d2 = x2 - mean;
    red[tid] = d0 * d0 + d1 * d1 + d2 * d2;
    __syncthreads();
    for (int st = 128; st > 0; st >>= 1) { if (tid < st) red[tid] += red[tid + st]; __syncthreads(); }
    float rstd = rsqrtf(red[0] * (1.0f / 768.0f) + 1e-6f);
    __syncthreads();
    smem[tid]       = d0 * rstd * ln_g[tid]       + ln_b[tid];
    smem[tid + 256] = d1 * rstd * ln_g[tid + 256] + ln_b[tid + 256];
    smem[tid + 512] = d2 * rstd * ln_g[tid + 512] + ln_b[tid + 512];
    __syncthreads();
#pragma unroll
    for (int k = 0; k < 3; k++) {
      const int cc = tid + k * 256;
      const float* kw = &kv_w[(size_t)cc * 1536 + h * HDD];
      float acc = 0.f;
#pragma unroll
      for (int dd = 0; dd < HDD; dd++) acc += smem[h * HDD + dd] * kw[dd];
      Wt[(size_t)(1536 + s) * CC + cc] = f2bf(acc * 0.125f);
    }
  }
}

// ---------------- big GEMM: 128x128, BK=64, swizzled; N=1664 ---------------
__global__ __launch_bounds__(256) void gemm_bt_kernel(
    const short* __restrict__ A,     // [MM][768] bf16
    const short* __restrict__ Bt,    // [1664][768] bf16 (B^T)
    short* __restrict__ C,           // [MM][1664] bf16 (v|xq| n/a)
    float* __restrict__ scf)         // [MM][128] fp32 scores
{
  __shared__ short As[128 * BK];
  __shared__ short Bs[128 * BK];
  const int tid = threadIdx.x;
  const int wave = tid >> 6, lane = tid & 63;
  const int lid = blockIdx.x;                    // 3328 = 8 * 416
  const int wid = (lid & 7) * 416 + (lid >> 3);
  const int bn = (wid % 13) * 128;
  const int bm = (wid / 13) * 128;
  const int wmo = (wave >> 1) * 64;
  const int wno = (wave & 1) * 64;
  const int lrow = lane & 15;
  const int kgrp = lane >> 4;
  const int sr = tid >> 3;
  const int ss = tid & 7;
  const int slotG = ss ^ (sr & 7);
  const short* gA = A + (size_t)(bm + sr) * CC + slotG * 8;
  const short* gB = Bt + (size_t)(bn + sr) * CC + slotG * 8;
  const short* lA = &As[sr * BK + ss * 8];
  const short* lB = &Bs[sr * BK + ss * 8];
  const int rs0 = kgrp ^ (lrow & 7);
  const int rs1 = (4 + kgrp) ^ (lrow & 7);
  f32x4 acc[4][4];
#pragma unroll
  for (int i = 0; i < 4; i++)
#pragma unroll
    for (int j = 0; j < 4; j++) acc[i][j] = (f32x4){0.f, 0.f, 0.f, 0.f};
  for (int k0 = 0; k0 < CC; k0 += BK) {
    __syncthreads();
#pragma unroll
    for (int i = 0; i < 4; i++) {
      gload16(gA + (size_t)(i * 32) * CC + k0, lA + i * 32 * BK);
      gload16(gB + (size_t)(i * 32) * CC + k0, lB + i * 32 * BK);
    }
    __syncthreads();
#pragma unroll
    for (int kh = 0; kh < 2; kh++) {
      const int rs = kh ? rs1 : rs0;
      bf16x8 af[4], bfr[4];
#pragma unroll
      for (int i = 0; i < 4; i++)
        af[i] = *(const bf16x8*)&As[(wmo + i * 16 + lrow) * BK + rs * 8];
#pragma unroll
      for (int j = 0; j < 4; j++)
        bfr[j] = *(const bf16x8*)&Bs[(wno + j * 16 + lrow) * BK + rs * 8];
#pragma unroll
      for (int i = 0; i < 4; i++)
#pragma unroll
        for (int j = 0; j < 4; j++)
          acc[i][j] = __builtin_amdgcn_mfma_f32_16x16x32_bf16(af[i], bfr[j], acc[i][j], 0, 0, 0);
    }
  }
  if (bn < 1536) {
#pragma unroll
    for (int i = 0; i < 4; i++)
#pragma unroll
      for (int j = 0; j < 4; j++)
#pragma unroll
        for (int r = 0; r < 4; r++) {
          const int row = bm + wmo + i * 16 + kgrp * 4 + r;
          const int col = bn + wno + j * 16 + lrow;
          C[(size_t)row * KN2 + col] = f2bf(acc[i][j][r]);
        }
  } else {
#pragma unroll
    for (int i = 0; i < 4; i++)
#pragma unroll
      for (int j = 0; j < 4; j++)
#pragma unroll
        for (int r = 0; r < 4; r++) {
          const int row = bm + wmo + i * 16 + kgrp * 4 + r;
          const int col = wno + j * 16 + lrow;   // 0..127
          scf[(size_t)row * 128 + col] = acc[i][j][r];
        }
  }
}

// ---------------- mini MFMA GEMM: M-tile 96, N-tile 128, BK=64 -------------
template <int EP>
__global__ __launch_bounds__(256) void mfma96_kernel(
    const short* __restrict__ A,    // [288][K] bf16
    const short* __restrict__ Bt,   // [N][K] bf16
    int K, int ldn,
    const float* __restrict__ bias, // [ldn]
    const float* __restrict__ kern, // EP0
    float* __restrict__ Cf,
    short* __restrict__ Cb)
{
  __shared__ short As[96 * BK];
  __shared__ short Bs[128 * BK];
  const int tid = threadIdx.x;
  const int wave = tid >> 6, lane = tid & 63;
  const int bm = blockIdx.x * 96;
  const int bn = blockIdx.y * 128;
  const int wmo = (wave >> 1) * 48;
  const int wno = (wave & 1) * 64;
  const int lrow = lane & 15;
  const int kgrp = lane >> 4;
  const int sr = tid >> 3;
  const int ss = tid & 7;
  const int rs0 = kgrp ^ (lrow & 7);
  const int rs1 = (4 + kgrp) ^ (lrow & 7);
  f32x4 acc[3][4];
#pragma unroll
  for (int i = 0; i < 3; i++)
#pragma unroll
    for (int j = 0; j < 4; j++) acc[i][j] = (f32x4){0.f, 0.f, 0.f, 0.f};
  for (int k0 = 0; k0 < K; k0 += BK) {
    __syncthreads();
#pragma unroll
    for (int i = 0; i < 3; i++) {
      const int r = i * 32 + sr;
      const int sg = ss ^ (r & 7);
      gload16(A + (size_t)(bm + r) * K + k0 + sg * 8, &As[r * BK + ss * 8]);
    }
#pragma unroll
    for (int i = 0; i < 4; i++) {
      const int r = i * 32 + sr;
      const int sg = ss ^ (r & 7);
      gload16(Bt + (size_t)(bn + r) * K + k0 + sg * 8, &Bs[r * BK + ss * 8]);
    }
    __syncthreads();
#pragma unroll
    for (int kh = 0; kh < 2; kh++) {
      const int rs = kh ? rs1 : rs0;
      bf16x8 af[3], bfr[4];
#pragma unroll
      for (int m = 0; m < 3; m++)
        af[m] = *(const bf16x8*)&As[(wmo + m * 16 + lrow) * BK + rs * 8];
#pragma unroll
      for (int n = 0; n < 4; n++)
        bfr[n] = *(const bf16x8*)&Bs[(wno + n * 16 + lrow) * BK + rs * 8];
#pragma unroll
      for (int m = 0; m < 3; m++)
#pragma unroll
        for (int n = 0; n < 4; n++)
          acc[m][n] = __builtin_amdgcn_mfma_f32_16x16x32_bf16(af[m], bfr[n], acc[m][n], 0, 0, 0);
    }
  }
#pragma unroll
  for (int m = 0; m < 3; m++)
#pragma unroll
    for (int n = 0; n < 4; n++)
#pragma unroll
      for (int r = 0; r < 4; r++) {
        const int row = bm + wmo + m * 16 + kgrp * 4 + r;
        const int col = bn + wno + n * 16 + lrow;
        float v = acc[m][n][r] + bias[col];
        if (EP == 0) Cf[(size_t)row * ldn + col] = v + kern[(row % KKK) * ldn + col];
        if (EP == 1) Cb[(size_t)row * ldn + col] = f2bf(gelu_f(v));
        if (EP == 2) Cf[(size_t)row * ldn + col] += v;
      }
}

// ---------------- row LayerNorm (fp32 in, bf16 out) ------------------------
__global__ __launch_bounds__(256) void row_ln_bf_kernel(
    const float* __restrict__ in, short* __restrict__ out,
    const float* __restrict__ g, const float* __restrict__ bb, float eps)
{
  const int row = blockIdx.x;
  const int tid = threadIdx.x;
  __shared__ float red[256];
  const size_t base = (size_t)row * CC;
  float x0 = in[base + tid];
  float x1 = in[base + tid + 256];
  float x2 = in[base + tid + 512];
  red[tid] = x0 + x1 + x2;
  __syncthreads();
  for (int st = 128; st > 0; st >>= 1) { if (tid < st) red[tid] += red[tid + st]; __syncthreads(); }
  float mean = red[0] * (1.0f / 768.0f);
  __syncthreads();
  float d0 = x0 - mean, d1 = x1 - mean, d2 = x2 - mean;
  red[tid] = d0 * d0 + d1 * d1 + d2 * d2;
  __syncthreads();
  for (int st = 128; st > 0; st >>= 1) { if (tid < st) red[tid] += red[tid + st]; __syncthreads(); }
  float rstd = rsqrtf(red[0] * (1.0f / 768.0f) + eps);
  out[base + tid]       = f2bf(d0 * rstd * g[tid]       + bb[tid]);
  out[base + tid + 256] = f2bf(d1 * rstd * g[tid + 256] + bb[tid + 256]);
  out[base + tid + 512] = f2bf(d2 * rstd * g[tid + 512] + bb[tid + 512]);
}

// ---------------- attention: precomputed scores; softmax + PV --------------
__global__ __launch_bounds__(256) void attn_kernel(
    const float* __restrict__ scf,      // [32768][128] fp32 (pre-scaled)
    const short* __restrict__ big,      // [32768][1664] bf16 (v|xq|..)
    short* __restrict__ ca)             // [32][9][768] bf16
{
  const int b = blockIdx.x;
  const int h = blockIdx.y;
  const int tid = threadIdx.x;
  const int wave = tid >> 6, lane = tid & 63;
  __shared__ float sc[KKK][NN];
  __shared__ float part[4][KKK][HDD];
#pragma unroll
  for (int nn = 0; nn < 4; nn++) {
    const int n = tid + nn * 256;
    const float* sp = &scf[(size_t)(b * NN + n) * 128 + h * 9];
#pragma unroll
    for (int q = 0; q < KKK; q++) sc[q][n] = sp[q];
  }
  __syncthreads();
  for (int q = wave; q < KKK; q += 4) {
    float m = -1e30f;
#pragma unroll
    for (int i = 0; i < 16; i++) m = fmaxf(m, sc[q][lane + i * 64]);
#pragma unroll
    for (int off = 32; off > 0; off >>= 1) m = fmaxf(m, __shfl_xor(m, off));
    float s = 0.f;
#pragma unroll
    for (int i = 0; i < 16; i++) {
      float e = expf(sc[q][lane + i * 64] - m);
      sc[q][lane + i * 64] = e;
      s += e;
    }
#pragma unroll
    for (int off = 32; off > 0; off >>= 1) s += __shfl_xor(s, off);
    float inv = 1.0f / s;
#pragma unroll
    for (int i = 0; i < 16; i++) sc[q][lane + i * 64] *= inv;
  }
  __syncthreads();
  const int d = tid & 63, prt = tid >> 6;
  float po[KKK];
#pragma unroll
  for (int q = 0; q < KKK; q++) po[q] = 0.f;
  const short* vbase = &big[(size_t)(b * NN) * KN2 + h * HDD + d];  // v at col 0
  for (int n0 = prt * 256; n0 < prt * 256 + 256; n0 += 4) {
    f32x4 p[KKK];
#pragma unroll
    for (int q = 0; q < KKK; q++) p[q] = *(const f32x4*)&sc[q][n0];
#pragma unroll
    for (int j = 0; j < 4; j++) {
      float vf = bfbits2f(vbase[(size_t)(n0 + j) * KN2]);
#pragma unroll
      for (int q = 0; q < KKK; q++) po[q] += p[q][j] * vf;
    }
  }
#pragma unroll
  for (int q = 0; q < KKK; q++) part[prt][q][d] = po[q];
  __syncthreads();
  for (int i = tid; i < KKK * HDD; i += 256) {
    int q = i >> 6, dd = i & 63;
    ca[(size_t)(b * KKK + q) * CC + h * HDD + dd] =
        f2bf(part[0][q][dd] + part[1][q][dd] + part[2][q][dd] + part[3][q][dd]);
  }
}

// ---------------- token mixer (bf16 input) ---------------------------------
__global__ __launch_bounds__(256) void token_mix_kernel(
    const short* __restrict__ ln1,     // [288][768] bf16
    const float* __restrict__ pm1_w,   // [9][1536]
    const float* __restrict__ pm1_b,   // [1536]
    const float* __restrict__ pm2_w,   // [1536][9]
    float* __restrict__ part)          // [8][32][9][768]
{
  const int tid = threadIdx.x;
  const int c = blockIdx.x * 256 + tid;
  const int b = blockIdx.y;
  const int jc = blockIdx.z;
  float u[KKK], o[KKK];
#pragma unroll
  for (int q = 0; q < KKK; q++) {
    u[q] = bfbits2f(ln1[(size_t)(b * KKK + q) * CC + c]);
    o[q] = 0.f;
  }
  const int j0 = jc * (PMDD / 8);
  for (int j = j0; j < j0 + PMDD / 8; j++) {
    float hs = pm1_b[j];
#pragma unroll
    for (int q = 0; q < KKK; q++) hs += u[q] * pm1_w[q * PMDD + j];
    float gv = gelu_f(hs);
    const float* p2 = &pm2_w[(size_t)j * KKK];
#pragma unroll
    for (int q = 0; q < KKK; q++) o[q] += gv * p2[q];
  }
  float* pp = &part[(size_t)((jc * BB + b) * KKK) * CC + c];
#pragma unroll
  for (int q = 0; q < KKK; q++) pp[(size_t)q * CC] = o[q];
}

// ---------------- token reduce + LN2 (bf16 LN output) ----------------------
__global__ __launch_bounds__(256) void token_reduce_ln_kernel(
    const float* __restrict__ part,    // [8][32][9][768]
    const float* __restrict__ pm2_b,   // [9]
    const float* __restrict__ g, const float* __restrict__ bb,
    float* __restrict__ w1,            // [288][768] (in/out)
    short* __restrict__ lnb)           // [288][768] bf16
{
  const int row = blockIdx.x;
  const int q = row % KKK;
  const int tid = threadIdx.x;
  __shared__ float red[256];
  const size_t base = (size_t)row * CC;
  float v[3];
#pragma unroll
  for (int j = 0; j < 3; j++) {
    const int c = tid + j * 256;
    float s = 0.f;
#pragma unroll
    for (int gg = 0; gg < 8; gg++)
      s += part[(size_t)gg * BB * KKK * CC + base + c];
    v[j] = w1[base + c] + s + pm2_b[q];
    w1[base + c] = v[j];
  }
  red[tid] = v[0] + v[1] + v[2];
  __syncthreads();
  for (int st = 128; st > 0; st >>= 1) { if (tid < st) red[tid] += red[tid + st]; __syncthreads(); }
  float mean = red[0] * (1.0f / 768.0f);
  __syncthreads();
  float d0 = v[0] - mean, d1 = v[1] - mean, d2 = v[2] - mean;
  red[tid] = d0 * d0 + d1 * d1 + d2 * d2;
  __syncthreads();
  for (int st = 128; st > 0; st >>= 1) { if (tid < st) red[tid] += red[tid + st]; __syncthreads(); }
  float rstd = rsqrtf(red[0] * (1.0f / 768.0f) + 1e-5f);
  lnb[base + tid]       = f2bf(d0 * rstd * g[tid]       + bb[tid]);
  lnb[base + tid + 256] = f2bf(d1 * rstd * g[tid + 256] + bb[tid + 256]);
  lnb[base + tid + 512] = f2bf(d2 * rstd * g[tid + 512] + bb[tid + 512]);
}

// ---------------- conv: LDS-staged read-once, sliding window ---------------
__global__ __launch_bounds__(256) void conv_lds_kernel(
    const short* __restrict__ big,   // xq (bf16) at column offset 768
    const float* __restrict__ w1,    // [32][9][768] filters
    float* __restrict__ out)         // [32][1024][768] fp32
{
  __shared__ short rows[3][32][132];
  const int c0 = blockIdx.x * 128;
  const int b = blockIdx.y;
  const int y0 = blockIdx.z * 8;
  const int tid = threadIdx.x;
  const int xl = tid >> 3, cg = tid & 7;
  const int cl = tid & 127, xh = tid >> 7;
  float f[KKK];
#pragma unroll
  for (int q = 0; q < KKK; q++) f[q] = w1[(size_t)(b * KKK + q) * CC + c0 + cl];

#define LOAD_ROW(yy, slot)                                                     \
  {                                                                            \
    short* dst = &rows[slot][xl][cg * 16];                                     \
    if ((yy) >= 0 && (yy) < 32) {                                              \
      const short* src =                                                       \
          &big[(size_t)(b * NN + (yy) * 32 + xl) * KN2 + CC + c0 + cg * 16];   \
      *(bf16x8*)dst = *(const bf16x8*)src;                                     \
      *(bf16x8*)(dst + 8) = *(const bf16x8*)(src + 8);                         \
    } else {                                                                   \
      bf16x8 z = {0, 0, 0, 0, 0, 0, 0, 0};                                     \
      *(bf16x8*)dst = z;                                                       \
      *(bf16x8*)(dst + 8) = z;                                                 \
    }                                                                          \
  }

  int sPrev = 0, sCur = 1, sNext = 2;
  LOAD_ROW(y0 - 1, 0);
  LOAD_ROW(y0, 1);
  for (int y = y0; y < y0 + 8; ++y) {
    LOAD_ROW(y + 1, sNext);
    __syncthreads();
    const int xb = xh * 16;
    float v0[3], v1[3];
#pragma unroll
    for (int ky = 0; ky < 3; ky++) {
      const int s = (ky == 0) ? sPrev : (ky == 1 ? sCur : sNext);
      v1[ky] = bfbits2f(rows[s][xb][cl]);
      v0[ky] = (xb == 0) ? 0.f : bfbits2f(rows[s][xb - 1][cl]);
    }
    float* op = &out[(size_t)(b * NN + y * 32 + xb) * CC + c0 + cl];
#pragma unroll
    for (int i = 0; i < 16; i++) {
      const int x = xb + i;
      float v2[3];
#pragma unroll
      for (int ky = 0; ky < 3; ky++) {
        const int s = (ky == 0) ? sPrev : (ky == 1 ? sCur : sNext);
        v2[ky] = (x + 1 < 32) ? bfbits2f(rows[s][x + 1][cl]) : 0.f;
      }
      float acc = 0.f;
#pragma unroll
      for (int ky = 0; ky < 3; ky++)
        acc += f[ky * 3] * v0[ky] + f[ky * 3 + 1] * v1[ky] + f[ky * 3 + 2] * v2[ky];
      op[(size_t)i * CC] = acc;
#pragma unroll
      for (int ky = 0; ky < 3; ky++) { v0[ky] = v1[ky]; v1[ky] = v2[ky]; }
    }
    __syncthreads();
    const int t = sPrev; sPrev = sCur; sCur = sNext; sNext = t;
  }
#undef LOAD_ROW
}

// ---------------------------------------------------------------------------
extern "C" void kernel_launch(void* const* d_in, const int* in_sizes, int n_in,
                              void* d_out, int out_size, void* d_ws, size_t ws_size,
                              hipStream_t stream) {
  (void)in_sizes; (void)n_in; (void)out_size; (void)ws_size;
  const float* x       = (const float*)d_in[0];
  const float* kern    = (const float*)d_in[3];
  const float* ln_g    = (const float*)d_in[4];
  const float* ln_b    = (const float*)d_in[5];
  const float* kv_w    = (const float*)d_in[6];
  const float* proj_w  = (const float*)d_in[7];
  const float* proj_b  = (const float*)d_in[8];
  const float* projq_w = (const float*)d_in[9];
  const float* n1_g    = (const float*)d_in[10];
  const float* n1_b    = (const float*)d_in[11];
  const float* n2_g    = (const float*)d_in[12];
  const float* n2_b    = (const float*)d_in[13];
  const float* pm1_w   = (const float*)d_in[14];
  const float* pm1_b   = (const float*)d_in[15];
  const float* pm2_w   = (const float*)d_in[16];
  const float* pm2_b   = (const float*)d_in[17];
  const float* cm1_w   = (const float*)d_in[18];
  const float* cm1_b   = (const float*)d_in[19];
  const float* cm2_w   = (const float*)d_in[20];
  const float* cm2_b   = (const float*)d_in[21];
  float* out = (float*)d_out;

  uint8_t* ws = (uint8_t*)d_ws;
  short* Wt   = (short*)(ws);                    // 1664*768*2 = 2,555,904
  short* h1   = (short*)(ws);                    // ALIAS: 884,736 (Wt dead)
  short* big  = (short*)(ws + 3538944);          // 32768*1664*2 = 109,051,904
  float* scf  = (float*)(ws + 112590848);        // 32768*128*4 = 16,777,216
  short* cab  = (short*)(ws + 154561536);        // 442,368
  float* w1   = (float*)(ws + 155446272);        // 884,736
  short* ln1b = (short*)(ws + 156331008);        // 442,368
  short* ln2b = (short*)(ws + 156773376);        // 442,368 -> 157,215,744

  short* xb    = (short*)d_out;
  float* tpart = (float*)d_out;
  short* WpT   = (short*)((uint8_t*)d_out + 62914560);  // [768][768]
  short* Wc1T  = (short*)((uint8_t*)d_out + 64094208);  // [1536][768]
  short* Wc2T  = (short*)((uint8_t*)d_out + 66453504);  // [768][1536]

  prep_kernel<<<dim3(XBF_BLOCKS + WT_BLOCKS + WT2_BLOCKS + SW_BLOCKS), 256, 0, stream>>>(
      x, xb, kv_w, projq_w, Wt, proj_w, cm1_w, cm2_w, WpT, Wc1T, Wc2T,
      kern, ln_g, ln_b);
  gemm_bt_kernel<<<dim3((MM / 128) * (KN2 / 128)), 256, 0, stream>>>(xb, Wt, big, scf);
  attn_kernel<<<dim3(BB, NHH), 256, 0, stream>>>(scf, big, cab);
  mfma96_kernel<0><<<dim3(3, 6), 256, 0, stream>>>(cab, WpT, CC, CC,
                                                   proj_b, kern, w1, nullptr);
  row_ln_bf_kernel<<<dim3(BB * KKK), 256, 0, stream>>>(w1, ln1b, n1_g, n1_b, 1e-5f);
  token_mix_kernel<<<dim3(3, 32, 8), 256, 0, stream>>>(ln1b, pm1_w, pm1_b, pm2_w, tpart);
  token_reduce_ln_kernel<<<dim3(BB * KKK), 256, 0, stream>>>(tpart, pm2_b,
                                                             n2_g, n2_b, w1, ln2b);
  mfma96_kernel<1><<<dim3(3, 12), 256, 0, stream>>>(ln2b, Wc1T, CC, CMDD,
                                                    cm1_b, nullptr, nullptr, h1);
  mfma96_kernel<2><<<dim3(3, 6), 256, 0, stream>>>(h1, Wc2T, CMDD, CC,
                                                   cm2_b, nullptr, w1, nullptr);
  conv_lds_kernel<<<dim3(6, 32, 4), 256, 0, stream>>>(big, w1, out);
}